// Round 13
// baseline (1190.573 us; speedup 1.0000x reference)
//
#include <hip/hip_runtime.h>
#include <math.h>

#define NT 4096
#define DM 1152
#define NH 16
#define DH 72
#define KRET 1638
#define NPR (NT - KRET)
#define CSB 8
#define CHUNK 205
#define SCALE 0.11785113019775793f
#define RSPLIT 2048.0f
#define INV_RSPLIT 4.8828125e-4f

typedef __attribute__((ext_vector_type(8))) short bf16x8;
typedef _Float16 f16;
typedef __attribute__((ext_vector_type(8))) _Float16 f16x8;
typedef __attribute__((ext_vector_type(4))) float f32x4;
typedef unsigned short ushort_t;

#define MFMA16(a, b, c) __builtin_amdgcn_mfma_f32_16x16x32_f16(a, b, c, 0, 0, 0)
#define MFMABF(a, b, c) __builtin_amdgcn_mfma_f32_16x16x32_bf16(a, b, c, 0, 0, 0)

__device__ inline ushort_t f2b(float f) {
    union { float f; unsigned int u; } v; v.f = f;
    unsigned int u = v.u;
    return (ushort_t)((u + 0x7FFFu + ((u >> 16) & 1u)) >> 16);
}

// async global->LDS copy, 16B per lane; LDS base wave-uniform, global per-lane
__device__ __forceinline__ void async16(void* lds, const void* g) {
    __builtin_amdgcn_global_load_lds(
        (const __attribute__((address_space(1))) unsigned*)g,
        (__attribute__((address_space(3))) unsigned*)lds, 16, 0, 0);
}

// tiled Q/K address: [NH][rowblk 256][ks 3][r 16][ki 32]
__device__ inline size_t qkAddr(int h, int row, int ks, int ki) {
    return ((((size_t)h * 256 + (row >> 4)) * 3 + ks) * 16 + (row & 15)) * 32 + ki;
}

// ---------- split x into fp16 hi/lo(x2048) planes + bf16 copy ----------------
__global__ __launch_bounds__(256) void split_x(
    const float* __restrict__ in, f16* __restrict__ x0, f16* __restrict__ x1,
    ushort_t* __restrict__ xb, int nElem)
{
    int i = blockIdx.x * 256 + threadIdx.x;
    int stride = gridDim.x * 256;
    for (; i < nElem; i += stride) {
        float v = in[i];
        f16 h0 = (f16)v;
        float res = (v - (float)h0) * RSPLIT;
        x0[i] = h0;
        x1[i] = (f16)res;
        xb[i] = f2b(v);
    }
}

__global__ __launch_bounds__(256) void transposeW_split(
    const float* __restrict__ W, f16* __restrict__ T0, f16* __restrict__ T1, int n)
{
    __shared__ float t[32][33];
    int bx = blockIdx.x * 32, by = blockIdx.y * 32;
    int tx = threadIdx.x & 31, ty = threadIdx.x >> 5;
    for (int i = ty; i < 32; i += 8)
        t[i][tx] = W[(size_t)(by + i) * n + bx + tx];
    __syncthreads();
    for (int i = ty; i < 32; i += 8) {
        float v = t[tx][i];
        f16 h0 = (f16)v;
        float res = (v - (float)h0) * RSPLIT;
        T0[(size_t)(bx + i) * n + by + tx] = h0;
        T1[(size_t)(bx + i) * n + by + tx] = (f16)res;
    }
}

__global__ __launch_bounds__(256) void transposeW_bf16(
    const float* __restrict__ W, ushort_t* __restrict__ WT, int n)
{
    __shared__ ushort_t t[32][33];
    int bx = blockIdx.x * 32, by = blockIdx.y * 32;
    int tx = threadIdx.x & 31, ty = threadIdx.x >> 5;
    for (int i = ty; i < 32; i += 8)
        t[i][tx] = f2b(W[(size_t)(by + i) * n + bx + tx]);
    __syncthreads();
    for (int i = ty; i < 32; i += 8)
        WT[(size_t)(bx + i) * n + by + tx] = t[tx][i];
}

// ---------- LDS-tiled split projection -> MFMA-tiled per-head output ---------
__global__ __launch_bounds__(256) void proj_split3(
    const f16* __restrict__ A0, const f16* __restrict__ A1,
    const f16* __restrict__ B0, const f16* __restrict__ B1,
    f16* __restrict__ Qt0, f16* __restrict__ Qt1, float scl)
{
    __shared__ __align__(16) f16 As0[128][40];
    __shared__ __align__(16) f16 As1[128][40];
    __shared__ __align__(16) f16 Bs0[64][40];
    __shared__ __align__(16) f16 Bs1[64][40];
    const int tid = threadIdx.x;
    const int wave = tid >> 6, lane = tid & 63;
    const int r = lane & 15, g = lane >> 4;
    const int row0 = blockIdx.y * 128;
    const int col0 = blockIdx.x * 64;
    f32x4 accM[2][4] = {}, accC[2][4] = {};
    for (int k0 = 0; k0 < DM; k0 += 32) {
        for (int idx = tid; idx < 128 * 4; idx += 256) {
            int row = idx >> 2, c = idx & 3;
            size_t src = (size_t)(row0 + row) * DM + k0 + c * 8;
            *(f16x8*)&As0[row][c * 8] = *(const f16x8*)(A0 + src);
            *(f16x8*)&As1[row][c * 8] = *(const f16x8*)(A1 + src);
        }
        for (int idx = tid; idx < 64 * 4; idx += 256) {
            int row = idx >> 2, c = idx & 3;
            size_t src = (size_t)(col0 + row) * DM + k0 + c * 8;
            *(f16x8*)&Bs0[row][c * 8] = *(const f16x8*)(B0 + src);
            *(f16x8*)&Bs1[row][c * 8] = *(const f16x8*)(B1 + src);
        }
        __syncthreads();
        f16x8 a0[2], a1[2], b0[4], b1[4];
#pragma unroll
        for (int rf = 0; rf < 2; ++rf) {
            a0[rf] = *(const f16x8*)&As0[wave * 32 + rf * 16 + r][g * 8];
            a1[rf] = *(const f16x8*)&As1[wave * 32 + rf * 16 + r][g * 8];
        }
#pragma unroll
        for (int cf = 0; cf < 4; ++cf) {
            b0[cf] = *(const f16x8*)&Bs0[cf * 16 + r][g * 8];
            b1[cf] = *(const f16x8*)&Bs1[cf * 16 + r][g * 8];
        }
#pragma unroll
        for (int rf = 0; rf < 2; ++rf)
#pragma unroll
            for (int cf = 0; cf < 4; ++cf) {
                accM[rf][cf] = MFMA16(a0[rf], b0[cf], accM[rf][cf]);
                accC[rf][cf] = MFMA16(a0[rf], b1[cf], accC[rf][cf]);
                accC[rf][cf] = MFMA16(a1[rf], b0[cf], accC[rf][cf]);
            }
        __syncthreads();
    }
#pragma unroll
    for (int rf = 0; rf < 2; ++rf)
#pragma unroll
        for (int cf = 0; cf < 4; ++cf) {
            int col = col0 + cf * 16 + r;
            int head = col / DH;
            int c = col - head * DH;
            int ks = c >> 5, ki = c & 31;
#pragma unroll
            for (int j = 0; j < 4; ++j) {
                int row = row0 + wave * 32 + rf * 16 + g * 4 + j;
                float v = (accM[rf][cf][j] + accC[rf][cf][j] * INV_RSPLIT) * scl;
                f16 h0 = (f16)v;
                float res = (v - (float)h0) * RSPLIT;
                size_t addr = qkAddr(head, row, ks, ki);
                Qt0[addr] = h0;
                Qt1[addr] = (f16)res;
            }
        }
}

// ---------- LDS-tiled bf16 MFMA GEMM; mode 0 = fp32 flat, 2 = Vp tiled -------
__global__ __launch_bounds__(256) void gemm_bf16_lds(
    const ushort_t* __restrict__ A, const ushort_t* __restrict__ BT,
    const float* __restrict__ bias, void* __restrict__ C, int mode,
    int Nn, int K)
{
    __shared__ __align__(16) ushort_t As[128][40];
    __shared__ __align__(16) ushort_t Bs[64][40];
    const int tid = threadIdx.x;
    const int wave = tid >> 6, lane = tid & 63;
    const int r = lane & 15, g = lane >> 4;
    const int row0 = blockIdx.y * 128;
    const int col0 = blockIdx.x * 64;
    f32x4 acc[2][4] = {};
    for (int k0 = 0; k0 < K; k0 += 32) {
        for (int idx = tid; idx < 128 * 4; idx += 256) {
            int row = idx >> 2, c = idx & 3;
            *(bf16x8*)&As[row][c * 8] = *(const bf16x8*)(A + (size_t)(row0 + row) * K + k0 + c * 8);
        }
        for (int idx = tid; idx < 64 * 4; idx += 256) {
            int row = idx >> 2, c = idx & 3;
            *(bf16x8*)&Bs[row][c * 8] = *(const bf16x8*)(BT + (size_t)(col0 + row) * K + k0 + c * 8);
        }
        __syncthreads();
        bf16x8 a[2], b[4];
#pragma unroll
        for (int rf = 0; rf < 2; ++rf)
            a[rf] = *(const bf16x8*)&As[wave * 32 + rf * 16 + r][g * 8];
#pragma unroll
        for (int cf = 0; cf < 4; ++cf)
            b[cf] = *(const bf16x8*)&Bs[cf * 16 + r][g * 8];
#pragma unroll
        for (int rf = 0; rf < 2; ++rf)
#pragma unroll
            for (int cf = 0; cf < 4; ++cf)
                acc[rf][cf] = MFMABF(a[rf], b[cf], acc[rf][cf]);
        __syncthreads();
    }
#pragma unroll
    for (int rf = 0; rf < 2; ++rf)
#pragma unroll
        for (int cf = 0; cf < 4; ++cf) {
            int col = col0 + cf * 16 + r;
            float bv = bias ? bias[col] : 0.f;
#pragma unroll
            for (int j = 0; j < 4; ++j) {
                int row = row0 + wave * 32 + rf * 16 + g * 4 + j;
                float vv = acc[rf][cf][j] + bv;
                if (mode == 2) {
                    int head = col / DH;
                    int d = col - head * DH;
                    size_t addr = (((size_t)head * 128 + (row >> 5)) * 80 + d) * 32 + (row & 31);
                    ((ushort_t*)C)[addr] = f2b(vv);
                } else {
                    ((float*)C)[(size_t)row * Nn + col] = vv;
                }
            }
        }
}

// ---------- pass A: rowsum + PV, swapped-operand QK, async dbuf staging ------
__global__ __launch_bounds__(256) void rowsum_pv(
    const f16* __restrict__ Qt0, const f16* __restrict__ Qt1,
    const f16* __restrict__ Kt0, const f16* __restrict__ Kt1,
    const ushort_t* __restrict__ Vp,
    float* __restrict__ invs, ushort_t* __restrict__ otmpb)
{
    __shared__ __align__(16) f16 KL[2][2][6144];   // [buf][plane][12 tiles of 512]
    const int tid = threadIdx.x;
    const int wv = tid >> 6, lane = tid & 63;
    const int r = lane & 15, g = lane >> 4;
    const int h = blockIdx.y;
    const int rowblk = blockIdx.x * 4 + wv;
    // Q fragments (used as the B operand of the swapped MFMA)
    f16x8 a0[3], a1[3];
#pragma unroll
    for (int ks = 0; ks < 3; ++ks) {
        size_t o = ((((size_t)h * 256 + rowblk) * 3 + ks) * 16) * 32 + r * 32 + g * 8;
        a0[ks] = *(const f16x8*)(Qt0 + o);
        a1[ks] = *(const f16x8*)(Qt1 + o);
    }
    // permuted per-lane K read columns: c32 = (r>>2)*8 + cfp*4 + (r&3)
    const int c32p0 = ((r >> 2) << 3) + (r & 3);
    float rs = 0.f;
    f32x4 oacc[5] = {};

    auto stageK = [&](int buf, int ct) {
        const size_t ctBase = ((size_t)h * 256 + ct * 4) * 1536;
#pragma unroll
        for (int s = 0; s < 6; ++s) {
            int wc = s * 4 + wv;             // 0..23 wave-chunks of 1024B
            int plane = wc >= 12;
            int cip = wc - plane * 12;
            const f16* src = (plane ? Kt1 : Kt0) + ctBase + cip * 512 + lane * 8;
            async16(&KL[buf][plane][cip * 512], src);
        }
    };

    stageK(0, 0);
    asm volatile("s_waitcnt vmcnt(0)" ::: "memory");
    __builtin_amdgcn_s_barrier();
    int cur = 0;
    for (int ct = 0; ct < 64; ++ct) {
        if (ct + 1 < 64) stageK(cur ^ 1, ct + 1);
        f32x4 accM[4] = {}, accC[4] = {};
#pragma unroll
        for (int ks = 0; ks < 3; ++ks) {
#pragma unroll
            for (int group = 0; group < 2; ++group) {
#pragma unroll
                for (int cfp = 0; cfp < 2; ++cfp) {
                    const int c32 = c32p0 + cfp * 4;
                    const int off = (((group * 2 + (c32 >> 4)) * 3 + ks) << 9)
                                  + ((c32 & 15) << 5) + (g << 3);
                    f16x8 b0 = *(const f16x8*)&KL[cur][0][off];
                    f16x8 b1 = *(const f16x8*)&KL[cur][1][off];
                    const int cf = group * 2 + cfp;
                    accM[cf] = MFMA16(b0, a0[ks], accM[cf]);
                    accC[cf] = MFMA16(b1, a0[ks], accC[cf]);
                    accC[cf] = MFMA16(b0, a1[ks], accC[cf]);
                }
            }
        }
        // exp -> rs + in-register bf16 pack -> PV
        const int kt0 = ct * 2;
#pragma unroll
        for (int group = 0; group < 2; ++group) {
            bf16x8 pa;
#pragma unroll
            for (int cfp = 0; cfp < 2; ++cfp) {
                const int cf = group * 2 + cfp;
#pragma unroll
                for (int j = 0; j < 4; ++j) {
                    float ev = __expf(accM[cf][j] + accC[cf][j] * INV_RSPLIT);
                    rs += ev;
                    pa[cfp * 4 + j] = (short)f2b(ev);
                }
            }
#pragma unroll
            for (int t = 0; t < 5; ++t) {
                int col = t * 16 + r;
                size_t vo = (((size_t)h * 128 + kt0 + group) * 80 + col) * 32 + g * 8;
                bf16x8 b = *(const bf16x8*)(Vp + vo);
                oacc[t] = MFMABF(pa, b, oacc[t]);
            }
        }
        asm volatile("s_waitcnt vmcnt(0)" ::: "memory");
        __builtin_amdgcn_s_barrier();
        cur ^= 1;
    }
    // rs is per-lane partial for q-row r; reduce over the 4 g-groups
    rs += __shfl_xor(rs, 16);
    rs += __shfl_xor(rs, 32);
    const float inv = 1.0f / rs;
    if (g == 0)
        invs[(size_t)h * NT + rowblk * 16 + r] = inv;
    float invq[4];
#pragma unroll
    for (int j = 0; j < 4; ++j) invq[j] = __shfl(inv, g * 4 + j);
#pragma unroll
    for (int t = 0; t < 5; ++t) {
        int col = t * 16 + r;
        if (col < DH) {
#pragma unroll
            for (int j = 0; j < 4; ++j) {
                int row = rowblk * 16 + g * 4 + j;
                otmpb[(size_t)row * DM + h * DH + col] = f2b(oacc[t][j] * invq[j]);
            }
        }
    }
}

// ---------- pass B: attn head-sum, head-outer, async dbuf staging ------------
__global__ __launch_bounds__(256) void attn_sum(
    const f16* __restrict__ Qt0, const f16* __restrict__ Qt1,
    const f16* __restrict__ Kt0, const f16* __restrict__ Kt1,
    const float* __restrict__ invs, float* __restrict__ attn)
{
    __shared__ __align__(16) f16 KL[2][2][6144];   // [buf][plane][12 tiles]
    const int tid = threadIdx.x;
    const int wr = tid >> 6, lane = tid & 63;
    const int r = lane & 15, g = lane >> 4;
    const int cs = blockIdx.x;
    const int rowblk = blockIdx.y * 4 + wr;
    const int row0 = rowblk * 16;
    const int cb0 = cs * 32;                    // colblk base for this col-slice
    float aacc[8][4][4] = {};                   // [ct][cf][j]

    auto stageA = [&](int buf, int step) {
        int hh = step >> 3, ct = step & 7;
        const size_t ctBase = ((size_t)hh * 256 + cb0 + ct * 4) * 1536;
#pragma unroll
        for (int s = 0; s < 6; ++s) {
            int wc = s * 4 + wr;                // 0..23 wave-chunks of 1024B
            int plane = wc >= 12;
            int cip = wc - plane * 12;
            const f16* src = (plane ? Kt1 : Kt0) + ctBase + cip * 512 + lane * 8;
            async16(&KL[buf][plane][cip * 512], src);
        }
    };

    stageA(0, 0);
    asm volatile("s_waitcnt vmcnt(0)" ::: "memory");
    __builtin_amdgcn_s_barrier();
    int cur = 0;
    for (int h = 0; h < NH; ++h) {
        // Q fragments once per head
        f16x8 a0[3], a1[3];
#pragma unroll
        for (int ks = 0; ks < 3; ++ks) {
            size_t o = ((((size_t)h * 256 + rowblk) * 3 + ks) * 16) * 32 + r * 32 + g * 8;
            a0[ks] = *(const f16x8*)(Qt0 + o);
            a1[ks] = *(const f16x8*)(Qt1 + o);
        }
        float vinv[4];
#pragma unroll
        for (int j = 0; j < 4; ++j)
            vinv[j] = invs[(size_t)h * NT + row0 + g * 4 + j];
#pragma unroll
        for (int ct = 0; ct < 8; ++ct) {
            int step = h * 8 + ct;
            if (step + 1 < 128) stageA(cur ^ 1, step + 1);
            f32x4 accM[4] = {}, accC[4] = {};
#pragma unroll
            for (int ks = 0; ks < 3; ++ks) {
#pragma unroll
                for (int cf = 0; cf < 4; ++cf) {
                    f16x8 b0 = *(const f16x8*)&KL[cur][0][(cf * 3 + ks) * 512 + r * 32 + g * 8];
                    f16x8 b1 = *(const f16x8*)&KL[cur][1][(cf * 3 + ks) * 512 + r * 32 + g * 8];
                    accM[cf] = MFMA16(a0[ks], b0, accM[cf]);
                    accC[cf] = MFMA16(a0[ks], b1, accC[cf]);
                    accC[cf] = MFMA16(a1[ks], b0, accC[cf]);
                }
            }
#pragma unroll
            for (int cf = 0; cf < 4; ++cf) {
#pragma unroll
                for (int j = 0; j < 4; ++j) {
                    float p = __expf(accM[cf][j] + accC[cf][j] * INV_RSPLIT) * vinv[j];
                    aacc[ct][cf][j] += p;
                }
            }
            asm volatile("s_waitcnt vmcnt(0)" ::: "memory");
            __builtin_amdgcn_s_barrier();
            cur ^= 1;
        }
    }
    // write attn once (no rmw)
#pragma unroll
    for (int ct = 0; ct < 8; ++ct) {
        const int colbase = cs * 512 + ct * 64;
#pragma unroll
        for (int cf = 0; cf < 4; ++cf) {
#pragma unroll
            for (int j = 0; j < 4; ++j) {
                int row = row0 + g * 4 + j;
                attn[(size_t)row * NT + colbase + cf * 16 + r] = aacc[ct][cf][j] * 0.0625f;
            }
        }
    }
}

// ---------- pagerank power iteration (fp32, unchanged) -----------------------
__global__ __launch_bounds__(256) void init_dist(float* __restrict__ d)
{
    int t = blockIdx.x * 256 + threadIdx.x;
    if (t < NT) d[t] = 1.0f / NT;
}

__global__ __launch_bounds__(256) void power_a(
    const float* __restrict__ attn, const float* __restrict__ din,
    float* __restrict__ part)
{
    int j = blockIdx.x * 256 + threadIdx.x;
    int i0 = blockIdx.y * 128;
    float acc = 0.f;
    for (int i = i0; i < i0 + 128; ++i)
        acc += din[i] * attn[(size_t)i * NT + j];
    part[(size_t)blockIdx.y * NT + j] = acc;
}

__global__ __launch_bounds__(256) void power_b(
    const float* __restrict__ part, float* __restrict__ dout)
{
    int j = blockIdx.x * 256 + threadIdx.x;
    float acc = 0.f;
    for (int ib = 0; ib < 32; ++ib) acc += part[(size_t)ib * NT + j];
    dout[j] = acc;
}

// ---------- top-k: tiled rank counting (deterministic int atomics) -----------
__global__ __launch_bounds__(256) void rank_count(
    const float* __restrict__ imp, int* __restrict__ rank, int* __restrict__ prank)
{
    __shared__ float sj[256];
    const int tid = threadIdx.x;
    const int jb = blockIdx.y * 256;
    sj[tid] = imp[jb + tid];
    __syncthreads();
    const int i = blockIdx.x * 256 + tid;
    const float mv = imp[i];
    int r = 0, rp = 0;
    for (int jj = 0; jj < 256; ++jj) {
        float vj = sj[jj];
        int j = jb + jj;
        int tie_low = (vj == mv) && (j < i);
        r  += (vj > mv) || tie_low;
        rp += (vj < mv) || tie_low;
    }
    atomicAdd(&rank[i], r);
    atomicAdd(&prank[i], rp);
}

__global__ __launch_bounds__(256) void scatter_topk2(
    const int* __restrict__ rank, const int* __restrict__ prank,
    float* __restrict__ out_imps, float* __restrict__ out_prune,
    int* __restrict__ imp_rows, int* __restrict__ prune_cols)
{
    __shared__ unsigned char fr[NT];
    __shared__ unsigned char fp[NT];
    __shared__ int sr[256], sp[256];
    const int tid = threadIdx.x;
    for (int t = tid; t < NT; t += 256) {
        fr[t] = rank[t] < KRET;
        fp[t] = prank[t] < NPR;
    }
    __syncthreads();
    const int base = tid * 16;
    int cr = 0, cp = 0;
#pragma unroll
    for (int e = 0; e < 16; ++e) { cr += fr[base + e]; cp += fp[base + e]; }
    sr[tid] = cr; sp[tid] = cp;
    __syncthreads();
    int pr = 0, pp = 0;
    for (int j = 0; j < tid; ++j) { pr += sr[j]; pp += sp[j]; }
#pragma unroll
    for (int e = 0; e < 16; ++e) {
        int i = base + e;
        if (fr[i]) { out_imps[pr] = (float)i; imp_rows[pr] = i; ++pr; }
        if (fp[i]) { out_prune[pp] = (float)i; prune_cols[pp] = i; ++pp; }
    }
}

__global__ __launch_bounds__(256) void argmax_part(
    const float* __restrict__ attn, const int* __restrict__ imp_rows,
    float* __restrict__ pbest, int* __restrict__ pbi)
{
    __shared__ int rows[CHUNK];
    const int tid = threadIdx.x;
    const int rc = blockIdx.y;
    const int r0 = rc * CHUNK;
    const int nr = min(KRET - r0, CHUNK);
    for (int t = tid; t < nr; t += 256) rows[t] = imp_rows[r0 + t];
    __syncthreads();
    const int j = blockIdx.x * 256 + tid;
    float best = -INFINITY;
    int bi = 0;
    for (int rr = 0; rr < nr; ++rr) {
        float val = attn[(size_t)rows[rr] * NT + j];
        if (val > best) { best = val; bi = r0 + rr; }
    }
    pbest[(size_t)rc * NT + j] = best;
    pbi[(size_t)rc * NT + j] = bi;
}

__global__ __launch_bounds__(256) void argmax_red(
    const float* __restrict__ pbest, const int* __restrict__ pbi,
    int* __restrict__ maxind)
{
    const int j = blockIdx.x * 256 + threadIdx.x;
    float best = -INFINITY;
    int bi = 0;
#pragma unroll
    for (int rc = 0; rc < 8; ++rc) {
        float val = pbest[(size_t)rc * NT + j];
        if (val > best) { best = val; bi = pbi[(size_t)rc * NT + j]; }
    }
    maxind[j] = bi;
}

__global__ __launch_bounds__(256) void finalize(
    const float* __restrict__ dist, const int* __restrict__ prune_cols,
    const int* __restrict__ maxind, float* __restrict__ out_imp,
    float* __restrict__ out_simi)
{
    int t = blockIdx.x * 256 + threadIdx.x;
    if (t < NT) out_imp[t] = dist[t];
    if (t < NPR) out_simi[t] = (float)maxind[prune_cols[t]];
}

extern "C" void kernel_launch(void* const* d_in, const int* in_sizes, int n_in,
                              void* d_out, int out_size, void* d_ws, size_t ws_size,
                              hipStream_t stream)
{
    const float* x  = (const float*)d_in[0];
    const float* Wq = (const float*)d_in[1];
    const float* Wk = (const float*)d_in[2];
    const float* Wv = (const float*)d_in[3];
    const float* Wo = (const float*)d_in[4];
    const float* bo = (const float*)d_in[5];
    float* out = (float*)d_out;

    const size_t QKT_EL = (size_t)NH * 256 * 3 * 16 * 32;   // 6.29M f16 per plane
    const size_t VP_EL  = (size_t)NH * 128 * 80 * 32;       // 5.24M bf16

    // ---- workspace layout (float units) ----
    float* ws = (float*)d_ws;
    size_t off = 0;
    float* attn = ws + off; off += (size_t)NT * NT;
    f16* Qt0 = (f16*)(ws + off); off += QKT_EL / 2;
    f16* Qt1 = (f16*)(ws + off); off += QKT_EL / 2;
    f16* Kt0 = (f16*)(ws + off); off += QKT_EL / 2;
    f16* Kt1 = (f16*)(ws + off); off += QKT_EL / 2;
    ushort_t* Vp = (ushort_t*)(ws + off); off += VP_EL / 2;
    size_t zero_floats = 4 * (QKT_EL / 2) + VP_EL / 2;      // Qt0..Vp contiguous
    ushort_t* otmpb = (ushort_t*)(ws + off); off += ((size_t)NT * DM) / 2;
    f16* X0 = (f16*)(ws + off); f16* X1 = X0 + (size_t)NT * DM; off += (size_t)NT * DM;
    f16* T0 = (f16*)(ws + off); f16* T1 = T0 + (size_t)DM * DM; off += (size_t)DM * DM;
    ushort_t* Wslot = (ushort_t*)(ws + off); off += ((size_t)DM * DM) / 2;
    float* invs    = ws + off; off += (size_t)NH * NT;
    float* pbest   = ws + off; off += 8 * NT;
    int*   pbi     = (int*)(ws + off); off += 8 * NT;
    float* dist0 = ws + off; off += NT;
    float* dist1 = ws + off; off += NT;
    float* partial = ws + off; off += 32 * NT;
    int* rank      = (int*)(ws + off); off += NT;
    int* prank     = (int*)(ws + off); off += NT;
    int* imp_rows  = (int*)(ws + off); off += 2048;
    int* prune_cols= (int*)(ws + off); off += 2560;
    int* maxind    = (int*)(ws + off); off += NT;

    // setup-only alias inside attn region (dead before attn_sum writes)
    ushort_t* xb = (ushort_t*)attn;

    // output layout
    float* out_out   = out;
    float* out_imp   = out + (size_t)NT * DM;
    float* out_imps  = out_imp + NT;
    float* out_prune = out_imps + KRET;
    float* out_simi  = out_prune + NPR;

    // ---- setup ----
    hipMemsetAsync(Qt0, 0, zero_floats * sizeof(float), stream);  // zero-pad tiles
    split_x<<<2048, 256, 0, stream>>>(x, X0, X1, xb, NT * DM);

    dim3 gT(DM / 32, DM / 32);
    dim3 gP(DM / 64, NT / 128);
    transposeW_split<<<gT, 256, 0, stream>>>(Wq, T0, T1, DM);
    proj_split3<<<gP, 256, 0, stream>>>(X0, X1, T0, T1, Qt0, Qt1, SCALE);
    transposeW_split<<<gT, 256, 0, stream>>>(Wk, T0, T1, DM);
    proj_split3<<<gP, 256, 0, stream>>>(X0, X1, T0, T1, Kt0, Kt1, 1.0f);

    transposeW_bf16<<<gT, 256, 0, stream>>>(Wv, Wslot, DM);
    gemm_bf16_lds<<<gP, 256, 0, stream>>>(xb, Wslot, nullptr, Vp, 2, DM, DM);

    // ---- pass A: rowsums + PV (swapped-operand QK, register-resident P) ----
    rowsum_pv<<<dim3(NT / 64, NH), 256, 0, stream>>>(Qt0, Qt1, Kt0, Kt1, Vp,
                                                     invs, otmpb);

    // ---- pass B: attn head-sum, single launch, head-outer, write-once ----
    attn_sum<<<dim3(CSB, NT / 64), 256, 0, stream>>>(Qt0, Qt1, Kt0, Kt1, invs, attn);

    // ---- output projection ----
    transposeW_bf16<<<gT, 256, 0, stream>>>(Wo, Wslot, DM);
    gemm_bf16_lds<<<gP, 256, 0, stream>>>(otmpb, Wslot, bo, out_out, 0, DM, DM);

    // ---- pagerank ----
    init_dist<<<16, 256, 0, stream>>>(dist0);
    float* da = dist0;
    float* db = dist1;
    for (int it = 0; it < 5; ++it) {
        power_a<<<dim3(16, 32), 256, 0, stream>>>(attn, da, partial);
        power_b<<<16, 256, 0, stream>>>(partial, db);
        float* t = da; da = db; db = t;
    }

    // ---- top-k ----
    hipMemsetAsync(rank, 0, 2 * NT * sizeof(int), stream);
    rank_count<<<dim3(16, 16), 256, 0, stream>>>(da, rank, prank);
    scatter_topk2<<<1, 256, 0, stream>>>(rank, prank, out_imps, out_prune,
                                         imp_rows, prune_cols);
    argmax_part<<<dim3(16, 8), 256, 0, stream>>>(attn, imp_rows, pbest, pbi);
    argmax_red<<<16, 256, 0, stream>>>(pbest, pbi, maxind);
    finalize<<<16, 256, 0, stream>>>(da, prune_cols, maxind, out_imp, out_simi);
}

// Round 14
// 930.124 us; speedup vs baseline: 1.2800x; 1.2800x over previous
//
#include <hip/hip_runtime.h>
#include <math.h>

#define NT 4096
#define DM 1152
#define NH 16
#define DH 72
#define KRET 1638
#define NPR (NT - KRET)
#define CSB 8
#define ACSB 16
#define CHUNK 205
#define SCALE 0.11785113019775793f
#define RSPLIT 2048.0f
#define INV_RSPLIT 4.8828125e-4f

typedef __attribute__((ext_vector_type(8))) short bf16x8;
typedef _Float16 f16;
typedef __attribute__((ext_vector_type(8))) _Float16 f16x8;
typedef __attribute__((ext_vector_type(4))) float f32x4;
typedef unsigned short ushort_t;

#define MFMA16(a, b, c) __builtin_amdgcn_mfma_f32_16x16x32_f16(a, b, c, 0, 0, 0)
#define MFMABF(a, b, c) __builtin_amdgcn_mfma_f32_16x16x32_bf16(a, b, c, 0, 0, 0)

__device__ inline ushort_t f2b(float f) {
    union { float f; unsigned int u; } v; v.f = f;
    unsigned int u = v.u;
    return (ushort_t)((u + 0x7FFFu + ((u >> 16) & 1u)) >> 16);
}

// tiled Q/K address: [NH][rowblk 256][ks 3][r 16][ki 32]
__device__ inline size_t qkAddr(int h, int row, int ks, int ki) {
    return ((((size_t)h * 256 + (row >> 4)) * 3 + ks) * 16 + (row & 15)) * 32 + ki;
}

// ---------- split x into fp16 hi/lo(x2048) planes + bf16 copy ----------------
__global__ __launch_bounds__(256) void split_x(
    const float* __restrict__ in, f16* __restrict__ x0, f16* __restrict__ x1,
    ushort_t* __restrict__ xb, int nElem)
{
    int i = blockIdx.x * 256 + threadIdx.x;
    int stride = gridDim.x * 256;
    for (; i < nElem; i += stride) {
        float v = in[i];
        f16 h0 = (f16)v;
        float res = (v - (float)h0) * RSPLIT;
        x0[i] = h0;
        x1[i] = (f16)res;
        xb[i] = f2b(v);
    }
}

__global__ __launch_bounds__(256) void transposeW_split(
    const float* __restrict__ W, f16* __restrict__ T0, f16* __restrict__ T1, int n)
{
    __shared__ float t[32][33];
    int bx = blockIdx.x * 32, by = blockIdx.y * 32;
    int tx = threadIdx.x & 31, ty = threadIdx.x >> 5;
    for (int i = ty; i < 32; i += 8)
        t[i][tx] = W[(size_t)(by + i) * n + bx + tx];
    __syncthreads();
    for (int i = ty; i < 32; i += 8) {
        float v = t[tx][i];
        f16 h0 = (f16)v;
        float res = (v - (float)h0) * RSPLIT;
        T0[(size_t)(bx + i) * n + by + tx] = h0;
        T1[(size_t)(bx + i) * n + by + tx] = (f16)res;
    }
}

__global__ __launch_bounds__(256) void transposeW_bf16(
    const float* __restrict__ W, ushort_t* __restrict__ WT, int n)
{
    __shared__ ushort_t t[32][33];
    int bx = blockIdx.x * 32, by = blockIdx.y * 32;
    int tx = threadIdx.x & 31, ty = threadIdx.x >> 5;
    for (int i = ty; i < 32; i += 8)
        t[i][tx] = f2b(W[(size_t)(by + i) * n + bx + tx]);
    __syncthreads();
    for (int i = ty; i < 32; i += 8)
        WT[(size_t)(bx + i) * n + by + tx] = t[tx][i];
}

// ---------- LDS-tiled split projection -> MFMA-tiled per-head output ---------
__global__ __launch_bounds__(256) void proj_split3(
    const f16* __restrict__ A0, const f16* __restrict__ A1,
    const f16* __restrict__ B0, const f16* __restrict__ B1,
    f16* __restrict__ Qt0, f16* __restrict__ Qt1, float scl)
{
    __shared__ __align__(16) f16 As0[128][40];
    __shared__ __align__(16) f16 As1[128][40];
    __shared__ __align__(16) f16 Bs0[64][40];
    __shared__ __align__(16) f16 Bs1[64][40];
    const int tid = threadIdx.x;
    const int wave = tid >> 6, lane = tid & 63;
    const int r = lane & 15, g = lane >> 4;
    const int row0 = blockIdx.y * 128;
    const int col0 = blockIdx.x * 64;
    f32x4 accM[2][4] = {}, accC[2][4] = {};
    for (int k0 = 0; k0 < DM; k0 += 32) {
        for (int idx = tid; idx < 128 * 4; idx += 256) {
            int row = idx >> 2, c = idx & 3;
            size_t src = (size_t)(row0 + row) * DM + k0 + c * 8;
            *(f16x8*)&As0[row][c * 8] = *(const f16x8*)(A0 + src);
            *(f16x8*)&As1[row][c * 8] = *(const f16x8*)(A1 + src);
        }
        for (int idx = tid; idx < 64 * 4; idx += 256) {
            int row = idx >> 2, c = idx & 3;
            size_t src = (size_t)(col0 + row) * DM + k0 + c * 8;
            *(f16x8*)&Bs0[row][c * 8] = *(const f16x8*)(B0 + src);
            *(f16x8*)&Bs1[row][c * 8] = *(const f16x8*)(B1 + src);
        }
        __syncthreads();
        f16x8 a0[2], a1[2], b0[4], b1[4];
#pragma unroll
        for (int rf = 0; rf < 2; ++rf) {
            a0[rf] = *(const f16x8*)&As0[wave * 32 + rf * 16 + r][g * 8];
            a1[rf] = *(const f16x8*)&As1[wave * 32 + rf * 16 + r][g * 8];
        }
#pragma unroll
        for (int cf = 0; cf < 4; ++cf) {
            b0[cf] = *(const f16x8*)&Bs0[cf * 16 + r][g * 8];
            b1[cf] = *(const f16x8*)&Bs1[cf * 16 + r][g * 8];
        }
#pragma unroll
        for (int rf = 0; rf < 2; ++rf)
#pragma unroll
            for (int cf = 0; cf < 4; ++cf) {
                accM[rf][cf] = MFMA16(a0[rf], b0[cf], accM[rf][cf]);
                accC[rf][cf] = MFMA16(a0[rf], b1[cf], accC[rf][cf]);
                accC[rf][cf] = MFMA16(a1[rf], b0[cf], accC[rf][cf]);
            }
        __syncthreads();
    }
#pragma unroll
    for (int rf = 0; rf < 2; ++rf)
#pragma unroll
        for (int cf = 0; cf < 4; ++cf) {
            int col = col0 + cf * 16 + r;
            int head = col / DH;
            int c = col - head * DH;
            int ks = c >> 5, ki = c & 31;
#pragma unroll
            for (int j = 0; j < 4; ++j) {
                int row = row0 + wave * 32 + rf * 16 + g * 4 + j;
                float v = (accM[rf][cf][j] + accC[rf][cf][j] * INV_RSPLIT) * scl;
                f16 h0 = (f16)v;
                float res = (v - (float)h0) * RSPLIT;
                size_t addr = qkAddr(head, row, ks, ki);
                Qt0[addr] = h0;
                Qt1[addr] = (f16)res;
            }
        }
}

// ---------- LDS-tiled bf16 MFMA GEMM; mode 0 = fp32 flat, 2 = Vp tiled -------
__global__ __launch_bounds__(256) void gemm_bf16_lds(
    const ushort_t* __restrict__ A, const ushort_t* __restrict__ BT,
    const float* __restrict__ bias, void* __restrict__ C, int mode,
    int Nn, int K)
{
    __shared__ __align__(16) ushort_t As[128][40];
    __shared__ __align__(16) ushort_t Bs[64][40];
    const int tid = threadIdx.x;
    const int wave = tid >> 6, lane = tid & 63;
    const int r = lane & 15, g = lane >> 4;
    const int row0 = blockIdx.y * 128;
    const int col0 = blockIdx.x * 64;
    f32x4 acc[2][4] = {};
    for (int k0 = 0; k0 < K; k0 += 32) {
        for (int idx = tid; idx < 128 * 4; idx += 256) {
            int row = idx >> 2, c = idx & 3;
            *(bf16x8*)&As[row][c * 8] = *(const bf16x8*)(A + (size_t)(row0 + row) * K + k0 + c * 8);
        }
        for (int idx = tid; idx < 64 * 4; idx += 256) {
            int row = idx >> 2, c = idx & 3;
            *(bf16x8*)&Bs[row][c * 8] = *(const bf16x8*)(BT + (size_t)(col0 + row) * K + k0 + c * 8);
        }
        __syncthreads();
        bf16x8 a[2], b[4];
#pragma unroll
        for (int rf = 0; rf < 2; ++rf)
            a[rf] = *(const bf16x8*)&As[wave * 32 + rf * 16 + r][g * 8];
#pragma unroll
        for (int cf = 0; cf < 4; ++cf)
            b[cf] = *(const bf16x8*)&Bs[cf * 16 + r][g * 8];
#pragma unroll
        for (int rf = 0; rf < 2; ++rf)
#pragma unroll
            for (int cf = 0; cf < 4; ++cf)
                acc[rf][cf] = MFMABF(a[rf], b[cf], acc[rf][cf]);
        __syncthreads();
    }
#pragma unroll
    for (int rf = 0; rf < 2; ++rf)
#pragma unroll
        for (int cf = 0; cf < 4; ++cf) {
            int col = col0 + cf * 16 + r;
            float bv = bias ? bias[col] : 0.f;
#pragma unroll
            for (int j = 0; j < 4; ++j) {
                int row = row0 + wave * 32 + rf * 16 + g * 4 + j;
                float vv = acc[rf][cf][j] + bv;
                if (mode == 2) {
                    int head = col / DH;
                    int d = col - head * DH;
                    size_t addr = (((size_t)head * 128 + (row >> 5)) * 80 + d) * 32 + (row & 31);
                    ((ushort_t*)C)[addr] = f2b(vv);
                } else {
                    ((float*)C)[(size_t)row * Nn + col] = vv;
                }
            }
        }
}

// ---------- pass A: rowsum + PV, swapped-operand QK (round-12 version) -------
__global__ __launch_bounds__(256) void rowsum_pv(
    const f16* __restrict__ Qt0, const f16* __restrict__ Qt1,
    const f16* __restrict__ Kt0, const f16* __restrict__ Kt1,
    const ushort_t* __restrict__ Vp,
    float* __restrict__ invs, ushort_t* __restrict__ otmpb)
{
    __shared__ __align__(16) f16 KL[2][6144];   // [plane][12 tiles of 512]
    const int tid = threadIdx.x;
    const int wv = tid >> 6, lane = tid & 63;
    const int r = lane & 15, g = lane >> 4;
    const int h = blockIdx.y;
    const int rowblk = blockIdx.x * 4 + wv;
    // Q fragments (used as the B operand of the swapped MFMA)
    f16x8 a0[3], a1[3];
#pragma unroll
    for (int ks = 0; ks < 3; ++ks) {
        size_t o = ((((size_t)h * 256 + rowblk) * 3 + ks) * 16) * 32 + r * 32 + g * 8;
        a0[ks] = *(const f16x8*)(Qt0 + o);
        a1[ks] = *(const f16x8*)(Qt1 + o);
    }
    // permuted per-lane K read columns: c32 = (r>>2)*8 + cfp*4 + (r&3)
    const int c32p0 = ((r >> 2) << 3) + (r & 3);
    float rs = 0.f;
    f32x4 oacc[5] = {};
    for (int ct = 0; ct < 64; ++ct) {
        __syncthreads();
        const size_t ctBase = ((size_t)h * 256 + ct * 4) * 1536;
#pragma unroll
        for (int s = 0; s < 6; ++s) {
            int wc = s * 4 + wv;             // 0..23 wave-chunks of 1024B
            int plane = wc >= 12;
            int cip = wc - plane * 12;
            const f16* src = (plane ? Kt1 : Kt0) + ctBase + cip * 512 + lane * 8;
            *(f16x8*)&KL[plane][cip * 512 + lane * 8] = *(const f16x8*)src;
        }
        __syncthreads();
        f32x4 accM[4] = {}, accC[4] = {};
#pragma unroll
        for (int ks = 0; ks < 3; ++ks) {
#pragma unroll
            for (int group = 0; group < 2; ++group) {
#pragma unroll
                for (int cfp = 0; cfp < 2; ++cfp) {
                    const int c32 = c32p0 + cfp * 4;
                    const int off = (((group * 2 + (c32 >> 4)) * 3 + ks) << 9)
                                  + ((c32 & 15) << 5) + (g << 3);
                    f16x8 b0 = *(const f16x8*)&KL[0][off];
                    f16x8 b1 = *(const f16x8*)&KL[1][off];
                    const int cf = group * 2 + cfp;
                    accM[cf] = MFMA16(b0, a0[ks], accM[cf]);
                    accC[cf] = MFMA16(b1, a0[ks], accC[cf]);
                    accC[cf] = MFMA16(b0, a1[ks], accC[cf]);
                }
            }
        }
        // exp -> rs + in-register bf16 pack -> PV
        const int kt0 = ct * 2;
#pragma unroll
        for (int group = 0; group < 2; ++group) {
            bf16x8 pa;
#pragma unroll
            for (int cfp = 0; cfp < 2; ++cfp) {
                const int cf = group * 2 + cfp;
#pragma unroll
                for (int j = 0; j < 4; ++j) {
                    float ev = __expf(accM[cf][j] + accC[cf][j] * INV_RSPLIT);
                    rs += ev;
                    pa[cfp * 4 + j] = (short)f2b(ev);
                }
            }
#pragma unroll
            for (int t = 0; t < 5; ++t) {
                int col = t * 16 + r;
                size_t vo = (((size_t)h * 128 + kt0 + group) * 80 + col) * 32 + g * 8;
                bf16x8 b = *(const bf16x8*)(Vp + vo);
                oacc[t] = MFMABF(pa, b, oacc[t]);
            }
        }
    }
    // rs is per-lane partial for q-row r; reduce over the 4 g-groups
    rs += __shfl_xor(rs, 16);
    rs += __shfl_xor(rs, 32);
    const float inv = 1.0f / rs;
    if (g == 0)
        invs[(size_t)h * NT + rowblk * 16 + r] = inv;
    float invq[4];
#pragma unroll
    for (int j = 0; j < 4; ++j) invq[j] = __shfl(inv, g * 4 + j);
#pragma unroll
    for (int t = 0; t < 5; ++t) {
        int col = t * 16 + r;
        if (col < DH) {
#pragma unroll
            for (int j = 0; j < 4; ++j) {
                int row = rowblk * 16 + g * 4 + j;
                otmpb[(size_t)row * DM + h * DH + col] = f2b(oacc[t][j] * invq[j]);
            }
        }
    }
}

// ---------- pass B: attn head-sum; head-outer; 16 col-slices of 256 ----------
// grid (ACSB, NT/64). Q loaded once per head; 256-col attn strip in registers.
__global__ __launch_bounds__(256) void attn_sum(
    const f16* __restrict__ Qt0, const f16* __restrict__ Qt1,
    const f16* __restrict__ Kt0, const f16* __restrict__ Kt1,
    const float* __restrict__ invs, float* __restrict__ attn)
{
    __shared__ __align__(16) f16 KL[2][6144];   // [plane][12 tiles of 512]
    const int tid = threadIdx.x;
    const int wr = tid >> 6, lane = tid & 63;
    const int r = lane & 15, g = lane >> 4;
    const int cs = blockIdx.x;
    const int rowblk = blockIdx.y * 4 + wr;
    const int row0 = rowblk * 16;
    const int cb0 = cs * 16;                    // colblk base (256 cols/slice)
    float aacc[4][4][4] = {};                   // [ct][cf][j]
    for (int h = 0; h < NH; ++h) {
        // Q fragments once per head
        f16x8 a0[3], a1[3];
#pragma unroll
        for (int ks = 0; ks < 3; ++ks) {
            size_t o = ((((size_t)h * 256 + rowblk) * 3 + ks) * 16) * 32 + r * 32 + g * 8;
            a0[ks] = *(const f16x8*)(Qt0 + o);
            a1[ks] = *(const f16x8*)(Qt1 + o);
        }
        float vinv[4];
#pragma unroll
        for (int j = 0; j < 4; ++j)
            vinv[j] = invs[(size_t)h * NT + row0 + g * 4 + j];
#pragma unroll
        for (int ct = 0; ct < 4; ++ct) {
            __syncthreads();
            const size_t ctBase = ((size_t)h * 256 + cb0 + ct * 4) * 1536;
#pragma unroll
            for (int s = 0; s < 6; ++s) {
                int wc = s * 4 + wr;            // 0..23 wave-chunks of 1024B
                int plane = wc >= 12;
                int cip = wc - plane * 12;
                const f16* src = (plane ? Kt1 : Kt0) + ctBase + cip * 512 + lane * 8;
                *(f16x8*)&KL[plane][cip * 512 + lane * 8] = *(const f16x8*)src;
            }
            __syncthreads();
            f32x4 accM[4] = {}, accC[4] = {};
#pragma unroll
            for (int ks = 0; ks < 3; ++ks) {
#pragma unroll
                for (int cf = 0; cf < 4; ++cf) {
                    f16x8 b0 = *(const f16x8*)&KL[0][(cf * 3 + ks) * 512 + r * 32 + g * 8];
                    f16x8 b1 = *(const f16x8*)&KL[1][(cf * 3 + ks) * 512 + r * 32 + g * 8];
                    accM[cf] = MFMA16(a0[ks], b0, accM[cf]);
                    accC[cf] = MFMA16(a0[ks], b1, accC[cf]);
                    accC[cf] = MFMA16(a1[ks], b0, accC[cf]);
                }
            }
#pragma unroll
            for (int cf = 0; cf < 4; ++cf) {
#pragma unroll
                for (int j = 0; j < 4; ++j) {
                    float p = __expf(accM[cf][j] + accC[cf][j] * INV_RSPLIT) * vinv[j];
                    aacc[ct][cf][j] += p;
                }
            }
        }
    }
    // write attn once (no rmw)
#pragma unroll
    for (int ct = 0; ct < 4; ++ct) {
        const int colbase = cs * 256 + ct * 64;
#pragma unroll
        for (int cf = 0; cf < 4; ++cf) {
#pragma unroll
            for (int j = 0; j < 4; ++j) {
                int row = row0 + g * 4 + j;
                attn[(size_t)row * NT + colbase + cf * 16 + r] = aacc[ct][cf][j] * 0.0625f;
            }
        }
    }
}

// ---------- pagerank power iteration (fp32, unchanged) -----------------------
__global__ __launch_bounds__(256) void init_dist(float* __restrict__ d)
{
    int t = blockIdx.x * 256 + threadIdx.x;
    if (t < NT) d[t] = 1.0f / NT;
}

__global__ __launch_bounds__(256) void power_a(
    const float* __restrict__ attn, const float* __restrict__ din,
    float* __restrict__ part)
{
    int j = blockIdx.x * 256 + threadIdx.x;
    int i0 = blockIdx.y * 128;
    float acc = 0.f;
    for (int i = i0; i < i0 + 128; ++i)
        acc += din[i] * attn[(size_t)i * NT + j];
    part[(size_t)blockIdx.y * NT + j] = acc;
}

__global__ __launch_bounds__(256) void power_b(
    const float* __restrict__ part, float* __restrict__ dout)
{
    int j = blockIdx.x * 256 + threadIdx.x;
    float acc = 0.f;
    for (int ib = 0; ib < 32; ++ib) acc += part[(size_t)ib * NT + j];
    dout[j] = acc;
}

// ---------- top-k: tiled rank counting (deterministic int atomics) -----------
__global__ __launch_bounds__(256) void rank_count(
    const float* __restrict__ imp, int* __restrict__ rank, int* __restrict__ prank)
{
    __shared__ float sj[256];
    const int tid = threadIdx.x;
    const int jb = blockIdx.y * 256;
    sj[tid] = imp[jb + tid];
    __syncthreads();
    const int i = blockIdx.x * 256 + tid;
    const float mv = imp[i];
    int r = 0, rp = 0;
    for (int jj = 0; jj < 256; ++jj) {
        float vj = sj[jj];
        int j = jb + jj;
        int tie_low = (vj == mv) && (j < i);
        r  += (vj > mv) || tie_low;
        rp += (vj < mv) || tie_low;
    }
    atomicAdd(&rank[i], r);
    atomicAdd(&prank[i], rp);
}

__global__ __launch_bounds__(256) void scatter_topk2(
    const int* __restrict__ rank, const int* __restrict__ prank,
    float* __restrict__ out_imps, float* __restrict__ out_prune,
    int* __restrict__ imp_rows, int* __restrict__ prune_cols)
{
    __shared__ unsigned char fr[NT];
    __shared__ unsigned char fp[NT];
    __shared__ int sr[256], sp[256];
    const int tid = threadIdx.x;
    for (int t = tid; t < NT; t += 256) {
        fr[t] = rank[t] < KRET;
        fp[t] = prank[t] < NPR;
    }
    __syncthreads();
    const int base = tid * 16;
    int cr = 0, cp = 0;
#pragma unroll
    for (int e = 0; e < 16; ++e) { cr += fr[base + e]; cp += fp[base + e]; }
    sr[tid] = cr; sp[tid] = cp;
    __syncthreads();
    int pr = 0, pp = 0;
    for (int j = 0; j < tid; ++j) { pr += sr[j]; pp += sp[j]; }
#pragma unroll
    for (int e = 0; e < 16; ++e) {
        int i = base + e;
        if (fr[i]) { out_imps[pr] = (float)i; imp_rows[pr] = i; ++pr; }
        if (fp[i]) { out_prune[pp] = (float)i; prune_cols[pp] = i; ++pp; }
    }
}

__global__ __launch_bounds__(256) void argmax_part(
    const float* __restrict__ attn, const int* __restrict__ imp_rows,
    float* __restrict__ pbest, int* __restrict__ pbi)
{
    __shared__ int rows[CHUNK];
    const int tid = threadIdx.x;
    const int rc = blockIdx.y;
    const int r0 = rc * CHUNK;
    const int nr = min(KRET - r0, CHUNK);
    for (int t = tid; t < nr; t += 256) rows[t] = imp_rows[r0 + t];
    __syncthreads();
    const int j = blockIdx.x * 256 + tid;
    float best = -INFINITY;
    int bi = 0;
    for (int rr = 0; rr < nr; ++rr) {
        float val = attn[(size_t)rows[rr] * NT + j];
        if (val > best) { best = val; bi = r0 + rr; }
    }
    pbest[(size_t)rc * NT + j] = best;
    pbi[(size_t)rc * NT + j] = bi;
}

__global__ __launch_bounds__(256) void argmax_red(
    const float* __restrict__ pbest, const int* __restrict__ pbi,
    int* __restrict__ maxind)
{
    const int j = blockIdx.x * 256 + threadIdx.x;
    float best = -INFINITY;
    int bi = 0;
#pragma unroll
    for (int rc = 0; rc < 8; ++rc) {
        float val = pbest[(size_t)rc * NT + j];
        if (val > best) { best = val; bi = pbi[(size_t)rc * NT + j]; }
    }
    maxind[j] = bi;
}

__global__ __launch_bounds__(256) void finalize(
    const float* __restrict__ dist, const int* __restrict__ prune_cols,
    const int* __restrict__ maxind, float* __restrict__ out_imp,
    float* __restrict__ out_simi)
{
    int t = blockIdx.x * 256 + threadIdx.x;
    if (t < NT) out_imp[t] = dist[t];
    if (t < NPR) out_simi[t] = (float)maxind[prune_cols[t]];
}

extern "C" void kernel_launch(void* const* d_in, const int* in_sizes, int n_in,
                              void* d_out, int out_size, void* d_ws, size_t ws_size,
                              hipStream_t stream)
{
    const float* x  = (const float*)d_in[0];
    const float* Wq = (const float*)d_in[1];
    const float* Wk = (const float*)d_in[2];
    const float* Wv = (const float*)d_in[3];
    const float* Wo = (const float*)d_in[4];
    const float* bo = (const float*)d_in[5];
    float* out = (float*)d_out;

    const size_t QKT_EL = (size_t)NH * 256 * 3 * 16 * 32;   // 6.29M f16 per plane
    const size_t VP_EL  = (size_t)NH * 128 * 80 * 32;       // 5.24M bf16

    // ---- workspace layout (float units) ----
    float* ws = (float*)d_ws;
    size_t off = 0;
    float* attn = ws + off; off += (size_t)NT * NT;
    f16* Qt0 = (f16*)(ws + off); off += QKT_EL / 2;
    f16* Qt1 = (f16*)(ws + off); off += QKT_EL / 2;
    f16* Kt0 = (f16*)(ws + off); off += QKT_EL / 2;
    f16* Kt1 = (f16*)(ws + off); off += QKT_EL / 2;
    ushort_t* Vp = (ushort_t*)(ws + off); off += VP_EL / 2;
    size_t zero_floats = 4 * (QKT_EL / 2) + VP_EL / 2;      // Qt0..Vp contiguous
    ushort_t* otmpb = (ushort_t*)(ws + off); off += ((size_t)NT * DM) / 2;
    f16* X0 = (f16*)(ws + off); f16* X1 = X0 + (size_t)NT * DM; off += (size_t)NT * DM;
    f16* T0 = (f16*)(ws + off); f16* T1 = T0 + (size_t)DM * DM; off += (size_t)DM * DM;
    ushort_t* Wslot = (ushort_t*)(ws + off); off += ((size_t)DM * DM) / 2;
    float* invs    = ws + off; off += (size_t)NH * NT;
    float* pbest   = ws + off; off += 8 * NT;
    int*   pbi     = (int*)(ws + off); off += 8 * NT;
    float* dist0 = ws + off; off += NT;
    float* dist1 = ws + off; off += NT;
    float* partial = ws + off; off += 32 * NT;
    int* rank      = (int*)(ws + off); off += NT;
    int* prank     = (int*)(ws + off); off += NT;
    int* imp_rows  = (int*)(ws + off); off += 2048;
    int* prune_cols= (int*)(ws + off); off += 2560;
    int* maxind    = (int*)(ws + off); off += NT;

    // setup-only alias inside attn region (dead before attn_sum writes)
    ushort_t* xb = (ushort_t*)attn;

    // output layout
    float* out_out   = out;
    float* out_imp   = out + (size_t)NT * DM;
    float* out_imps  = out_imp + NT;
    float* out_prune = out_imps + KRET;
    float* out_simi  = out_prune + NPR;

    // ---- setup ----
    hipMemsetAsync(Qt0, 0, zero_floats * sizeof(float), stream);  // zero-pad tiles
    split_x<<<2048, 256, 0, stream>>>(x, X0, X1, xb, NT * DM);

    dim3 gT(DM / 32, DM / 32);
    dim3 gP(DM / 64, NT / 128);
    transposeW_split<<<gT, 256, 0, stream>>>(Wq, T0, T1, DM);
    proj_split3<<<gP, 256, 0, stream>>>(X0, X1, T0, T1, Qt0, Qt1, SCALE);
    transposeW_split<<<gT, 256, 0, stream>>>(Wk, T0, T1, DM);
    proj_split3<<<gP, 256, 0, stream>>>(X0, X1, T0, T1, Kt0, Kt1, 1.0f);

    transposeW_bf16<<<gT, 256, 0, stream>>>(Wv, Wslot, DM);
    gemm_bf16_lds<<<gP, 256, 0, stream>>>(xb, Wslot, nullptr, Vp, 2, DM, DM);

    // ---- pass A: rowsums + PV (swapped-operand QK, register-resident P) ----
    rowsum_pv<<<dim3(NT / 64, NH), 256, 0, stream>>>(Qt0, Qt1, Kt0, Kt1, Vp,
                                                     invs, otmpb);

    // ---- pass B: attn head-sum, head-outer, 16 col-slices, write-once ----
    attn_sum<<<dim3(ACSB, NT / 64), 256, 0, stream>>>(Qt0, Qt1, Kt0, Kt1, invs, attn);

    // ---- output projection ----
    transposeW_bf16<<<gT, 256, 0, stream>>>(Wo, Wslot, DM);
    gemm_bf16_lds<<<gP, 256, 0, stream>>>(otmpb, Wslot, bo, out_out, 0, DM, DM);

    // ---- pagerank ----
    init_dist<<<16, 256, 0, stream>>>(dist0);
    float* da = dist0;
    float* db = dist1;
    for (int it = 0; it < 5; ++it) {
        power_a<<<dim3(16, 32), 256, 0, stream>>>(attn, da, partial);
        power_b<<<16, 256, 0, stream>>>(partial, db);
        float* t = da; da = db; db = t;
    }

    // ---- top-k ----
    hipMemsetAsync(rank, 0, 2 * NT * sizeof(int), stream);
    rank_count<<<dim3(16, 16), 256, 0, stream>>>(da, rank, prank);
    scatter_topk2<<<1, 256, 0, stream>>>(rank, prank, out_imps, out_prune,
                                         imp_rows, prune_cols);
    argmax_part<<<dim3(16, 8), 256, 0, stream>>>(attn, imp_rows, pbest, pbi);
    argmax_red<<<16, 256, 0, stream>>>(pbest, pbi, maxind);
    finalize<<<16, 256, 0, stream>>>(da, prune_cols, maxind, out_imp, out_simi);
}

// Round 15
// 843.340 us; speedup vs baseline: 1.4117x; 1.1029x over previous
//
#include <hip/hip_runtime.h>
#include <math.h>

#define NT 4096
#define DM 1152
#define NH 16
#define DH 72
#define KRET 1638
#define NPR (NT - KRET)
#define ACSB 32
#define CHUNK 205
#define SCALE 0.11785113019775793f
#define RSPLIT 2048.0f
#define INV_RSPLIT 4.8828125e-4f

typedef __attribute__((ext_vector_type(8))) short bf16x8;
typedef _Float16 f16;
typedef __attribute__((ext_vector_type(8))) _Float16 f16x8;
typedef __attribute__((ext_vector_type(4))) float f32x4;
typedef unsigned short ushort_t;

#define MFMA16(a, b, c) __builtin_amdgcn_mfma_f32_16x16x32_f16(a, b, c, 0, 0, 0)
#define MFMABF(a, b, c) __builtin_amdgcn_mfma_f32_16x16x32_bf16(a, b, c, 0, 0, 0)

__device__ inline ushort_t f2b(float f) {
    union { float f; unsigned int u; } v; v.f = f;
    unsigned int u = v.u;
    return (ushort_t)((u + 0x7FFFu + ((u >> 16) & 1u)) >> 16);
}

__device__ inline float b2f(ushort_t u) {
    union { unsigned int u; float f; } v; v.u = ((unsigned int)u) << 16;
    return v.f;
}

// tiled Q/K address: [NH][rowblk 256][ks 3][r 16][ki 32]
__device__ inline size_t qkAddr(int h, int row, int ks, int ki) {
    return ((((size_t)h * 256 + (row >> 4)) * 3 + ks) * 16 + (row & 15)) * 32 + ki;
}

// ---------- split x into fp16 hi/lo(x2048) planes + bf16 copy ----------------
__global__ __launch_bounds__(256) void split_x(
    const float* __restrict__ in, f16* __restrict__ x0, f16* __restrict__ x1,
    ushort_t* __restrict__ xb, int nElem)
{
    int i = blockIdx.x * 256 + threadIdx.x;
    int stride = gridDim.x * 256;
    for (; i < nElem; i += stride) {
        float v = in[i];
        f16 h0 = (f16)v;
        float res = (v - (float)h0) * RSPLIT;
        x0[i] = h0;
        x1[i] = (f16)res;
        xb[i] = f2b(v);
    }
}

__global__ __launch_bounds__(256) void transposeW_split(
    const float* __restrict__ W, f16* __restrict__ T0, f16* __restrict__ T1, int n)
{
    __shared__ float t[32][33];
    int bx = blockIdx.x * 32, by = blockIdx.y * 32;
    int tx = threadIdx.x & 31, ty = threadIdx.x >> 5;
    for (int i = ty; i < 32; i += 8)
        t[i][tx] = W[(size_t)(by + i) * n + bx + tx];
    __syncthreads();
    for (int i = ty; i < 32; i += 8) {
        float v = t[tx][i];
        f16 h0 = (f16)v;
        float res = (v - (float)h0) * RSPLIT;
        T0[(size_t)(bx + i) * n + by + tx] = h0;
        T1[(size_t)(bx + i) * n + by + tx] = (f16)res;
    }
}

__global__ __launch_bounds__(256) void transposeW_bf16(
    const float* __restrict__ W, ushort_t* __restrict__ WT, int n)
{
    __shared__ ushort_t t[32][33];
    int bx = blockIdx.x * 32, by = blockIdx.y * 32;
    int tx = threadIdx.x & 31, ty = threadIdx.x >> 5;
    for (int i = ty; i < 32; i += 8)
        t[i][tx] = f2b(W[(size_t)(by + i) * n + bx + tx]);
    __syncthreads();
    for (int i = ty; i < 32; i += 8)
        WT[(size_t)(bx + i) * n + by + tx] = t[tx][i];
}

// ---------- LDS-tiled split projection -> MFMA-tiled per-head output ---------
__global__ __launch_bounds__(256) void proj_split3(
    const f16* __restrict__ A0, const f16* __restrict__ A1,
    const f16* __restrict__ B0, const f16* __restrict__ B1,
    f16* __restrict__ Qt0, f16* __restrict__ Qt1, float scl)
{
    __shared__ __align__(16) f16 As0[128][40];
    __shared__ __align__(16) f16 As1[128][40];
    __shared__ __align__(16) f16 Bs0[64][40];
    __shared__ __align__(16) f16 Bs1[64][40];
    const int tid = threadIdx.x;
    const int wave = tid >> 6, lane = tid & 63;
    const int r = lane & 15, g = lane >> 4;
    const int row0 = blockIdx.y * 128;
    const int col0 = blockIdx.x * 64;
    f32x4 accM[2][4] = {}, accC[2][4] = {};
    for (int k0 = 0; k0 < DM; k0 += 32) {
        for (int idx = tid; idx < 128 * 4; idx += 256) {
            int row = idx >> 2, c = idx & 3;
            size_t src = (size_t)(row0 + row) * DM + k0 + c * 8;
            *(f16x8*)&As0[row][c * 8] = *(const f16x8*)(A0 + src);
            *(f16x8*)&As1[row][c * 8] = *(const f16x8*)(A1 + src);
        }
        for (int idx = tid; idx < 64 * 4; idx += 256) {
            int row = idx >> 2, c = idx & 3;
            size_t src = (size_t)(col0 + row) * DM + k0 + c * 8;
            *(f16x8*)&Bs0[row][c * 8] = *(const f16x8*)(B0 + src);
            *(f16x8*)&Bs1[row][c * 8] = *(const f16x8*)(B1 + src);
        }
        __syncthreads();
        f16x8 a0[2], a1[2], b0[4], b1[4];
#pragma unroll
        for (int rf = 0; rf < 2; ++rf) {
            a0[rf] = *(const f16x8*)&As0[wave * 32 + rf * 16 + r][g * 8];
            a1[rf] = *(const f16x8*)&As1[wave * 32 + rf * 16 + r][g * 8];
        }
#pragma unroll
        for (int cf = 0; cf < 4; ++cf) {
            b0[cf] = *(const f16x8*)&Bs0[cf * 16 + r][g * 8];
            b1[cf] = *(const f16x8*)&Bs1[cf * 16 + r][g * 8];
        }
#pragma unroll
        for (int rf = 0; rf < 2; ++rf)
#pragma unroll
            for (int cf = 0; cf < 4; ++cf) {
                accM[rf][cf] = MFMA16(a0[rf], b0[cf], accM[rf][cf]);
                accC[rf][cf] = MFMA16(a0[rf], b1[cf], accC[rf][cf]);
                accC[rf][cf] = MFMA16(a1[rf], b0[cf], accC[rf][cf]);
            }
        __syncthreads();
    }
#pragma unroll
    for (int rf = 0; rf < 2; ++rf)
#pragma unroll
        for (int cf = 0; cf < 4; ++cf) {
            int col = col0 + cf * 16 + r;
            int head = col / DH;
            int c = col - head * DH;
            int ks = c >> 5, ki = c & 31;
#pragma unroll
            for (int j = 0; j < 4; ++j) {
                int row = row0 + wave * 32 + rf * 16 + g * 4 + j;
                float v = (accM[rf][cf][j] + accC[rf][cf][j] * INV_RSPLIT) * scl;
                f16 h0 = (f16)v;
                float res = (v - (float)h0) * RSPLIT;
                size_t addr = qkAddr(head, row, ks, ki);
                Qt0[addr] = h0;
                Qt1[addr] = (f16)res;
            }
        }
}

// ---------- LDS-tiled bf16 MFMA GEMM; mode 0 = fp32 flat, 2 = Vp tiled -------
__global__ __launch_bounds__(256) void gemm_bf16_lds(
    const ushort_t* __restrict__ A, const ushort_t* __restrict__ BT,
    const float* __restrict__ bias, void* __restrict__ C, int mode,
    int Nn, int K)
{
    __shared__ __align__(16) ushort_t As[128][40];
    __shared__ __align__(16) ushort_t Bs[64][40];
    const int tid = threadIdx.x;
    const int wave = tid >> 6, lane = tid & 63;
    const int r = lane & 15, g = lane >> 4;
    const int row0 = blockIdx.y * 128;
    const int col0 = blockIdx.x * 64;
    f32x4 acc[2][4] = {};
    for (int k0 = 0; k0 < K; k0 += 32) {
        for (int idx = tid; idx < 128 * 4; idx += 256) {
            int row = idx >> 2, c = idx & 3;
            *(bf16x8*)&As[row][c * 8] = *(const bf16x8*)(A + (size_t)(row0 + row) * K + k0 + c * 8);
        }
        for (int idx = tid; idx < 64 * 4; idx += 256) {
            int row = idx >> 2, c = idx & 3;
            *(bf16x8*)&Bs[row][c * 8] = *(const bf16x8*)(BT + (size_t)(col0 + row) * K + k0 + c * 8);
        }
        __syncthreads();
        bf16x8 a[2], b[4];
#pragma unroll
        for (int rf = 0; rf < 2; ++rf)
            a[rf] = *(const bf16x8*)&As[wave * 32 + rf * 16 + r][g * 8];
#pragma unroll
        for (int cf = 0; cf < 4; ++cf)
            b[cf] = *(const bf16x8*)&Bs[cf * 16 + r][g * 8];
#pragma unroll
        for (int rf = 0; rf < 2; ++rf)
#pragma unroll
            for (int cf = 0; cf < 4; ++cf)
                acc[rf][cf] = MFMABF(a[rf], b[cf], acc[rf][cf]);
        __syncthreads();
    }
#pragma unroll
    for (int rf = 0; rf < 2; ++rf)
#pragma unroll
        for (int cf = 0; cf < 4; ++cf) {
            int col = col0 + cf * 16 + r;
            float bv = bias ? bias[col] : 0.f;
#pragma unroll
            for (int j = 0; j < 4; ++j) {
                int row = row0 + wave * 32 + rf * 16 + g * 4 + j;
                float vv = acc[rf][cf][j] + bv;
                if (mode == 2) {
                    int head = col / DH;
                    int d = col - head * DH;
                    size_t addr = (((size_t)head * 128 + (row >> 5)) * 80 + d) * 32 + (row & 31);
                    ((ushort_t*)C)[addr] = f2b(vv);
                } else {
                    ((float*)C)[(size_t)row * Nn + col] = vv;
                }
            }
        }
}

// ---------- pass A: rowsum + PV, swapped-operand QK, ct-split x2 -------------
// grid (NT/64, NH, 2). Each half: 32 ct-steps; partial rs (fp32) + PV (bf16).
__global__ __launch_bounds__(256) void rowsum_pv(
    const f16* __restrict__ Qt0, const f16* __restrict__ Qt1,
    const f16* __restrict__ Kt0, const f16* __restrict__ Kt1,
    const ushort_t* __restrict__ Vp,
    float* __restrict__ rsPart, ushort_t* __restrict__ part_pv)
{
    __shared__ __align__(16) f16 KL[2][6144];   // [plane][12 tiles of 512]
    const int tid = threadIdx.x;
    const int wv = tid >> 6, lane = tid & 63;
    const int r = lane & 15, g = lane >> 4;
    const int h = blockIdx.y;
    const int half = blockIdx.z;
    const int rowblk = blockIdx.x * 4 + wv;
    // Q fragments (used as the B operand of the swapped MFMA)
    f16x8 a0[3], a1[3];
#pragma unroll
    for (int ks = 0; ks < 3; ++ks) {
        size_t o = ((((size_t)h * 256 + rowblk) * 3 + ks) * 16) * 32 + r * 32 + g * 8;
        a0[ks] = *(const f16x8*)(Qt0 + o);
        a1[ks] = *(const f16x8*)(Qt1 + o);
    }
    // permuted per-lane K read columns: c32 = (r>>2)*8 + cfp*4 + (r&3)
    const int c32p0 = ((r >> 2) << 3) + (r & 3);
    float rs = 0.f;
    f32x4 oacc[5] = {};
    for (int ct = half * 32; ct < half * 32 + 32; ++ct) {
        __syncthreads();
        const size_t ctBase = ((size_t)h * 256 + ct * 4) * 1536;
#pragma unroll
        for (int s = 0; s < 6; ++s) {
            int wc = s * 4 + wv;             // 0..23 wave-chunks of 1024B
            int plane = wc >= 12;
            int cip = wc - plane * 12;
            const f16* src = (plane ? Kt1 : Kt0) + ctBase + cip * 512 + lane * 8;
            *(f16x8*)&KL[plane][cip * 512 + lane * 8] = *(const f16x8*)src;
        }
        __syncthreads();
        f32x4 accM[4] = {}, accC[4] = {};
#pragma unroll
        for (int ks = 0; ks < 3; ++ks) {
#pragma unroll
            for (int group = 0; group < 2; ++group) {
#pragma unroll
                for (int cfp = 0; cfp < 2; ++cfp) {
                    const int c32 = c32p0 + cfp * 4;
                    const int off = (((group * 2 + (c32 >> 4)) * 3 + ks) << 9)
                                  + ((c32 & 15) << 5) + (g << 3);
                    f16x8 b0 = *(const f16x8*)&KL[0][off];
                    f16x8 b1 = *(const f16x8*)&KL[1][off];
                    const int cf = group * 2 + cfp;
                    accM[cf] = MFMA16(b0, a0[ks], accM[cf]);
                    accC[cf] = MFMA16(b1, a0[ks], accC[cf]);
                    accC[cf] = MFMA16(b0, a1[ks], accC[cf]);
                }
            }
        }
        // exp -> rs + in-register bf16 pack -> PV
        const int kt0 = ct * 2;
#pragma unroll
        for (int group = 0; group < 2; ++group) {
            bf16x8 pa;
#pragma unroll
            for (int cfp = 0; cfp < 2; ++cfp) {
                const int cf = group * 2 + cfp;
#pragma unroll
                for (int j = 0; j < 4; ++j) {
                    float ev = __expf(accM[cf][j] + accC[cf][j] * INV_RSPLIT);
                    rs += ev;
                    pa[cfp * 4 + j] = (short)f2b(ev);
                }
            }
#pragma unroll
            for (int t = 0; t < 5; ++t) {
                int col = t * 16 + r;
                size_t vo = (((size_t)h * 128 + kt0 + group) * 80 + col) * 32 + g * 8;
                bf16x8 b = *(const bf16x8*)(Vp + vo);
                oacc[t] = MFMABF(pa, b, oacc[t]);
            }
        }
    }
    // rs is per-lane partial for q-row r; reduce over the 4 g-groups
    rs += __shfl_xor(rs, 16);
    rs += __shfl_xor(rs, 32);
    if (g == 0)
        rsPart[((size_t)half * NH + h) * NT + rowblk * 16 + r] = rs;
    // unnormalized PV partial (bf16)
#pragma unroll
    for (int t = 0; t < 5; ++t) {
        int col = t * 16 + r;
        if (col < DH) {
#pragma unroll
            for (int j = 0; j < 4; ++j) {
                int row = rowblk * 16 + g * 4 + j;
                part_pv[(((size_t)half * NH + h) * NT + row) * DH + col] = f2b(oacc[t][j]);
            }
        }
    }
}

// ---------- combine rowsum/PV halves: invs + normalized otmpb ----------------
// grid (NH, NT/32), 256 threads.
__global__ __launch_bounds__(256) void pv_norm(
    const float* __restrict__ rsPart, const ushort_t* __restrict__ part_pv,
    float* __restrict__ invs, ushort_t* __restrict__ otmpb)
{
    __shared__ float sinv[32];
    const int h = blockIdx.x;
    const int row0 = blockIdx.y * 32;
    const int tid = threadIdx.x;
    if (tid < 32) {
        float rsA = rsPart[(size_t)h * NT + row0 + tid];
        float rsB = rsPart[((size_t)NH + h) * NT + row0 + tid];
        float inv = 1.0f / (rsA + rsB);
        sinv[tid] = inv;
        invs[(size_t)h * NT + row0 + tid] = inv;
    }
    __syncthreads();
    for (int e = tid; e < 32 * DH; e += 256) {
        int rr = e / DH, col = e - rr * DH;
        int row = row0 + rr;
        float a = b2f(part_pv[((size_t)h * NT + row) * DH + col]);
        float b = b2f(part_pv[(((size_t)NH + h) * NT + row) * DH + col]);
        otmpb[(size_t)row * DM + h * DH + col] = f2b((a + b) * sinv[rr]);
    }
}

// ---------- pass B: attn head-sum; head-outer; 32 col-slices of 128 ----------
__global__ __launch_bounds__(256) void attn_sum(
    const f16* __restrict__ Qt0, const f16* __restrict__ Qt1,
    const f16* __restrict__ Kt0, const f16* __restrict__ Kt1,
    const float* __restrict__ invs, float* __restrict__ attn)
{
    __shared__ __align__(16) f16 KL[2][6144];   // [plane][12 tiles of 512]
    const int tid = threadIdx.x;
    const int wr = tid >> 6, lane = tid & 63;
    const int r = lane & 15, g = lane >> 4;
    const int cs = blockIdx.x;
    const int rowblk = blockIdx.y * 4 + wr;
    const int row0 = rowblk * 16;
    const int cb0 = cs * 8;                     // colblk base (128 cols/slice)
    float aacc[2][4][4] = {};                   // [ct][cf][j]
    for (int h = 0; h < NH; ++h) {
        // Q fragments once per head
        f16x8 a0[3], a1[3];
#pragma unroll
        for (int ks = 0; ks < 3; ++ks) {
            size_t o = ((((size_t)h * 256 + rowblk) * 3 + ks) * 16) * 32 + r * 32 + g * 8;
            a0[ks] = *(const f16x8*)(Qt0 + o);
            a1[ks] = *(const f16x8*)(Qt1 + o);
        }
        float vinv[4];
#pragma unroll
        for (int j = 0; j < 4; ++j)
            vinv[j] = invs[(size_t)h * NT + row0 + g * 4 + j];
#pragma unroll
        for (int ct = 0; ct < 2; ++ct) {
            __syncthreads();
            const size_t ctBase = ((size_t)h * 256 + cb0 + ct * 4) * 1536;
#pragma unroll
            for (int s = 0; s < 6; ++s) {
                int wc = s * 4 + wr;            // 0..23 wave-chunks of 1024B
                int plane = wc >= 12;
                int cip = wc - plane * 12;
                const f16* src = (plane ? Kt1 : Kt0) + ctBase + cip * 512 + lane * 8;
                *(f16x8*)&KL[plane][cip * 512 + lane * 8] = *(const f16x8*)src;
            }
            __syncthreads();
            f32x4 accM[4] = {}, accC[4] = {};
#pragma unroll
            for (int ks = 0; ks < 3; ++ks) {
#pragma unroll
                for (int cf = 0; cf < 4; ++cf) {
                    f16x8 b0 = *(const f16x8*)&KL[0][(cf * 3 + ks) * 512 + r * 32 + g * 8];
                    f16x8 b1 = *(const f16x8*)&KL[1][(cf * 3 + ks) * 512 + r * 32 + g * 8];
                    accM[cf] = MFMA16(a0[ks], b0, accM[cf]);
                    accC[cf] = MFMA16(a0[ks], b1, accC[cf]);
                    accC[cf] = MFMA16(a1[ks], b0, accC[cf]);
                }
            }
#pragma unroll
            for (int cf = 0; cf < 4; ++cf) {
#pragma unroll
                for (int j = 0; j < 4; ++j) {
                    float p = __expf(accM[cf][j] + accC[cf][j] * INV_RSPLIT) * vinv[j];
                    aacc[ct][cf][j] += p;
                }
            }
        }
    }
    // write attn once (no rmw)
#pragma unroll
    for (int ct = 0; ct < 2; ++ct) {
        const int colbase = cs * 128 + ct * 64;
#pragma unroll
        for (int cf = 0; cf < 4; ++cf) {
#pragma unroll
            for (int j = 0; j < 4; ++j) {
                int row = row0 + g * 4 + j;
                attn[(size_t)row * NT + colbase + cf * 16 + r] = aacc[ct][cf][j] * 0.0625f;
            }
        }
    }
}

// ---------- pagerank power iteration (fp32, unchanged) -----------------------
__global__ __launch_bounds__(256) void init_dist(float* __restrict__ d)
{
    int t = blockIdx.x * 256 + threadIdx.x;
    if (t < NT) d[t] = 1.0f / NT;
}

__global__ __launch_bounds__(256) void power_a(
    const float* __restrict__ attn, const float* __restrict__ din,
    float* __restrict__ part)
{
    int j = blockIdx.x * 256 + threadIdx.x;
    int i0 = blockIdx.y * 128;
    float acc = 0.f;
    for (int i = i0; i < i0 + 128; ++i)
        acc += din[i] * attn[(size_t)i * NT + j];
    part[(size_t)blockIdx.y * NT + j] = acc;
}

__global__ __launch_bounds__(256) void power_b(
    const float* __restrict__ part, float* __restrict__ dout)
{
    int j = blockIdx.x * 256 + threadIdx.x;
    float acc = 0.f;
    for (int ib = 0; ib < 32; ++ib) acc += part[(size_t)ib * NT + j];
    dout[j] = acc;
}

// ---------- top-k: tiled rank counting (deterministic int atomics) -----------
__global__ __launch_bounds__(256) void rank_count(
    const float* __restrict__ imp, int* __restrict__ rank, int* __restrict__ prank)
{
    __shared__ float sj[256];
    const int tid = threadIdx.x;
    const int jb = blockIdx.y * 256;
    sj[tid] = imp[jb + tid];
    __syncthreads();
    const int i = blockIdx.x * 256 + tid;
    const float mv = imp[i];
    int r = 0, rp = 0;
    for (int jj = 0; jj < 256; ++jj) {
        float vj = sj[jj];
        int j = jb + jj;
        int tie_low = (vj == mv) && (j < i);
        r  += (vj > mv) || tie_low;
        rp += (vj < mv) || tie_low;
    }
    atomicAdd(&rank[i], r);
    atomicAdd(&prank[i], rp);
}

__global__ __launch_bounds__(256) void scatter_topk2(
    const int* __restrict__ rank, const int* __restrict__ prank,
    float* __restrict__ out_imps, float* __restrict__ out_prune,
    int* __restrict__ imp_rows, int* __restrict__ prune_cols)
{
    __shared__ unsigned char fr[NT];
    __shared__ unsigned char fp[NT];
    __shared__ int sr[256], sp[256];
    const int tid = threadIdx.x;
    for (int t = tid; t < NT; t += 256) {
        fr[t] = rank[t] < KRET;
        fp[t] = prank[t] < NPR;
    }
    __syncthreads();
    const int base = tid * 16;
    int cr = 0, cp = 0;
#pragma unroll
    for (int e = 0; e < 16; ++e) { cr += fr[base + e]; cp += fp[base + e]; }
    sr[tid] = cr; sp[tid] = cp;
    __syncthreads();
    int pr = 0, pp = 0;
    for (int j = 0; j < tid; ++j) { pr += sr[j]; pp += sp[j]; }
#pragma unroll
    for (int e = 0; e < 16; ++e) {
        int i = base + e;
        if (fr[i]) { out_imps[pr] = (float)i; imp_rows[pr] = i; ++pr; }
        if (fp[i]) { out_prune[pp] = (float)i; prune_cols[pp] = i; ++pp; }
    }
}

__global__ __launch_bounds__(256) void argmax_part(
    const float* __restrict__ attn, const int* __restrict__ imp_rows,
    float* __restrict__ pbest, int* __restrict__ pbi)
{
    __shared__ int rows[CHUNK];
    const int tid = threadIdx.x;
    const int rc = blockIdx.y;
    const int r0 = rc * CHUNK;
    const int nr = min(KRET - r0, CHUNK);
    for (int t = tid; t < nr; t += 256) rows[t] = imp_rows[r0 + t];
    __syncthreads();
    const int j = blockIdx.x * 256 + tid;
    float best = -INFINITY;
    int bi = 0;
    for (int rr = 0; rr < nr; ++rr) {
        float val = attn[(size_t)rows[rr] * NT + j];
        if (val > best) { best = val; bi = r0 + rr; }
    }
    pbest[(size_t)rc * NT + j] = best;
    pbi[(size_t)rc * NT + j] = bi;
}

__global__ __launch_bounds__(256) void argmax_red(
    const float* __restrict__ pbest, const int* __restrict__ pbi,
    int* __restrict__ maxind)
{
    const int j = blockIdx.x * 256 + threadIdx.x;
    float best = -INFINITY;
    int bi = 0;
#pragma unroll
    for (int rc = 0; rc < 8; ++rc) {
        float val = pbest[(size_t)rc * NT + j];
        if (val > best) { best = val; bi = pbi[(size_t)rc * NT + j]; }
    }
    maxind[j] = bi;
}

__global__ __launch_bounds__(256) void finalize(
    const float* __restrict__ dist, const int* __restrict__ prune_cols,
    const int* __restrict__ maxind, float* __restrict__ out_imp,
    float* __restrict__ out_simi)
{
    int t = blockIdx.x * 256 + threadIdx.x;
    if (t < NT) out_imp[t] = dist[t];
    if (t < NPR) out_simi[t] = (float)maxind[prune_cols[t]];
}

extern "C" void kernel_launch(void* const* d_in, const int* in_sizes, int n_in,
                              void* d_out, int out_size, void* d_ws, size_t ws_size,
                              hipStream_t stream)
{
    const float* x  = (const float*)d_in[0];
    const float* Wq = (const float*)d_in[1];
    const float* Wk = (const float*)d_in[2];
    const float* Wv = (const float*)d_in[3];
    const float* Wo = (const float*)d_in[4];
    const float* bo = (const float*)d_in[5];
    float* out = (float*)d_out;

    const size_t QKT_EL = (size_t)NH * 256 * 3 * 16 * 32;   // 6.29M f16 per plane
    const size_t VP_EL  = (size_t)NH * 128 * 80 * 32;       // 5.24M bf16

    // ---- workspace layout (float units) ----
    float* ws = (float*)d_ws;
    size_t off = 0;
    float* attn = ws + off; off += (size_t)NT * NT;
    f16* Qt0 = (f16*)(ws + off); off += QKT_EL / 2;
    f16* Qt1 = (f16*)(ws + off); off += QKT_EL / 2;
    f16* Kt0 = (f16*)(ws + off); off += QKT_EL / 2;
    f16* Kt1 = (f16*)(ws + off); off += QKT_EL / 2;
    ushort_t* Vp = (ushort_t*)(ws + off); off += VP_EL / 2;
    size_t zero_floats = 4 * (QKT_EL / 2) + VP_EL / 2;      // Qt0..Vp contiguous
    ushort_t* otmpb = (ushort_t*)(ws + off); off += ((size_t)NT * DM) / 2;
    f16* X0 = (f16*)(ws + off); f16* X1 = X0 + (size_t)NT * DM; off += (size_t)NT * DM;
    f16* T0 = (f16*)(ws + off); f16* T1 = T0 + (size_t)DM * DM; off += (size_t)DM * DM;
    ushort_t* Wslot = (ushort_t*)(ws + off); off += ((size_t)DM * DM) / 2;
    float* invs    = ws + off; off += (size_t)NH * NT;
    float* rsPart  = ws + off; off += (size_t)2 * NH * NT;
    ushort_t* part_pv = (ushort_t*)(ws + off); off += (size_t)2 * NH * NT * DH / 2;
    float* pbest   = ws + off; off += 8 * NT;
    int*   pbi     = (int*)(ws + off); off += 8 * NT;
    float* dist0 = ws + off; off += NT;
    float* dist1 = ws + off; off += NT;
    float* partial = ws + off; off += 32 * NT;
    int* rank      = (int*)(ws + off); off += NT;
    int* prank     = (int*)(ws + off); off += NT;
    int* imp_rows  = (int*)(ws + off); off += 2048;
    int* prune_cols= (int*)(ws + off); off += 2560;
    int* maxind    = (int*)(ws + off); off += NT;

    // setup-only alias inside attn region (dead before attn_sum writes)
    ushort_t* xb = (ushort_t*)attn;

    // output layout
    float* out_out   = out;
    float* out_imp   = out + (size_t)NT * DM;
    float* out_imps  = out_imp + NT;
    float* out_prune = out_imps + KRET;
    float* out_simi  = out_prune + NPR;

    // ---- setup ----
    hipMemsetAsync(Qt0, 0, zero_floats * sizeof(float), stream);  // zero-pad tiles
    split_x<<<2048, 256, 0, stream>>>(x, X0, X1, xb, NT * DM);

    dim3 gT(DM / 32, DM / 32);
    dim3 gP(DM / 64, NT / 128);
    transposeW_split<<<gT, 256, 0, stream>>>(Wq, T0, T1, DM);
    proj_split3<<<gP, 256, 0, stream>>>(X0, X1, T0, T1, Qt0, Qt1, SCALE);
    transposeW_split<<<gT, 256, 0, stream>>>(Wk, T0, T1, DM);
    proj_split3<<<gP, 256, 0, stream>>>(X0, X1, T0, T1, Kt0, Kt1, 1.0f);

    transposeW_bf16<<<gT, 256, 0, stream>>>(Wv, Wslot, DM);
    gemm_bf16_lds<<<gP, 256, 0, stream>>>(xb, Wslot, nullptr, Vp, 2, DM, DM);

    // ---- pass A: rowsums + PV, ct-split x2 ----
    rowsum_pv<<<dim3(NT / 64, NH, 2), 256, 0, stream>>>(Qt0, Qt1, Kt0, Kt1, Vp,
                                                        rsPart, part_pv);
    pv_norm<<<dim3(NH, NT / 32), 256, 0, stream>>>(rsPart, part_pv, invs, otmpb);

    // ---- pass B: attn head-sum, head-outer, 32 col-slices, write-once ----
    attn_sum<<<dim3(ACSB, NT / 64), 256, 0, stream>>>(Qt0, Qt1, Kt0, Kt1, invs, attn);

    // ---- output projection ----
    transposeW_bf16<<<gT, 256, 0, stream>>>(Wo, Wslot, DM);
    gemm_bf16_lds<<<gP, 256, 0, stream>>>(otmpb, Wslot, bo, out_out, 0, DM, DM);

    // ---- pagerank ----
    init_dist<<<16, 256, 0, stream>>>(dist0);
    float* da = dist0;
    float* db = dist1;
    for (int it = 0; it < 5; ++it) {
        power_a<<<dim3(16, 32), 256, 0, stream>>>(attn, da, partial);
        power_b<<<16, 256, 0, stream>>>(partial, db);
        float* t = da; da = db; db = t;
    }

    // ---- top-k ----
    hipMemsetAsync(rank, 0, 2 * NT * sizeof(int), stream);
    rank_count<<<dim3(16, 16), 256, 0, stream>>>(da, rank, prank);
    scatter_topk2<<<1, 256, 0, stream>>>(rank, prank, out_imps, out_prune,
                                         imp_rows, prune_cols);
    argmax_part<<<dim3(16, 8), 256, 0, stream>>>(attn, imp_rows, pbest, pbi);
    argmax_red<<<16, 256, 0, stream>>>(pbest, pbi, maxind);
    finalize<<<16, 256, 0, stream>>>(da, prune_cols, maxind, out_imp, out_simi);
}

// Round 16
// 837.834 us; speedup vs baseline: 1.4210x; 1.0066x over previous
//
#include <hip/hip_runtime.h>
#include <math.h>

#define NT 4096
#define DM 1152
#define NH 16
#define DH 72
#define KRET 1638
#define NPR (NT - KRET)
#define QSPLIT 4
#define ACSB 64
#define CHUNK 205
#define SCALE 0.11785113019775793f
#define RSPLIT 2048.0f
#define INV_RSPLIT 4.8828125e-4f

typedef __attribute__((ext_vector_type(8))) short bf16x8;
typedef _Float16 f16;
typedef __attribute__((ext_vector_type(8))) _Float16 f16x8;
typedef __attribute__((ext_vector_type(4))) float f32x4;
typedef unsigned short ushort_t;

#define MFMA16(a, b, c) __builtin_amdgcn_mfma_f32_16x16x32_f16(a, b, c, 0, 0, 0)
#define MFMABF(a, b, c) __builtin_amdgcn_mfma_f32_16x16x32_bf16(a, b, c, 0, 0, 0)

__device__ inline ushort_t f2b(float f) {
    union { float f; unsigned int u; } v; v.f = f;
    unsigned int u = v.u;
    return (ushort_t)((u + 0x7FFFu + ((u >> 16) & 1u)) >> 16);
}

__device__ inline float b2f(ushort_t u) {
    union { unsigned int u; float f; } v; v.u = ((unsigned int)u) << 16;
    return v.f;
}

// tiled Q/K address: [NH][rowblk 256][ks 3][r 16][ki 32]
__device__ inline size_t qkAddr(int h, int row, int ks, int ki) {
    return ((((size_t)h * 256 + (row >> 4)) * 3 + ks) * 16 + (row & 15)) * 32 + ki;
}

// ---------- split x into fp16 hi/lo(x2048) planes + bf16 copy ----------------
__global__ __launch_bounds__(256) void split_x(
    const float* __restrict__ in, f16* __restrict__ x0, f16* __restrict__ x1,
    ushort_t* __restrict__ xb, int nElem)
{
    int i = blockIdx.x * 256 + threadIdx.x;
    int stride = gridDim.x * 256;
    for (; i < nElem; i += stride) {
        float v = in[i];
        f16 h0 = (f16)v;
        float res = (v - (float)h0) * RSPLIT;
        x0[i] = h0;
        x1[i] = (f16)res;
        xb[i] = f2b(v);
    }
}

__global__ __launch_bounds__(256) void transposeW_split(
    const float* __restrict__ W, f16* __restrict__ T0, f16* __restrict__ T1, int n)
{
    __shared__ float t[32][33];
    int bx = blockIdx.x * 32, by = blockIdx.y * 32;
    int tx = threadIdx.x & 31, ty = threadIdx.x >> 5;
    for (int i = ty; i < 32; i += 8)
        t[i][tx] = W[(size_t)(by + i) * n + bx + tx];
    __syncthreads();
    for (int i = ty; i < 32; i += 8) {
        float v = t[tx][i];
        f16 h0 = (f16)v;
        float res = (v - (float)h0) * RSPLIT;
        T0[(size_t)(bx + i) * n + by + tx] = h0;
        T1[(size_t)(bx + i) * n + by + tx] = (f16)res;
    }
}

__global__ __launch_bounds__(256) void transposeW_bf16(
    const float* __restrict__ W, ushort_t* __restrict__ WT, int n)
{
    __shared__ ushort_t t[32][33];
    int bx = blockIdx.x * 32, by = blockIdx.y * 32;
    int tx = threadIdx.x & 31, ty = threadIdx.x >> 5;
    for (int i = ty; i < 32; i += 8)
        t[i][tx] = f2b(W[(size_t)(by + i) * n + bx + tx]);
    __syncthreads();
    for (int i = ty; i < 32; i += 8)
        WT[(size_t)(bx + i) * n + by + tx] = t[tx][i];
}

// ---------- LDS-tiled split projection -> MFMA-tiled per-head output ---------
__global__ __launch_bounds__(256) void proj_split3(
    const f16* __restrict__ A0, const f16* __restrict__ A1,
    const f16* __restrict__ B0, const f16* __restrict__ B1,
    f16* __restrict__ Qt0, f16* __restrict__ Qt1, float scl)
{
    __shared__ __align__(16) f16 As0[128][40];
    __shared__ __align__(16) f16 As1[128][40];
    __shared__ __align__(16) f16 Bs0[64][40];
    __shared__ __align__(16) f16 Bs1[64][40];
    const int tid = threadIdx.x;
    const int wave = tid >> 6, lane = tid & 63;
    const int r = lane & 15, g = lane >> 4;
    const int row0 = blockIdx.y * 128;
    const int col0 = blockIdx.x * 64;
    f32x4 accM[2][4] = {}, accC[2][4] = {};
    for (int k0 = 0; k0 < DM; k0 += 32) {
        for (int idx = tid; idx < 128 * 4; idx += 256) {
            int row = idx >> 2, c = idx & 3;
            size_t src = (size_t)(row0 + row) * DM + k0 + c * 8;
            *(f16x8*)&As0[row][c * 8] = *(const f16x8*)(A0 + src);
            *(f16x8*)&As1[row][c * 8] = *(const f16x8*)(A1 + src);
        }
        for (int idx = tid; idx < 64 * 4; idx += 256) {
            int row = idx >> 2, c = idx & 3;
            size_t src = (size_t)(col0 + row) * DM + k0 + c * 8;
            *(f16x8*)&Bs0[row][c * 8] = *(const f16x8*)(B0 + src);
            *(f16x8*)&Bs1[row][c * 8] = *(const f16x8*)(B1 + src);
        }
        __syncthreads();
        f16x8 a0[2], a1[2], b0[4], b1[4];
#pragma unroll
        for (int rf = 0; rf < 2; ++rf) {
            a0[rf] = *(const f16x8*)&As0[wave * 32 + rf * 16 + r][g * 8];
            a1[rf] = *(const f16x8*)&As1[wave * 32 + rf * 16 + r][g * 8];
        }
#pragma unroll
        for (int cf = 0; cf < 4; ++cf) {
            b0[cf] = *(const f16x8*)&Bs0[cf * 16 + r][g * 8];
            b1[cf] = *(const f16x8*)&Bs1[cf * 16 + r][g * 8];
        }
#pragma unroll
        for (int rf = 0; rf < 2; ++rf)
#pragma unroll
            for (int cf = 0; cf < 4; ++cf) {
                accM[rf][cf] = MFMA16(a0[rf], b0[cf], accM[rf][cf]);
                accC[rf][cf] = MFMA16(a0[rf], b1[cf], accC[rf][cf]);
                accC[rf][cf] = MFMA16(a1[rf], b0[cf], accC[rf][cf]);
            }
        __syncthreads();
    }
#pragma unroll
    for (int rf = 0; rf < 2; ++rf)
#pragma unroll
        for (int cf = 0; cf < 4; ++cf) {
            int col = col0 + cf * 16 + r;
            int head = col / DH;
            int c = col - head * DH;
            int ks = c >> 5, ki = c & 31;
#pragma unroll
            for (int j = 0; j < 4; ++j) {
                int row = row0 + wave * 32 + rf * 16 + g * 4 + j;
                float v = (accM[rf][cf][j] + accC[rf][cf][j] * INV_RSPLIT) * scl;
                f16 h0 = (f16)v;
                float res = (v - (float)h0) * RSPLIT;
                size_t addr = qkAddr(head, row, ks, ki);
                Qt0[addr] = h0;
                Qt1[addr] = (f16)res;
            }
        }
}

// ---------- LDS-tiled bf16 MFMA GEMM; mode 0 = fp32 flat, 2 = Vp tiled -------
__global__ __launch_bounds__(256) void gemm_bf16_lds(
    const ushort_t* __restrict__ A, const ushort_t* __restrict__ BT,
    const float* __restrict__ bias, void* __restrict__ C, int mode,
    int Nn, int K)
{
    __shared__ __align__(16) ushort_t As[128][40];
    __shared__ __align__(16) ushort_t Bs[64][40];
    const int tid = threadIdx.x;
    const int wave = tid >> 6, lane = tid & 63;
    const int r = lane & 15, g = lane >> 4;
    const int row0 = blockIdx.y * 128;
    const int col0 = blockIdx.x * 64;
    f32x4 acc[2][4] = {};
    for (int k0 = 0; k0 < K; k0 += 32) {
        for (int idx = tid; idx < 128 * 4; idx += 256) {
            int row = idx >> 2, c = idx & 3;
            *(bf16x8*)&As[row][c * 8] = *(const bf16x8*)(A + (size_t)(row0 + row) * K + k0 + c * 8);
        }
        for (int idx = tid; idx < 64 * 4; idx += 256) {
            int row = idx >> 2, c = idx & 3;
            *(bf16x8*)&Bs[row][c * 8] = *(const bf16x8*)(BT + (size_t)(col0 + row) * K + k0 + c * 8);
        }
        __syncthreads();
        bf16x8 a[2], b[4];
#pragma unroll
        for (int rf = 0; rf < 2; ++rf)
            a[rf] = *(const bf16x8*)&As[wave * 32 + rf * 16 + r][g * 8];
#pragma unroll
        for (int cf = 0; cf < 4; ++cf)
            b[cf] = *(const bf16x8*)&Bs[cf * 16 + r][g * 8];
#pragma unroll
        for (int rf = 0; rf < 2; ++rf)
#pragma unroll
            for (int cf = 0; cf < 4; ++cf)
                acc[rf][cf] = MFMABF(a[rf], b[cf], acc[rf][cf]);
        __syncthreads();
    }
#pragma unroll
    for (int rf = 0; rf < 2; ++rf)
#pragma unroll
        for (int cf = 0; cf < 4; ++cf) {
            int col = col0 + cf * 16 + r;
            float bv = bias ? bias[col] : 0.f;
#pragma unroll
            for (int j = 0; j < 4; ++j) {
                int row = row0 + wave * 32 + rf * 16 + g * 4 + j;
                float vv = acc[rf][cf][j] + bv;
                if (mode == 2) {
                    int head = col / DH;
                    int d = col - head * DH;
                    size_t addr = (((size_t)head * 128 + (row >> 5)) * 80 + d) * 32 + (row & 31);
                    ((ushort_t*)C)[addr] = f2b(vv);
                } else {
                    ((float*)C)[(size_t)row * Nn + col] = vv;
                }
            }
        }
}

// ---------- pass A: rowsum + PV, swapped-operand QK, ct-split x4 -------------
// grid (NT/64, NH, QSPLIT). Each quarter: 16 ct-steps; rs fp32 + PV bf16 partials.
__global__ __launch_bounds__(256) void rowsum_pv(
    const f16* __restrict__ Qt0, const f16* __restrict__ Qt1,
    const f16* __restrict__ Kt0, const f16* __restrict__ Kt1,
    const ushort_t* __restrict__ Vp,
    float* __restrict__ rsPart, ushort_t* __restrict__ part_pv)
{
    __shared__ __align__(16) f16 KL[2][6144];   // [plane][12 tiles of 512]
    const int tid = threadIdx.x;
    const int wv = tid >> 6, lane = tid & 63;
    const int r = lane & 15, g = lane >> 4;
    const int h = blockIdx.y;
    const int quar = blockIdx.z;
    const int rowblk = blockIdx.x * 4 + wv;
    // Q fragments (used as the B operand of the swapped MFMA)
    f16x8 a0[3], a1[3];
#pragma unroll
    for (int ks = 0; ks < 3; ++ks) {
        size_t o = ((((size_t)h * 256 + rowblk) * 3 + ks) * 16) * 32 + r * 32 + g * 8;
        a0[ks] = *(const f16x8*)(Qt0 + o);
        a1[ks] = *(const f16x8*)(Qt1 + o);
    }
    // permuted per-lane K read columns: c32 = (r>>2)*8 + cfp*4 + (r&3)
    const int c32p0 = ((r >> 2) << 3) + (r & 3);
    float rs = 0.f;
    f32x4 oacc[5] = {};
    for (int ct = quar * 16; ct < quar * 16 + 16; ++ct) {
        __syncthreads();
        const size_t ctBase = ((size_t)h * 256 + ct * 4) * 1536;
#pragma unroll
        for (int s = 0; s < 6; ++s) {
            int wc = s * 4 + wv;             // 0..23 wave-chunks of 1024B
            int plane = wc >= 12;
            int cip = wc - plane * 12;
            const f16* src = (plane ? Kt1 : Kt0) + ctBase + cip * 512 + lane * 8;
            *(f16x8*)&KL[plane][cip * 512 + lane * 8] = *(const f16x8*)src;
        }
        __syncthreads();
        f32x4 accM[4] = {}, accC[4] = {};
#pragma unroll
        for (int ks = 0; ks < 3; ++ks) {
#pragma unroll
            for (int group = 0; group < 2; ++group) {
#pragma unroll
                for (int cfp = 0; cfp < 2; ++cfp) {
                    const int c32 = c32p0 + cfp * 4;
                    const int off = (((group * 2 + (c32 >> 4)) * 3 + ks) << 9)
                                  + ((c32 & 15) << 5) + (g << 3);
                    f16x8 b0 = *(const f16x8*)&KL[0][off];
                    f16x8 b1 = *(const f16x8*)&KL[1][off];
                    const int cf = group * 2 + cfp;
                    accM[cf] = MFMA16(b0, a0[ks], accM[cf]);
                    accC[cf] = MFMA16(b1, a0[ks], accC[cf]);
                    accC[cf] = MFMA16(b0, a1[ks], accC[cf]);
                }
            }
        }
        // exp -> rs + cvt_pk bf16 pack -> PV
        const int kt0 = ct * 2;
#pragma unroll
        for (int group = 0; group < 2; ++group) {
            float e[8];
#pragma unroll
            for (int cfp = 0; cfp < 2; ++cfp) {
                const int cf = group * 2 + cfp;
#pragma unroll
                for (int j = 0; j < 4; ++j) {
                    float ev = __expf(accM[cf][j] + accC[cf][j] * INV_RSPLIT);
                    rs += ev;
                    e[cfp * 4 + j] = ev;
                }
            }
            union { bf16x8 v; unsigned w[4]; } pa;
#pragma unroll
            for (int wi = 0; wi < 4; ++wi) {
                unsigned rw;
                asm("v_cvt_pk_bf16_f32 %0, %1, %2"
                    : "=v"(rw) : "v"(e[wi * 2]), "v"(e[wi * 2 + 1]));
                pa.w[wi] = rw;
            }
#pragma unroll
            for (int t = 0; t < 5; ++t) {
                int col = t * 16 + r;
                size_t vo = (((size_t)h * 128 + kt0 + group) * 80 + col) * 32 + g * 8;
                bf16x8 b = *(const bf16x8*)(Vp + vo);
                oacc[t] = MFMABF(pa.v, b, oacc[t]);
            }
        }
    }
    // rs is per-lane partial for q-row r; reduce over the 4 g-groups
    rs += __shfl_xor(rs, 16);
    rs += __shfl_xor(rs, 32);
    if (g == 0)
        rsPart[((size_t)quar * NH + h) * NT + rowblk * 16 + r] = rs;
    // unnormalized PV partial (bf16)
#pragma unroll
    for (int t = 0; t < 5; ++t) {
        int col = t * 16 + r;
        if (col < DH) {
#pragma unroll
            for (int j = 0; j < 4; ++j) {
                int row = rowblk * 16 + g * 4 + j;
                part_pv[(((size_t)quar * NH + h) * NT + row) * DH + col] = f2b(oacc[t][j]);
            }
        }
    }
}

// ---------- combine rowsum/PV quarters: invs + normalized otmpb --------------
// grid (NH, NT/32), 256 threads.
__global__ __launch_bounds__(256) void pv_norm(
    const float* __restrict__ rsPart, const ushort_t* __restrict__ part_pv,
    float* __restrict__ invs, ushort_t* __restrict__ otmpb)
{
    __shared__ float sinv[32];
    const int h = blockIdx.x;
    const int row0 = blockIdx.y * 32;
    const int tid = threadIdx.x;
    if (tid < 32) {
        float s = 0.f;
#pragma unroll
        for (int q = 0; q < QSPLIT; ++q)
            s += rsPart[((size_t)q * NH + h) * NT + row0 + tid];
        float inv = 1.0f / s;
        sinv[tid] = inv;
        invs[(size_t)h * NT + row0 + tid] = inv;
    }
    __syncthreads();
    for (int e = tid; e < 32 * DH; e += 256) {
        int rr = e / DH, col = e - rr * DH;
        int row = row0 + rr;
        float s = 0.f;
#pragma unroll
        for (int q = 0; q < QSPLIT; ++q)
            s += b2f(part_pv[(((size_t)q * NH + h) * NT + row) * DH + col]);
        otmpb[(size_t)row * DM + h * DH + col] = f2b(s * sinv[rr]);
    }
}

// ---------- pass B: attn head-sum; head-outer; 64 col-slices of 64 -----------
__global__ __launch_bounds__(256) void attn_sum(
    const f16* __restrict__ Qt0, const f16* __restrict__ Qt1,
    const f16* __restrict__ Kt0, const f16* __restrict__ Kt1,
    const float* __restrict__ invs, float* __restrict__ attn)
{
    __shared__ __align__(16) f16 KL[2][6144];   // [plane][12 tiles of 512]
    const int tid = threadIdx.x;
    const int wr = tid >> 6, lane = tid & 63;
    const int r = lane & 15, g = lane >> 4;
    const int cs = blockIdx.x;
    const int rowblk = blockIdx.y * 4 + wr;
    const int row0 = rowblk * 16;
    const int cb0 = cs * 4;                     // colblk base (64 cols/slice)
    float aacc[4][4] = {};                      // [cf][j]
    for (int h = 0; h < NH; ++h) {
        // Q fragments once per head
        f16x8 a0[3], a1[3];
#pragma unroll
        for (int ks = 0; ks < 3; ++ks) {
            size_t o = ((((size_t)h * 256 + rowblk) * 3 + ks) * 16) * 32 + r * 32 + g * 8;
            a0[ks] = *(const f16x8*)(Qt0 + o);
            a1[ks] = *(const f16x8*)(Qt1 + o);
        }
        float vinv[4];
#pragma unroll
        for (int j = 0; j < 4; ++j)
            vinv[j] = invs[(size_t)h * NT + row0 + g * 4 + j];
        __syncthreads();
        const size_t ctBase = ((size_t)h * 256 + cb0) * 1536;
#pragma unroll
        for (int s = 0; s < 6; ++s) {
            int wc = s * 4 + wr;                // 0..23 wave-chunks of 1024B
            int plane = wc >= 12;
            int cip = wc - plane * 12;
            const f16* src = (plane ? Kt1 : Kt0) + ctBase + cip * 512 + lane * 8;
            *(f16x8*)&KL[plane][cip * 512 + lane * 8] = *(const f16x8*)src;
        }
        __syncthreads();
        f32x4 accM[4] = {}, accC[4] = {};
#pragma unroll
        for (int ks = 0; ks < 3; ++ks) {
#pragma unroll
            for (int cf = 0; cf < 4; ++cf) {
                f16x8 b0 = *(const f16x8*)&KL[0][(cf * 3 + ks) * 512 + r * 32 + g * 8];
                f16x8 b1 = *(const f16x8*)&KL[1][(cf * 3 + ks) * 512 + r * 32 + g * 8];
                accM[cf] = MFMA16(a0[ks], b0, accM[cf]);
                accC[cf] = MFMA16(a0[ks], b1, accC[cf]);
                accC[cf] = MFMA16(a1[ks], b0, accC[cf]);
            }
        }
#pragma unroll
        for (int cf = 0; cf < 4; ++cf) {
#pragma unroll
            for (int j = 0; j < 4; ++j) {
                float p = __expf(accM[cf][j] + accC[cf][j] * INV_RSPLIT) * vinv[j];
                aacc[cf][j] += p;
            }
        }
    }
    // write attn once (no rmw)
    const int colbase = cs * 64;
#pragma unroll
    for (int cf = 0; cf < 4; ++cf) {
#pragma unroll
        for (int j = 0; j < 4; ++j) {
            int row = row0 + g * 4 + j;
            attn[(size_t)row * NT + colbase + cf * 16 + r] = aacc[cf][j] * 0.0625f;
        }
    }
}

// ---------- pagerank power iteration (fp32, unchanged) -----------------------
__global__ __launch_bounds__(256) void init_dist(float* __restrict__ d)
{
    int t = blockIdx.x * 256 + threadIdx.x;
    if (t < NT) d[t] = 1.0f / NT;
}

__global__ __launch_bounds__(256) void power_a(
    const float* __restrict__ attn, const float* __restrict__ din,
    float* __restrict__ part)
{
    int j = blockIdx.x * 256 + threadIdx.x;
    int i0 = blockIdx.y * 128;
    float acc = 0.f;
    for (int i = i0; i < i0 + 128; ++i)
        acc += din[i] * attn[(size_t)i * NT + j];
    part[(size_t)blockIdx.y * NT + j] = acc;
}

__global__ __launch_bounds__(256) void power_b(
    const float* __restrict__ part, float* __restrict__ dout)
{
    int j = blockIdx.x * 256 + threadIdx.x;
    float acc = 0.f;
    for (int ib = 0; ib < 32; ++ib) acc += part[(size_t)ib * NT + j];
    dout[j] = acc;
}

// ---------- top-k: tiled rank counting (deterministic int atomics) -----------
__global__ __launch_bounds__(256) void rank_count(
    const float* __restrict__ imp, int* __restrict__ rank, int* __restrict__ prank)
{
    __shared__ float sj[256];
    const int tid = threadIdx.x;
    const int jb = blockIdx.y * 256;
    sj[tid] = imp[jb + tid];
    __syncthreads();
    const int i = blockIdx.x * 256 + tid;
    const float mv = imp[i];
    int r = 0, rp = 0;
    for (int jj = 0; jj < 256; ++jj) {
        float vj = sj[jj];
        int j = jb + jj;
        int tie_low = (vj == mv) && (j < i);
        r  += (vj > mv) || tie_low;
        rp += (vj < mv) || tie_low;
    }
    atomicAdd(&rank[i], r);
    atomicAdd(&prank[i], rp);
}

__global__ __launch_bounds__(256) void scatter_topk2(
    const int* __restrict__ rank, const int* __restrict__ prank,
    float* __restrict__ out_imps, float* __restrict__ out_prune,
    int* __restrict__ imp_rows, int* __restrict__ prune_cols)
{
    __shared__ unsigned char fr[NT];
    __shared__ unsigned char fp[NT];
    __shared__ int sr[256], sp[256];
    const int tid = threadIdx.x;
    for (int t = tid; t < NT; t += 256) {
        fr[t] = rank[t] < KRET;
        fp[t] = prank[t] < NPR;
    }
    __syncthreads();
    const int base = tid * 16;
    int cr = 0, cp = 0;
#pragma unroll
    for (int e = 0; e < 16; ++e) { cr += fr[base + e]; cp += fp[base + e]; }
    sr[tid] = cr; sp[tid] = cp;
    __syncthreads();
    int pr = 0, pp = 0;
    for (int j = 0; j < tid; ++j) { pr += sr[j]; pp += sp[j]; }
#pragma unroll
    for (int e = 0; e < 16; ++e) {
        int i = base + e;
        if (fr[i]) { out_imps[pr] = (float)i; imp_rows[pr] = i; ++pr; }
        if (fp[i]) { out_prune[pp] = (float)i; prune_cols[pp] = i; ++pp; }
    }
}

__global__ __launch_bounds__(256) void argmax_part(
    const float* __restrict__ attn, const int* __restrict__ imp_rows,
    float* __restrict__ pbest, int* __restrict__ pbi)
{
    __shared__ int rows[CHUNK];
    const int tid = threadIdx.x;
    const int rc = blockIdx.y;
    const int r0 = rc * CHUNK;
    const int nr = min(KRET - r0, CHUNK);
    for (int t = tid; t < nr; t += 256) rows[t] = imp_rows[r0 + t];
    __syncthreads();
    const int j = blockIdx.x * 256 + tid;
    float best = -INFINITY;
    int bi = 0;
    for (int rr = 0; rr < nr; ++rr) {
        float val = attn[(size_t)rows[rr] * NT + j];
        if (val > best) { best = val; bi = r0 + rr; }
    }
    pbest[(size_t)rc * NT + j] = best;
    pbi[(size_t)rc * NT + j] = bi;
}

__global__ __launch_bounds__(256) void argmax_red(
    const float* __restrict__ pbest, const int* __restrict__ pbi,
    int* __restrict__ maxind)
{
    const int j = blockIdx.x * 256 + threadIdx.x;
    float best = -INFINITY;
    int bi = 0;
#pragma unroll
    for (int rc = 0; rc < 8; ++rc) {
        float val = pbest[(size_t)rc * NT + j];
        if (val > best) { best = val; bi = pbi[(size_t)rc * NT + j]; }
    }
    maxind[j] = bi;
}

__global__ __launch_bounds__(256) void finalize(
    const float* __restrict__ dist, const int* __restrict__ prune_cols,
    const int* __restrict__ maxind, float* __restrict__ out_imp,
    float* __restrict__ out_simi)
{
    int t = blockIdx.x * 256 + threadIdx.x;
    if (t < NT) out_imp[t] = dist[t];
    if (t < NPR) out_simi[t] = (float)maxind[prune_cols[t]];
}

extern "C" void kernel_launch(void* const* d_in, const int* in_sizes, int n_in,
                              void* d_out, int out_size, void* d_ws, size_t ws_size,
                              hipStream_t stream)
{
    const float* x  = (const float*)d_in[0];
    const float* Wq = (const float*)d_in[1];
    const float* Wk = (const float*)d_in[2];
    const float* Wv = (const float*)d_in[3];
    const float* Wo = (const float*)d_in[4];
    const float* bo = (const float*)d_in[5];
    float* out = (float*)d_out;

    const size_t QKT_EL = (size_t)NH * 256 * 3 * 16 * 32;   // 6.29M f16 per plane
    const size_t VP_EL  = (size_t)NH * 128 * 80 * 32;       // 5.24M bf16

    // ---- workspace layout (float units), ~166 MB with aliasing ----
    float* ws = (float*)d_ws;
    size_t off = 0;
    float* attn = ws + off; off += (size_t)NT * NT;
    f16* Qt0 = (f16*)(ws + off); off += QKT_EL / 2;
    f16* Qt1 = (f16*)(ws + off); off += QKT_EL / 2;
    f16* Kt0 = (f16*)(ws + off); off += QKT_EL / 2;
    f16* Kt1 = (f16*)(ws + off); off += QKT_EL / 2;
    ushort_t* Vp = (ushort_t*)(ws + off); off += VP_EL / 2;
    size_t zero_floats = 4 * (QKT_EL / 2) + VP_EL / 2;      // Qt0..Vp contiguous
    ushort_t* otmpb = (ushort_t*)(ws + off); off += ((size_t)NT * DM) / 2;
    f16* X0 = (f16*)(ws + off); f16* X1 = X0 + (size_t)NT * DM;
    float* xs_base = ws + off; off += (size_t)NT * DM;
    f16* T0 = (f16*)(ws + off); f16* T1 = T0 + (size_t)DM * DM; off += (size_t)DM * DM;
    ushort_t* Wslot = (ushort_t*)(ws + off); off += ((size_t)DM * DM) / 2;
    float* invs    = ws + off; off += (size_t)NH * NT;
    float* pbest   = ws + off; off += 8 * NT;
    int*   pbi     = (int*)(ws + off); off += 8 * NT;
    float* dist0 = ws + off; off += NT;
    float* dist1 = ws + off; off += NT;
    float* partial = ws + off; off += 32 * NT;
    int* rank      = (int*)(ws + off); off += NT;
    int* prank     = (int*)(ws + off); off += NT;
    int* imp_rows  = (int*)(ws + off); off += 2048;
    int* prune_cols= (int*)(ws + off); off += 2560;
    int* maxind    = (int*)(ws + off); off += NT;

    // aliases (lifetime-checked):
    //   xb (setup only) and part_pv (pass A only) live inside attn;
    //   rsPart lives inside the dead X-split region after projections.
    ushort_t* xb = (ushort_t*)attn;
    ushort_t* part_pv = (ushort_t*)attn;       // QSPLIT*NH*NT*DH bf16 = 37.7 MB
    float* rsPart = xs_base;                   // QSPLIT*NH*NT fp32 = 1 MB

    // output layout
    float* out_out   = out;
    float* out_imp   = out + (size_t)NT * DM;
    float* out_imps  = out_imp + NT;
    float* out_prune = out_imps + KRET;
    float* out_simi  = out_prune + NPR;

    // ---- setup ----
    hipMemsetAsync(Qt0, 0, zero_floats * sizeof(float), stream);  // zero-pad tiles
    split_x<<<2048, 256, 0, stream>>>(x, X0, X1, xb, NT * DM);

    dim3 gT(DM / 32, DM / 32);
    dim3 gP(DM / 64, NT / 128);
    transposeW_split<<<gT, 256, 0, stream>>>(Wq, T0, T1, DM);
    proj_split3<<<gP, 256, 0, stream>>>(X0, X1, T0, T1, Qt0, Qt1, SCALE);
    transposeW_split<<<gT, 256, 0, stream>>>(Wk, T0, T1, DM);
    proj_split3<<<gP, 256, 0, stream>>>(X0, X1, T0, T1, Kt0, Kt1, 1.0f);

    transposeW_bf16<<<gT, 256, 0, stream>>>(Wv, Wslot, DM);
    gemm_bf16_lds<<<gP, 256, 0, stream>>>(xb, Wslot, nullptr, Vp, 2, DM, DM);

    // ---- pass A: rowsums + PV, ct-split x4 (partials alias attn region) ----
    rowsum_pv<<<dim3(NT / 64, NH, QSPLIT), 256, 0, stream>>>(Qt0, Qt1, Kt0, Kt1, Vp,
                                                             rsPart, part_pv);
    pv_norm<<<dim3(NH, NT / 32), 256, 0, stream>>>(rsPart, part_pv, invs, otmpb);

    // ---- pass B: attn head-sum, head-outer, 64 col-slices, write-once ----
    attn_sum<<<dim3(ACSB, NT / 64), 256, 0, stream>>>(Qt0, Qt1, Kt0, Kt1, invs, attn);

    // ---- output projection ----
    transposeW_bf16<<<gT, 256, 0, stream>>>(Wo, Wslot, DM);
    gemm_bf16_lds<<<gP, 256, 0, stream>>>(otmpb, Wslot, bo, out_out, 0, DM, DM);

    // ---- pagerank ----
    init_dist<<<16, 256, 0, stream>>>(dist0);
    float* da = dist0;
    float* db = dist1;
    for (int it = 0; it < 5; ++it) {
        power_a<<<dim3(16, 32), 256, 0, stream>>>(attn, da, partial);
        power_b<<<16, 256, 0, stream>>>(partial, db);
        float* t = da; da = db; db = t;
    }

    // ---- top-k ----
    hipMemsetAsync(rank, 0, 2 * NT * sizeof(int), stream);
    rank_count<<<dim3(16, 16), 256, 0, stream>>>(da, rank, prank);
    scatter_topk2<<<1, 256, 0, stream>>>(rank, prank, out_imps, out_prune,
                                         imp_rows, prune_cols);
    argmax_part<<<dim3(16, 8), 256, 0, stream>>>(attn, imp_rows, pbest, pbi);
    argmax_red<<<16, 256, 0, stream>>>(pbest, pbi, maxind);
    finalize<<<16, 256, 0, stream>>>(da, prune_cols, maxind, out_imp, out_simi);
}

// Round 17
// 822.535 us; speedup vs baseline: 1.4474x; 1.0186x over previous
//
#include <hip/hip_runtime.h>
#include <math.h>

#define NT 4096
#define DM 1152
#define NH 16
#define DH 72
#define KRET 1638
#define NPR (NT - KRET)
#define QSPLIT 4
#define ACSB 64
#define CHUNK 205
#define SCALE 0.11785113019775793f
#define RSPLIT 2048.0f
#define INV_RSPLIT 4.8828125e-4f

typedef __attribute__((ext_vector_type(8))) short bf16x8;
typedef _Float16 f16;
typedef __attribute__((ext_vector_type(8))) _Float16 f16x8;
typedef __attribute__((ext_vector_type(4))) float f32x4;
typedef unsigned short ushort_t;

#define MFMA16(a, b, c) __builtin_amdgcn_mfma_f32_16x16x32_f16(a, b, c, 0, 0, 0)
#define MFMABF(a, b, c) __builtin_amdgcn_mfma_f32_16x16x32_bf16(a, b, c, 0, 0, 0)

__device__ inline ushort_t f2b(float f) {
    union { float f; unsigned int u; } v; v.f = f;
    unsigned int u = v.u;
    return (ushort_t)((u + 0x7FFFu + ((u >> 16) & 1u)) >> 16);
}

__device__ inline float b2f(ushort_t u) {
    union { unsigned int u; float f; } v; v.u = ((unsigned int)u) << 16;
    return v.f;
}

// tiled Q/K address: [NH][rowblk 256][ks 3][r 16][ki 32]
__device__ inline size_t qkAddr(int h, int row, int ks, int ki) {
    return ((((size_t)h * 256 + (row >> 4)) * 3 + ks) * 16 + (row & 15)) * 32 + ki;
}

// ---------- split x into fp16 hi/lo(x2048) planes + bf16 copy ----------------
__global__ __launch_bounds__(256) void split_x(
    const float* __restrict__ in, f16* __restrict__ x0, f16* __restrict__ x1,
    ushort_t* __restrict__ xb, int nElem)
{
    int i = blockIdx.x * 256 + threadIdx.x;
    int stride = gridDim.x * 256;
    for (; i < nElem; i += stride) {
        float v = in[i];
        f16 h0 = (f16)v;
        float res = (v - (float)h0) * RSPLIT;
        x0[i] = h0;
        x1[i] = (f16)res;
        xb[i] = f2b(v);
    }
}

__global__ __launch_bounds__(256) void transposeW_split(
    const float* __restrict__ W, f16* __restrict__ T0, f16* __restrict__ T1, int n)
{
    __shared__ float t[32][33];
    int bx = blockIdx.x * 32, by = blockIdx.y * 32;
    int tx = threadIdx.x & 31, ty = threadIdx.x >> 5;
    for (int i = ty; i < 32; i += 8)
        t[i][tx] = W[(size_t)(by + i) * n + bx + tx];
    __syncthreads();
    for (int i = ty; i < 32; i += 8) {
        float v = t[tx][i];
        f16 h0 = (f16)v;
        float res = (v - (float)h0) * RSPLIT;
        T0[(size_t)(bx + i) * n + by + tx] = h0;
        T1[(size_t)(bx + i) * n + by + tx] = (f16)res;
    }
}

__global__ __launch_bounds__(256) void transposeW_bf16(
    const float* __restrict__ W, ushort_t* __restrict__ WT, int n)
{
    __shared__ ushort_t t[32][33];
    int bx = blockIdx.x * 32, by = blockIdx.y * 32;
    int tx = threadIdx.x & 31, ty = threadIdx.x >> 5;
    for (int i = ty; i < 32; i += 8)
        t[i][tx] = f2b(W[(size_t)(by + i) * n + bx + tx]);
    __syncthreads();
    for (int i = ty; i < 32; i += 8)
        WT[(size_t)(bx + i) * n + by + tx] = t[tx][i];
}

// ---------- LDS-tiled split projection -> MFMA-tiled per-head output ---------
__global__ __launch_bounds__(256) void proj_split3(
    const f16* __restrict__ A0, const f16* __restrict__ A1,
    const f16* __restrict__ B0, const f16* __restrict__ B1,
    f16* __restrict__ Qt0, f16* __restrict__ Qt1, float scl)
{
    __shared__ __align__(16) f16 As0[128][40];
    __shared__ __align__(16) f16 As1[128][40];
    __shared__ __align__(16) f16 Bs0[64][40];
    __shared__ __align__(16) f16 Bs1[64][40];
    const int tid = threadIdx.x;
    const int wave = tid >> 6, lane = tid & 63;
    const int r = lane & 15, g = lane >> 4;
    const int row0 = blockIdx.y * 128;
    const int col0 = blockIdx.x * 64;
    f32x4 accM[2][4] = {}, accC[2][4] = {};
    for (int k0 = 0; k0 < DM; k0 += 32) {
        for (int idx = tid; idx < 128 * 4; idx += 256) {
            int row = idx >> 2, c = idx & 3;
            size_t src = (size_t)(row0 + row) * DM + k0 + c * 8;
            *(f16x8*)&As0[row][c * 8] = *(const f16x8*)(A0 + src);
            *(f16x8*)&As1[row][c * 8] = *(const f16x8*)(A1 + src);
        }
        for (int idx = tid; idx < 64 * 4; idx += 256) {
            int row = idx >> 2, c = idx & 3;
            size_t src = (size_t)(col0 + row) * DM + k0 + c * 8;
            *(f16x8*)&Bs0[row][c * 8] = *(const f16x8*)(B0 + src);
            *(f16x8*)&Bs1[row][c * 8] = *(const f16x8*)(B1 + src);
        }
        __syncthreads();
        f16x8 a0[2], a1[2], b0[4], b1[4];
#pragma unroll
        for (int rf = 0; rf < 2; ++rf) {
            a0[rf] = *(const f16x8*)&As0[wave * 32 + rf * 16 + r][g * 8];
            a1[rf] = *(const f16x8*)&As1[wave * 32 + rf * 16 + r][g * 8];
        }
#pragma unroll
        for (int cf = 0; cf < 4; ++cf) {
            b0[cf] = *(const f16x8*)&Bs0[cf * 16 + r][g * 8];
            b1[cf] = *(const f16x8*)&Bs1[cf * 16 + r][g * 8];
        }
#pragma unroll
        for (int rf = 0; rf < 2; ++rf)
#pragma unroll
            for (int cf = 0; cf < 4; ++cf) {
                accM[rf][cf] = MFMA16(a0[rf], b0[cf], accM[rf][cf]);
                accC[rf][cf] = MFMA16(a0[rf], b1[cf], accC[rf][cf]);
                accC[rf][cf] = MFMA16(a1[rf], b0[cf], accC[rf][cf]);
            }
        __syncthreads();
    }
#pragma unroll
    for (int rf = 0; rf < 2; ++rf)
#pragma unroll
        for (int cf = 0; cf < 4; ++cf) {
            int col = col0 + cf * 16 + r;
            int head = col / DH;
            int c = col - head * DH;
            int ks = c >> 5, ki = c & 31;
#pragma unroll
            for (int j = 0; j < 4; ++j) {
                int row = row0 + wave * 32 + rf * 16 + g * 4 + j;
                float v = (accM[rf][cf][j] + accC[rf][cf][j] * INV_RSPLIT) * scl;
                f16 h0 = (f16)v;
                float res = (v - (float)h0) * RSPLIT;
                size_t addr = qkAddr(head, row, ks, ki);
                Qt0[addr] = h0;
                Qt1[addr] = (f16)res;
            }
        }
}

// ---------- LDS-tiled bf16 MFMA GEMM; mode 0 = fp32 flat, 2 = Vp tiled -------
__global__ __launch_bounds__(256) void gemm_bf16_lds(
    const ushort_t* __restrict__ A, const ushort_t* __restrict__ BT,
    const float* __restrict__ bias, void* __restrict__ C, int mode,
    int Nn, int K)
{
    __shared__ __align__(16) ushort_t As[128][40];
    __shared__ __align__(16) ushort_t Bs[64][40];
    const int tid = threadIdx.x;
    const int wave = tid >> 6, lane = tid & 63;
    const int r = lane & 15, g = lane >> 4;
    const int row0 = blockIdx.y * 128;
    const int col0 = blockIdx.x * 64;
    f32x4 acc[2][4] = {};
    for (int k0 = 0; k0 < K; k0 += 32) {
        for (int idx = tid; idx < 128 * 4; idx += 256) {
            int row = idx >> 2, c = idx & 3;
            *(bf16x8*)&As[row][c * 8] = *(const bf16x8*)(A + (size_t)(row0 + row) * K + k0 + c * 8);
        }
        for (int idx = tid; idx < 64 * 4; idx += 256) {
            int row = idx >> 2, c = idx & 3;
            *(bf16x8*)&Bs[row][c * 8] = *(const bf16x8*)(BT + (size_t)(col0 + row) * K + k0 + c * 8);
        }
        __syncthreads();
        bf16x8 a[2], b[4];
#pragma unroll
        for (int rf = 0; rf < 2; ++rf)
            a[rf] = *(const bf16x8*)&As[wave * 32 + rf * 16 + r][g * 8];
#pragma unroll
        for (int cf = 0; cf < 4; ++cf)
            b[cf] = *(const bf16x8*)&Bs[cf * 16 + r][g * 8];
#pragma unroll
        for (int rf = 0; rf < 2; ++rf)
#pragma unroll
            for (int cf = 0; cf < 4; ++cf)
                acc[rf][cf] = MFMABF(a[rf], b[cf], acc[rf][cf]);
        __syncthreads();
    }
#pragma unroll
    for (int rf = 0; rf < 2; ++rf)
#pragma unroll
        for (int cf = 0; cf < 4; ++cf) {
            int col = col0 + cf * 16 + r;
            float bv = bias ? bias[col] : 0.f;
#pragma unroll
            for (int j = 0; j < 4; ++j) {
                int row = row0 + wave * 32 + rf * 16 + g * 4 + j;
                float vv = acc[rf][cf][j] + bv;
                if (mode == 2) {
                    int head = col / DH;
                    int d = col - head * DH;
                    size_t addr = (((size_t)head * 128 + (row >> 5)) * 80 + d) * 32 + (row & 31);
                    ((ushort_t*)C)[addr] = f2b(vv);
                } else {
                    ((float*)C)[(size_t)row * Nn + col] = vv;
                }
            }
        }
}

// ---------- pass A: rowsum + PV; 2 rowblks/wave; ct-split x4 -----------------
// grid (NT/128, NH, QSPLIT). Per staged K-tile: 2x compute (rowsets).
__global__ __launch_bounds__(256) void rowsum_pv(
    const f16* __restrict__ Qt0, const f16* __restrict__ Qt1,
    const f16* __restrict__ Kt0, const f16* __restrict__ Kt1,
    const ushort_t* __restrict__ Vp,
    float* __restrict__ rsPart, ushort_t* __restrict__ part_pv)
{
    __shared__ __align__(16) f16 KL[2][6144];   // [plane][12 tiles of 512]
    const int tid = threadIdx.x;
    const int wv = tid >> 6, lane = tid & 63;
    const int r = lane & 15, g = lane >> 4;
    const int h = blockIdx.y;
    const int quar = blockIdx.z;
    const int rowblk0 = blockIdx.x * 8 + wv;    // rowsets: rowblk0, rowblk0+4
    // Q fragments for both rowsets (B operand of swapped MFMA)
    f16x8 a0[2][3], a1[2][3];
#pragma unroll
    for (int rr = 0; rr < 2; ++rr)
#pragma unroll
        for (int ks = 0; ks < 3; ++ks) {
            size_t o = ((((size_t)h * 256 + rowblk0 + rr * 4) * 3 + ks) * 16) * 32 + r * 32 + g * 8;
            a0[rr][ks] = *(const f16x8*)(Qt0 + o);
            a1[rr][ks] = *(const f16x8*)(Qt1 + o);
        }
    // permuted per-lane K read columns: c32 = (r>>2)*8 + cfp*4 + (r&3)
    const int c32p0 = ((r >> 2) << 3) + (r & 3);
    float rs[2] = {0.f, 0.f};
    f32x4 oacc[2][5] = {};
    for (int ct = quar * 16; ct < quar * 16 + 16; ++ct) {
        __syncthreads();
        const size_t ctBase = ((size_t)h * 256 + ct * 4) * 1536;
#pragma unroll
        for (int s = 0; s < 6; ++s) {
            int wc = s * 4 + wv;             // 0..23 wave-chunks of 1024B
            int plane = wc >= 12;
            int cip = wc - plane * 12;
            const f16* src = (plane ? Kt1 : Kt0) + ctBase + cip * 512 + lane * 8;
            *(f16x8*)&KL[plane][cip * 512 + lane * 8] = *(const f16x8*)src;
        }
        __syncthreads();
        const int kt0 = ct * 2;
#pragma unroll
        for (int rr = 0; rr < 2; ++rr) {
            f32x4 accM[4] = {}, accC[4] = {};
#pragma unroll
            for (int ks = 0; ks < 3; ++ks) {
#pragma unroll
                for (int group = 0; group < 2; ++group) {
#pragma unroll
                    for (int cfp = 0; cfp < 2; ++cfp) {
                        const int c32 = c32p0 + cfp * 4;
                        const int off = (((group * 2 + (c32 >> 4)) * 3 + ks) << 9)
                                      + ((c32 & 15) << 5) + (g << 3);
                        f16x8 b0 = *(const f16x8*)&KL[0][off];
                        f16x8 b1 = *(const f16x8*)&KL[1][off];
                        const int cf = group * 2 + cfp;
                        accM[cf] = MFMA16(b0, a0[rr][ks], accM[cf]);
                        accC[cf] = MFMA16(b1, a0[rr][ks], accC[cf]);
                        accC[cf] = MFMA16(b0, a1[rr][ks], accC[cf]);
                    }
                }
            }
            // exp -> rs + cvt_pk bf16 pack -> PV
#pragma unroll
            for (int group = 0; group < 2; ++group) {
                float e[8];
#pragma unroll
                for (int cfp = 0; cfp < 2; ++cfp) {
                    const int cf = group * 2 + cfp;
#pragma unroll
                    for (int j = 0; j < 4; ++j) {
                        float ev = __expf(accM[cf][j] + accC[cf][j] * INV_RSPLIT);
                        rs[rr] += ev;
                        e[cfp * 4 + j] = ev;
                    }
                }
                union { bf16x8 v; unsigned w[4]; } pa;
#pragma unroll
                for (int wi = 0; wi < 4; ++wi) {
                    unsigned rw;
                    asm("v_cvt_pk_bf16_f32 %0, %1, %2"
                        : "=v"(rw) : "v"(e[wi * 2]), "v"(e[wi * 2 + 1]));
                    pa.w[wi] = rw;
                }
#pragma unroll
                for (int t = 0; t < 5; ++t) {
                    int col = t * 16 + r;
                    size_t vo = (((size_t)h * 128 + kt0 + group) * 80 + col) * 32 + g * 8;
                    bf16x8 b = *(const bf16x8*)(Vp + vo);
                    oacc[rr][t] = MFMABF(pa.v, b, oacc[rr][t]);
                }
            }
        }
    }
#pragma unroll
    for (int rr = 0; rr < 2; ++rr) {
        const int rowblk = rowblk0 + rr * 4;
        float rsv = rs[rr];
        rsv += __shfl_xor(rsv, 16);
        rsv += __shfl_xor(rsv, 32);
        if (g == 0)
            rsPart[((size_t)quar * NH + h) * NT + rowblk * 16 + r] = rsv;
#pragma unroll
        for (int t = 0; t < 5; ++t) {
            int col = t * 16 + r;
            if (col < DH) {
#pragma unroll
                for (int j = 0; j < 4; ++j) {
                    int row = rowblk * 16 + g * 4 + j;
                    part_pv[(((size_t)quar * NH + h) * NT + row) * DH + col] = f2b(oacc[rr][t][j]);
                }
            }
        }
    }
}

// ---------- combine rowsum/PV quarters: invs + normalized otmpb --------------
__global__ __launch_bounds__(256) void pv_norm(
    const float* __restrict__ rsPart, const ushort_t* __restrict__ part_pv,
    float* __restrict__ invs, ushort_t* __restrict__ otmpb)
{
    __shared__ float sinv[32];
    const int h = blockIdx.x;
    const int row0 = blockIdx.y * 32;
    const int tid = threadIdx.x;
    if (tid < 32) {
        float s = 0.f;
#pragma unroll
        for (int q = 0; q < QSPLIT; ++q)
            s += rsPart[((size_t)q * NH + h) * NT + row0 + tid];
        float inv = 1.0f / s;
        sinv[tid] = inv;
        invs[(size_t)h * NT + row0 + tid] = inv;
    }
    __syncthreads();
    for (int e = tid; e < 32 * DH; e += 256) {
        int rr = e / DH, col = e - rr * DH;
        int row = row0 + rr;
        float s = 0.f;
#pragma unroll
        for (int q = 0; q < QSPLIT; ++q)
            s += b2f(part_pv[(((size_t)q * NH + h) * NT + row) * DH + col]);
        otmpb[(size_t)row * DM + h * DH + col] = f2b(s * sinv[rr]);
    }
}

// ---------- pass B: attn head-sum; 2 rowblks/wave; 64 col-slices -------------
// grid (ACSB, NT/128). Per staged K-tile (per head): 2x compute.
__global__ __launch_bounds__(256) void attn_sum(
    const f16* __restrict__ Qt0, const f16* __restrict__ Qt1,
    const f16* __restrict__ Kt0, const f16* __restrict__ Kt1,
    const float* __restrict__ invs, float* __restrict__ attn)
{
    __shared__ __align__(16) f16 KL[2][6144];   // [plane][12 tiles of 512]
    const int tid = threadIdx.x;
    const int wr = tid >> 6, lane = tid & 63;
    const int r = lane & 15, g = lane >> 4;
    const int cs = blockIdx.x;
    const int rowblk0 = blockIdx.y * 8 + wr;    // rowsets: rowblk0, rowblk0+4
    const int cb0 = cs * 4;                     // colblk base (64 cols/slice)
    float aacc[2][4][4] = {};                   // [rowset][cf][j]
    for (int h = 0; h < NH; ++h) {
        f16x8 a0[2][3], a1[2][3];
        float vinv[2][4];
#pragma unroll
        for (int rr = 0; rr < 2; ++rr) {
            const int rowblk = rowblk0 + rr * 4;
#pragma unroll
            for (int ks = 0; ks < 3; ++ks) {
                size_t o = ((((size_t)h * 256 + rowblk) * 3 + ks) * 16) * 32 + r * 32 + g * 8;
                a0[rr][ks] = *(const f16x8*)(Qt0 + o);
                a1[rr][ks] = *(const f16x8*)(Qt1 + o);
            }
#pragma unroll
            for (int j = 0; j < 4; ++j)
                vinv[rr][j] = invs[(size_t)h * NT + rowblk * 16 + g * 4 + j];
        }
        __syncthreads();
        const size_t ctBase = ((size_t)h * 256 + cb0) * 1536;
#pragma unroll
        for (int s = 0; s < 6; ++s) {
            int wc = s * 4 + wr;                // 0..23 wave-chunks of 1024B
            int plane = wc >= 12;
            int cip = wc - plane * 12;
            const f16* src = (plane ? Kt1 : Kt0) + ctBase + cip * 512 + lane * 8;
            *(f16x8*)&KL[plane][cip * 512 + lane * 8] = *(const f16x8*)src;
        }
        __syncthreads();
#pragma unroll
        for (int rr = 0; rr < 2; ++rr) {
            f32x4 accM[4] = {}, accC[4] = {};
#pragma unroll
            for (int ks = 0; ks < 3; ++ks) {
#pragma unroll
                for (int cf = 0; cf < 4; ++cf) {
                    f16x8 b0 = *(const f16x8*)&KL[0][(cf * 3 + ks) * 512 + r * 32 + g * 8];
                    f16x8 b1 = *(const f16x8*)&KL[1][(cf * 3 + ks) * 512 + r * 32 + g * 8];
                    accM[cf] = MFMA16(a0[rr][ks], b0, accM[cf]);
                    accC[cf] = MFMA16(a0[rr][ks], b1, accC[cf]);
                    accC[cf] = MFMA16(a1[rr][ks], b0, accC[cf]);
                }
            }
#pragma unroll
            for (int cf = 0; cf < 4; ++cf) {
#pragma unroll
                for (int j = 0; j < 4; ++j) {
                    float p = __expf(accM[cf][j] + accC[cf][j] * INV_RSPLIT) * vinv[rr][j];
                    aacc[rr][cf][j] += p;
                }
            }
        }
    }
    // write attn once (no rmw)
    const int colbase = cs * 64;
#pragma unroll
    for (int rr = 0; rr < 2; ++rr) {
        const int row0 = (rowblk0 + rr * 4) * 16;
#pragma unroll
        for (int cf = 0; cf < 4; ++cf) {
#pragma unroll
            for (int j = 0; j < 4; ++j) {
                int row = row0 + g * 4 + j;
                attn[(size_t)row * NT + colbase + cf * 16 + r] = aacc[rr][cf][j] * 0.0625f;
            }
        }
    }
}

// ---------- pagerank power iteration (fp32, unchanged) -----------------------
__global__ __launch_bounds__(256) void init_dist(float* __restrict__ d)
{
    int t = blockIdx.x * 256 + threadIdx.x;
    if (t < NT) d[t] = 1.0f / NT;
}

__global__ __launch_bounds__(256) void power_a(
    const float* __restrict__ attn, const float* __restrict__ din,
    float* __restrict__ part)
{
    int j = blockIdx.x * 256 + threadIdx.x;
    int i0 = blockIdx.y * 128;
    float acc = 0.f;
    for (int i = i0; i < i0 + 128; ++i)
        acc += din[i] * attn[(size_t)i * NT + j];
    part[(size_t)blockIdx.y * NT + j] = acc;
}

__global__ __launch_bounds__(256) void power_b(
    const float* __restrict__ part, float* __restrict__ dout)
{
    int j = blockIdx.x * 256 + threadIdx.x;
    float acc = 0.f;
    for (int ib = 0; ib < 32; ++ib) acc += part[(size_t)ib * NT + j];
    dout[j] = acc;
}

// ---------- top-k: tiled rank counting (deterministic int atomics) -----------
__global__ __launch_bounds__(256) void rank_count(
    const float* __restrict__ imp, int* __restrict__ rank, int* __restrict__ prank)
{
    __shared__ float sj[256];
    const int tid = threadIdx.x;
    const int jb = blockIdx.y * 256;
    sj[tid] = imp[jb + tid];
    __syncthreads();
    const int i = blockIdx.x * 256 + tid;
    const float mv = imp[i];
    int r = 0, rp = 0;
    for (int jj = 0; jj < 256; ++jj) {
        float vj = sj[jj];
        int j = jb + jj;
        int tie_low = (vj == mv) && (j < i);
        r  += (vj > mv) || tie_low;
        rp += (vj < mv) || tie_low;
    }
    atomicAdd(&rank[i], r);
    atomicAdd(&prank[i], rp);
}

__global__ __launch_bounds__(256) void scatter_topk2(
    const int* __restrict__ rank, const int* __restrict__ prank,
    float* __restrict__ out_imps, float* __restrict__ out_prune,
    int* __restrict__ imp_rows, int* __restrict__ prune_cols)
{
    __shared__ unsigned char fr[NT];
    __shared__ unsigned char fp[NT];
    __shared__ int sr[256], sp[256];
    const int tid = threadIdx.x;
    for (int t = tid; t < NT; t += 256) {
        fr[t] = rank[t] < KRET;
        fp[t] = prank[t] < NPR;
    }
    __syncthreads();
    const int base = tid * 16;
    int cr = 0, cp = 0;
#pragma unroll
    for (int e = 0; e < 16; ++e) { cr += fr[base + e]; cp += fp[base + e]; }
    sr[tid] = cr; sp[tid] = cp;
    __syncthreads();
    int pr = 0, pp = 0;
    for (int j = 0; j < tid; ++j) { pr += sr[j]; pp += sp[j]; }
#pragma unroll
    for (int e = 0; e < 16; ++e) {
        int i = base + e;
        if (fr[i]) { out_imps[pr] = (float)i; imp_rows[pr] = i; ++pr; }
        if (fp[i]) { out_prune[pp] = (float)i; prune_cols[pp] = i; ++pp; }
    }
}

__global__ __launch_bounds__(256) void argmax_part(
    const float* __restrict__ attn, const int* __restrict__ imp_rows,
    float* __restrict__ pbest, int* __restrict__ pbi)
{
    __shared__ int rows[CHUNK];
    const int tid = threadIdx.x;
    const int rc = blockIdx.y;
    const int r0 = rc * CHUNK;
    const int nr = min(KRET - r0, CHUNK);
    for (int t = tid; t < nr; t += 256) rows[t] = imp_rows[r0 + t];
    __syncthreads();
    const int j = blockIdx.x * 256 + tid;
    float best = -INFINITY;
    int bi = 0;
    for (int rr = 0; rr < nr; ++rr) {
        float val = attn[(size_t)rows[rr] * NT + j];
        if (val > best) { best = val; bi = r0 + rr; }
    }
    pbest[(size_t)rc * NT + j] = best;
    pbi[(size_t)rc * NT + j] = bi;
}

__global__ __launch_bounds__(256) void argmax_red(
    const float* __restrict__ pbest, const int* __restrict__ pbi,
    int* __restrict__ maxind)
{
    const int j = blockIdx.x * 256 + threadIdx.x;
    float best = -INFINITY;
    int bi = 0;
#pragma unroll
    for (int rc = 0; rc < 8; ++rc) {
        float val = pbest[(size_t)rc * NT + j];
        if (val > best) { best = val; bi = pbi[(size_t)rc * NT + j]; }
    }
    maxind[j] = bi;
}

__global__ __launch_bounds__(256) void finalize(
    const float* __restrict__ dist, const int* __restrict__ prune_cols,
    const int* __restrict__ maxind, float* __restrict__ out_imp,
    float* __restrict__ out_simi)
{
    int t = blockIdx.x * 256 + threadIdx.x;
    if (t < NT) out_imp[t] = dist[t];
    if (t < NPR) out_simi[t] = (float)maxind[prune_cols[t]];
}

extern "C" void kernel_launch(void* const* d_in, const int* in_sizes, int n_in,
                              void* d_out, int out_size, void* d_ws, size_t ws_size,
                              hipStream_t stream)
{
    const float* x  = (const float*)d_in[0];
    const float* Wq = (const float*)d_in[1];
    const float* Wk = (const float*)d_in[2];
    const float* Wv = (const float*)d_in[3];
    const float* Wo = (const float*)d_in[4];
    const float* bo = (const float*)d_in[5];
    float* out = (float*)d_out;

    const size_t QKT_EL = (size_t)NH * 256 * 3 * 16 * 32;   // 6.29M f16 per plane
    const size_t VP_EL  = (size_t)NH * 128 * 80 * 32;       // 5.24M bf16

    // ---- workspace layout (float units), ~166 MB with aliasing ----
    float* ws = (float*)d_ws;
    size_t off = 0;
    float* attn = ws + off; off += (size_t)NT * NT;
    f16* Qt0 = (f16*)(ws + off); off += QKT_EL / 2;
    f16* Qt1 = (f16*)(ws + off); off += QKT_EL / 2;
    f16* Kt0 = (f16*)(ws + off); off += QKT_EL / 2;
    f16* Kt1 = (f16*)(ws + off); off += QKT_EL / 2;
    ushort_t* Vp = (ushort_t*)(ws + off); off += VP_EL / 2;
    size_t zero_floats = 4 * (QKT_EL / 2) + VP_EL / 2;      // Qt0..Vp contiguous
    ushort_t* otmpb = (ushort_t*)(ws + off); off += ((size_t)NT * DM) / 2;
    f16* X0 = (f16*)(ws + off); f16* X1 = X0 + (size_t)NT * DM;
    float* xs_base = ws + off; off += (size_t)NT * DM;
    f16* T0 = (f16*)(ws + off); f16* T1 = T0 + (size_t)DM * DM; off += (size_t)DM * DM;
    ushort_t* Wslot = (ushort_t*)(ws + off); off += ((size_t)DM * DM) / 2;
    float* invs    = ws + off; off += (size_t)NH * NT;
    float* pbest   = ws + off; off += 8 * NT;
    int*   pbi     = (int*)(ws + off); off += 8 * NT;
    float* dist0 = ws + off; off += NT;
    float* dist1 = ws + off; off += NT;
    float* partial = ws + off; off += 32 * NT;
    int* rank      = (int*)(ws + off); off += NT;
    int* prank     = (int*)(ws + off); off += NT;
    int* imp_rows  = (int*)(ws + off); off += 2048;
    int* prune_cols= (int*)(ws + off); off += 2560;
    int* maxind    = (int*)(ws + off); off += NT;

    // aliases (lifetime-checked):
    //   xb (setup only) and part_pv (pass A only) live inside attn;
    //   rsPart lives inside the dead X-split region after projections.
    ushort_t* xb = (ushort_t*)attn;
    ushort_t* part_pv = (ushort_t*)attn;       // QSPLIT*NH*NT*DH bf16 = 37.7 MB
    float* rsPart = xs_base;                   // QSPLIT*NH*NT fp32 = 1 MB

    // output layout
    float* out_out   = out;
    float* out_imp   = out + (size_t)NT * DM;
    float* out_imps  = out_imp + NT;
    float* out_prune = out_imps + KRET;
    float* out_simi  = out_prune + NPR;

    // ---- setup ----
    hipMemsetAsync(Qt0, 0, zero_floats * sizeof(float), stream);  // zero-pad tiles
    split_x<<<2048, 256, 0, stream>>>(x, X0, X1, xb, NT * DM);

    dim3 gT(DM / 32, DM / 32);
    dim3 gP(DM / 64, NT / 128);
    transposeW_split<<<gT, 256, 0, stream>>>(Wq, T0, T1, DM);
    proj_split3<<<gP, 256, 0, stream>>>(X0, X1, T0, T1, Qt0, Qt1, SCALE);
    transposeW_split<<<gT, 256, 0, stream>>>(Wk, T0, T1, DM);
    proj_split3<<<gP, 256, 0, stream>>>(X0, X1, T0, T1, Kt0, Kt1, 1.0f);

    transposeW_bf16<<<gT, 256, 0, stream>>>(Wv, Wslot, DM);
    gemm_bf16_lds<<<gP, 256, 0, stream>>>(xb, Wslot, nullptr, Vp, 2, DM, DM);

    // ---- pass A: rowsums + PV, 2 rowblks/wave, ct-split x4 ----
    rowsum_pv<<<dim3(NT / 128, NH, QSPLIT), 256, 0, stream>>>(Qt0, Qt1, Kt0, Kt1, Vp,
                                                              rsPart, part_pv);
    pv_norm<<<dim3(NH, NT / 32), 256, 0, stream>>>(rsPart, part_pv, invs, otmpb);

    // ---- pass B: attn head-sum, 2 rowblks/wave, 64 col-slices ----
    attn_sum<<<dim3(ACSB, NT / 128), 256, 0, stream>>>(Qt0, Qt1, Kt0, Kt1, invs, attn);

    // ---- output projection ----
    transposeW_bf16<<<gT, 256, 0, stream>>>(Wo, Wslot, DM);
    gemm_bf16_lds<<<gP, 256, 0, stream>>>(otmpb, Wslot, bo, out_out, 0, DM, DM);

    // ---- pagerank ----
    init_dist<<<16, 256, 0, stream>>>(dist0);
    float* da = dist0;
    float* db = dist1;
    for (int it = 0; it < 5; ++it) {
        power_a<<<dim3(16, 32), 256, 0, stream>>>(attn, da, partial);
        power_b<<<16, 256, 0, stream>>>(partial, db);
        float* t = da; da = db; db = t;
    }

    // ---- top-k ----
    hipMemsetAsync(rank, 0, 2 * NT * sizeof(int), stream);
    rank_count<<<dim3(16, 16), 256, 0, stream>>>(da, rank, prank);
    scatter_topk2<<<1, 256, 0, stream>>>(rank, prank, out_imps, out_prune,
                                         imp_rows, prune_cols);
    argmax_part<<<dim3(16, 8), 256, 0, stream>>>(attn, imp_rows, pbest, pbi);
    argmax_red<<<16, 256, 0, stream>>>(pbest, pbi, maxind);
    finalize<<<16, 256, 0, stream>>>(da, prune_cols, maxind, out_imp, out_simi);
}

// Round 18
// 797.933 us; speedup vs baseline: 1.4921x; 1.0308x over previous
//
#include <hip/hip_runtime.h>
#include <math.h>

#define NT 4096
#define DM 1152
#define NH 16
#define DH 72
#define KRET 1638
#define NPR (NT - KRET)
#define QSPLIT 4
#define ACSB 64
#define CHUNK 205
#define SCALE 0.11785113019775793f
#define RSPLIT 2048.0f
#define INV_RSPLIT 4.8828125e-4f

typedef __attribute__((ext_vector_type(8))) short bf16x8;
typedef _Float16 f16;
typedef __attribute__((ext_vector_type(8))) _Float16 f16x8;
typedef __attribute__((ext_vector_type(4))) float f32x4;
typedef unsigned short ushort_t;

#define MFMA16(a, b, c) __builtin_amdgcn_mfma_f32_16x16x32_f16(a, b, c, 0, 0, 0)
#define MFMABF(a, b, c) __builtin_amdgcn_mfma_f32_16x16x32_bf16(a, b, c, 0, 0, 0)

__device__ inline ushort_t f2b(float f) {
    union { float f; unsigned int u; } v; v.f = f;
    unsigned int u = v.u;
    return (ushort_t)((u + 0x7FFFu + ((u >> 16) & 1u)) >> 16);
}

__device__ inline float b2f(ushort_t u) {
    union { unsigned int u; float f; } v; v.u = ((unsigned int)u) << 16;
    return v.f;
}

// tiled Q/K address: [NH][rowblk 256][ks 3][r 16][ki 32]
__device__ inline size_t qkAddr(int h, int row, int ks, int ki) {
    return ((((size_t)h * 256 + (row >> 4)) * 3 + ks) * 16 + (row & 15)) * 32 + ki;
}

// ---------- split x into fp16 hi/lo(x2048) planes + bf16 copy ----------------
__global__ __launch_bounds__(256) void split_x(
    const float* __restrict__ in, f16* __restrict__ x0, f16* __restrict__ x1,
    ushort_t* __restrict__ xb, int nElem)
{
    int i = blockIdx.x * 256 + threadIdx.x;
    int stride = gridDim.x * 256;
    for (; i < nElem; i += stride) {
        float v = in[i];
        f16 h0 = (f16)v;
        float res = (v - (float)h0) * RSPLIT;
        x0[i] = h0;
        x1[i] = (f16)res;
        xb[i] = f2b(v);
    }
}

__global__ __launch_bounds__(256) void transposeW_split(
    const float* __restrict__ W, f16* __restrict__ T0, f16* __restrict__ T1, int n)
{
    __shared__ float t[32][33];
    int bx = blockIdx.x * 32, by = blockIdx.y * 32;
    int tx = threadIdx.x & 31, ty = threadIdx.x >> 5;
    for (int i = ty; i < 32; i += 8)
        t[i][tx] = W[(size_t)(by + i) * n + bx + tx];
    __syncthreads();
    for (int i = ty; i < 32; i += 8) {
        float v = t[tx][i];
        f16 h0 = (f16)v;
        float res = (v - (float)h0) * RSPLIT;
        T0[(size_t)(bx + i) * n + by + tx] = h0;
        T1[(size_t)(bx + i) * n + by + tx] = (f16)res;
    }
}

__global__ __launch_bounds__(256) void transposeW_bf16(
    const float* __restrict__ W, ushort_t* __restrict__ WT, int n)
{
    __shared__ ushort_t t[32][33];
    int bx = blockIdx.x * 32, by = blockIdx.y * 32;
    int tx = threadIdx.x & 31, ty = threadIdx.x >> 5;
    for (int i = ty; i < 32; i += 8)
        t[i][tx] = f2b(W[(size_t)(by + i) * n + bx + tx]);
    __syncthreads();
    for (int i = ty; i < 32; i += 8)
        WT[(size_t)(bx + i) * n + by + tx] = t[tx][i];
}

// ---------- LDS-tiled split projection -> MFMA-tiled per-head output ---------
__global__ __launch_bounds__(256) void proj_split3(
    const f16* __restrict__ A0, const f16* __restrict__ A1,
    const f16* __restrict__ B0, const f16* __restrict__ B1,
    f16* __restrict__ Qt0, f16* __restrict__ Qt1, float scl)
{
    __shared__ __align__(16) f16 As0[128][40];
    __shared__ __align__(16) f16 As1[128][40];
    __shared__ __align__(16) f16 Bs0[64][40];
    __shared__ __align__(16) f16 Bs1[64][40];
    const int tid = threadIdx.x;
    const int wave = tid >> 6, lane = tid & 63;
    const int r = lane & 15, g = lane >> 4;
    const int row0 = blockIdx.y * 128;
    const int col0 = blockIdx.x * 64;
    f32x4 accM[2][4] = {}, accC[2][4] = {};
    for (int k0 = 0; k0 < DM; k0 += 32) {
        for (int idx = tid; idx < 128 * 4; idx += 256) {
            int row = idx >> 2, c = idx & 3;
            size_t src = (size_t)(row0 + row) * DM + k0 + c * 8;
            *(f16x8*)&As0[row][c * 8] = *(const f16x8*)(A0 + src);
            *(f16x8*)&As1[row][c * 8] = *(const f16x8*)(A1 + src);
        }
        for (int idx = tid; idx < 64 * 4; idx += 256) {
            int row = idx >> 2, c = idx & 3;
            size_t src = (size_t)(col0 + row) * DM + k0 + c * 8;
            *(f16x8*)&Bs0[row][c * 8] = *(const f16x8*)(B0 + src);
            *(f16x8*)&Bs1[row][c * 8] = *(const f16x8*)(B1 + src);
        }
        __syncthreads();
        f16x8 a0[2], a1[2], b0[4], b1[4];
#pragma unroll
        for (int rf = 0; rf < 2; ++rf) {
            a0[rf] = *(const f16x8*)&As0[wave * 32 + rf * 16 + r][g * 8];
            a1[rf] = *(const f16x8*)&As1[wave * 32 + rf * 16 + r][g * 8];
        }
#pragma unroll
        for (int cf = 0; cf < 4; ++cf) {
            b0[cf] = *(const f16x8*)&Bs0[cf * 16 + r][g * 8];
            b1[cf] = *(const f16x8*)&Bs1[cf * 16 + r][g * 8];
        }
#pragma unroll
        for (int rf = 0; rf < 2; ++rf)
#pragma unroll
            for (int cf = 0; cf < 4; ++cf) {
                accM[rf][cf] = MFMA16(a0[rf], b0[cf], accM[rf][cf]);
                accC[rf][cf] = MFMA16(a0[rf], b1[cf], accC[rf][cf]);
                accC[rf][cf] = MFMA16(a1[rf], b0[cf], accC[rf][cf]);
            }
        __syncthreads();
    }
#pragma unroll
    for (int rf = 0; rf < 2; ++rf)
#pragma unroll
        for (int cf = 0; cf < 4; ++cf) {
            int col = col0 + cf * 16 + r;
            int head = col / DH;
            int c = col - head * DH;
            int ks = c >> 5, ki = c & 31;
#pragma unroll
            for (int j = 0; j < 4; ++j) {
                int row = row0 + wave * 32 + rf * 16 + g * 4 + j;
                float v = (accM[rf][cf][j] + accC[rf][cf][j] * INV_RSPLIT) * scl;
                f16 h0 = (f16)v;
                float res = (v - (float)h0) * RSPLIT;
                size_t addr = qkAddr(head, row, ks, ki);
                Qt0[addr] = h0;
                Qt1[addr] = (f16)res;
            }
        }
}

// ---------- LDS-tiled bf16 MFMA GEMM; mode 0 = fp32 flat, 2 = Vp tiled -------
__global__ __launch_bounds__(256) void gemm_bf16_lds(
    const ushort_t* __restrict__ A, const ushort_t* __restrict__ BT,
    const float* __restrict__ bias, void* __restrict__ C, int mode,
    int Nn, int K)
{
    __shared__ __align__(16) ushort_t As[128][40];
    __shared__ __align__(16) ushort_t Bs[64][40];
    const int tid = threadIdx.x;
    const int wave = tid >> 6, lane = tid & 63;
    const int r = lane & 15, g = lane >> 4;
    const int row0 = blockIdx.y * 128;
    const int col0 = blockIdx.x * 64;
    f32x4 acc[2][4] = {};
    for (int k0 = 0; k0 < K; k0 += 32) {
        for (int idx = tid; idx < 128 * 4; idx += 256) {
            int row = idx >> 2, c = idx & 3;
            *(bf16x8*)&As[row][c * 8] = *(const bf16x8*)(A + (size_t)(row0 + row) * K + k0 + c * 8);
        }
        for (int idx = tid; idx < 64 * 4; idx += 256) {
            int row = idx >> 2, c = idx & 3;
            *(bf16x8*)&Bs[row][c * 8] = *(const bf16x8*)(BT + (size_t)(col0 + row) * K + k0 + c * 8);
        }
        __syncthreads();
        bf16x8 a[2], b[4];
#pragma unroll
        for (int rf = 0; rf < 2; ++rf)
            a[rf] = *(const bf16x8*)&As[wave * 32 + rf * 16 + r][g * 8];
#pragma unroll
        for (int cf = 0; cf < 4; ++cf)
            b[cf] = *(const bf16x8*)&Bs[cf * 16 + r][g * 8];
#pragma unroll
        for (int rf = 0; rf < 2; ++rf)
#pragma unroll
            for (int cf = 0; cf < 4; ++cf)
                acc[rf][cf] = MFMABF(a[rf], b[cf], acc[rf][cf]);
        __syncthreads();
    }
#pragma unroll
    for (int rf = 0; rf < 2; ++rf)
#pragma unroll
        for (int cf = 0; cf < 4; ++cf) {
            int col = col0 + cf * 16 + r;
            float bv = bias ? bias[col] : 0.f;
#pragma unroll
            for (int j = 0; j < 4; ++j) {
                int row = row0 + wave * 32 + rf * 16 + g * 4 + j;
                float vv = acc[rf][cf][j] + bv;
                if (mode == 2) {
                    int head = col / DH;
                    int d = col - head * DH;
                    size_t addr = (((size_t)head * 128 + (row >> 5)) * 80 + d) * 32 + (row & 31);
                    ((ushort_t*)C)[addr] = f2b(vv);
                } else {
                    ((float*)C)[(size_t)row * Nn + col] = vv;
                }
            }
        }
}

// ---------- pass A: rowsum + PV, swapped-operand QK, ct-split x4 (r16) -------
// grid (NT/64, NH, QSPLIT). Each quarter: 16 ct-steps; rs fp32 + PV bf16 partials.
__global__ __launch_bounds__(256) void rowsum_pv(
    const f16* __restrict__ Qt0, const f16* __restrict__ Qt1,
    const f16* __restrict__ Kt0, const f16* __restrict__ Kt1,
    const ushort_t* __restrict__ Vp,
    float* __restrict__ rsPart, ushort_t* __restrict__ part_pv)
{
    __shared__ __align__(16) f16 KL[2][6144];   // [plane][12 tiles of 512]
    const int tid = threadIdx.x;
    const int wv = tid >> 6, lane = tid & 63;
    const int r = lane & 15, g = lane >> 4;
    const int h = blockIdx.y;
    const int quar = blockIdx.z;
    const int rowblk = blockIdx.x * 4 + wv;
    // Q fragments (used as the B operand of the swapped MFMA)
    f16x8 a0[3], a1[3];
#pragma unroll
    for (int ks = 0; ks < 3; ++ks) {
        size_t o = ((((size_t)h * 256 + rowblk) * 3 + ks) * 16) * 32 + r * 32 + g * 8;
        a0[ks] = *(const f16x8*)(Qt0 + o);
        a1[ks] = *(const f16x8*)(Qt1 + o);
    }
    // permuted per-lane K read columns: c32 = (r>>2)*8 + cfp*4 + (r&3)
    const int c32p0 = ((r >> 2) << 3) + (r & 3);
    float rs = 0.f;
    f32x4 oacc[5] = {};
    for (int ct = quar * 16; ct < quar * 16 + 16; ++ct) {
        __syncthreads();
        const size_t ctBase = ((size_t)h * 256 + ct * 4) * 1536;
#pragma unroll
        for (int s = 0; s < 6; ++s) {
            int wc = s * 4 + wv;             // 0..23 wave-chunks of 1024B
            int plane = wc >= 12;
            int cip = wc - plane * 12;
            const f16* src = (plane ? Kt1 : Kt0) + ctBase + cip * 512 + lane * 8;
            *(f16x8*)&KL[plane][cip * 512 + lane * 8] = *(const f16x8*)src;
        }
        __syncthreads();
        f32x4 accM[4] = {}, accC[4] = {};
#pragma unroll
        for (int ks = 0; ks < 3; ++ks) {
#pragma unroll
            for (int group = 0; group < 2; ++group) {
#pragma unroll
                for (int cfp = 0; cfp < 2; ++cfp) {
                    const int c32 = c32p0 + cfp * 4;
                    const int off = (((group * 2 + (c32 >> 4)) * 3 + ks) << 9)
                                  + ((c32 & 15) << 5) + (g << 3);
                    f16x8 b0 = *(const f16x8*)&KL[0][off];
                    f16x8 b1 = *(const f16x8*)&KL[1][off];
                    const int cf = group * 2 + cfp;
                    accM[cf] = MFMA16(b0, a0[ks], accM[cf]);
                    accC[cf] = MFMA16(b1, a0[ks], accC[cf]);
                    accC[cf] = MFMA16(b0, a1[ks], accC[cf]);
                }
            }
        }
        // exp -> rs + cvt_pk bf16 pack -> PV
        const int kt0 = ct * 2;
#pragma unroll
        for (int group = 0; group < 2; ++group) {
            float e[8];
#pragma unroll
            for (int cfp = 0; cfp < 2; ++cfp) {
                const int cf = group * 2 + cfp;
#pragma unroll
                for (int j = 0; j < 4; ++j) {
                    float ev = __expf(accM[cf][j] + accC[cf][j] * INV_RSPLIT);
                    rs += ev;
                    e[cfp * 4 + j] = ev;
                }
            }
            union { bf16x8 v; unsigned w[4]; } pa;
#pragma unroll
            for (int wi = 0; wi < 4; ++wi) {
                unsigned rw;
                asm("v_cvt_pk_bf16_f32 %0, %1, %2"
                    : "=v"(rw) : "v"(e[wi * 2]), "v"(e[wi * 2 + 1]));
                pa.w[wi] = rw;
            }
#pragma unroll
            for (int t = 0; t < 5; ++t) {
                int col = t * 16 + r;
                size_t vo = (((size_t)h * 128 + kt0 + group) * 80 + col) * 32 + g * 8;
                bf16x8 b = *(const bf16x8*)(Vp + vo);
                oacc[t] = MFMABF(pa.v, b, oacc[t]);
            }
        }
    }
    // rs is per-lane partial for q-row r; reduce over the 4 g-groups
    rs += __shfl_xor(rs, 16);
    rs += __shfl_xor(rs, 32);
    if (g == 0)
        rsPart[((size_t)quar * NH + h) * NT + rowblk * 16 + r] = rs;
    // unnormalized PV partial (bf16)
#pragma unroll
    for (int t = 0; t < 5; ++t) {
        int col = t * 16 + r;
        if (col < DH) {
#pragma unroll
            for (int j = 0; j < 4; ++j) {
                int row = rowblk * 16 + g * 4 + j;
                part_pv[(((size_t)quar * NH + h) * NT + row) * DH + col] = f2b(oacc[t][j]);
            }
        }
    }
}

// ---------- combine rowsum/PV quarters: invs + normalized otmpb --------------
__global__ __launch_bounds__(256) void pv_norm(
    const float* __restrict__ rsPart, const ushort_t* __restrict__ part_pv,
    float* __restrict__ invs, ushort_t* __restrict__ otmpb)
{
    __shared__ float sinv[32];
    const int h = blockIdx.x;
    const int row0 = blockIdx.y * 32;
    const int tid = threadIdx.x;
    if (tid < 32) {
        float s = 0.f;
#pragma unroll
        for (int q = 0; q < QSPLIT; ++q)
            s += rsPart[((size_t)q * NH + h) * NT + row0 + tid];
        float inv = 1.0f / s;
        sinv[tid] = inv;
        invs[(size_t)h * NT + row0 + tid] = inv;
    }
    __syncthreads();
    for (int e = tid; e < 32 * DH; e += 256) {
        int rr = e / DH, col = e - rr * DH;
        int row = row0 + rr;
        float s = 0.f;
#pragma unroll
        for (int q = 0; q < QSPLIT; ++q)
            s += b2f(part_pv[(((size_t)q * NH + h) * NT + row) * DH + col]);
        otmpb[(size_t)row * DM + h * DH + col] = f2b(s * sinv[rr]);
    }
}

// ---------- pass B: attn head-sum; 2 rowblks/wave; 64 col-slices (r17) -------
// grid (ACSB, NT/128). Per staged K-tile (per head): 2x compute.
__global__ __launch_bounds__(256) void attn_sum(
    const f16* __restrict__ Qt0, const f16* __restrict__ Qt1,
    const f16* __restrict__ Kt0, const f16* __restrict__ Kt1,
    const float* __restrict__ invs, float* __restrict__ attn)
{
    __shared__ __align__(16) f16 KL[2][6144];   // [plane][12 tiles of 512]
    const int tid = threadIdx.x;
    const int wr = tid >> 6, lane = tid & 63;
    const int r = lane & 15, g = lane >> 4;
    const int cs = blockIdx.x;
    const int rowblk0 = blockIdx.y * 8 + wr;    // rowsets: rowblk0, rowblk0+4
    const int cb0 = cs * 4;                     // colblk base (64 cols/slice)
    float aacc[2][4][4] = {};                   // [rowset][cf][j]
    for (int h = 0; h < NH; ++h) {
        f16x8 a0[2][3], a1[2][3];
        float vinv[2][4];
#pragma unroll
        for (int rr = 0; rr < 2; ++rr) {
            const int rowblk = rowblk0 + rr * 4;
#pragma unroll
            for (int ks = 0; ks < 3; ++ks) {
                size_t o = ((((size_t)h * 256 + rowblk) * 3 + ks) * 16) * 32 + r * 32 + g * 8;
                a0[rr][ks] = *(const f16x8*)(Qt0 + o);
                a1[rr][ks] = *(const f16x8*)(Qt1 + o);
            }
#pragma unroll
            for (int j = 0; j < 4; ++j)
                vinv[rr][j] = invs[(size_t)h * NT + rowblk * 16 + g * 4 + j];
        }
        __syncthreads();
        const size_t ctBase = ((size_t)h * 256 + cb0) * 1536;
#pragma unroll
        for (int s = 0; s < 6; ++s) {
            int wc = s * 4 + wr;                // 0..23 wave-chunks of 1024B
            int plane = wc >= 12;
            int cip = wc - plane * 12;
            const f16* src = (plane ? Kt1 : Kt0) + ctBase + cip * 512 + lane * 8;
            *(f16x8*)&KL[plane][cip * 512 + lane * 8] = *(const f16x8*)src;
        }
        __syncthreads();
#pragma unroll
        for (int rr = 0; rr < 2; ++rr) {
            f32x4 accM[4] = {}, accC[4] = {};
#pragma unroll
            for (int ks = 0; ks < 3; ++ks) {
#pragma unroll
                for (int cf = 0; cf < 4; ++cf) {
                    f16x8 b0 = *(const f16x8*)&KL[0][(cf * 3 + ks) * 512 + r * 32 + g * 8];
                    f16x8 b1 = *(const f16x8*)&KL[1][(cf * 3 + ks) * 512 + r * 32 + g * 8];
                    accM[cf] = MFMA16(a0[rr][ks], b0, accM[cf]);
                    accC[cf] = MFMA16(a0[rr][ks], b1, accC[cf]);
                    accC[cf] = MFMA16(a1[rr][ks], b0, accC[cf]);
                }
            }
#pragma unroll
            for (int cf = 0; cf < 4; ++cf) {
#pragma unroll
                for (int j = 0; j < 4; ++j) {
                    float p = __expf(accM[cf][j] + accC[cf][j] * INV_RSPLIT) * vinv[rr][j];
                    aacc[rr][cf][j] += p;
                }
            }
        }
    }
    // write attn once (no rmw)
    const int colbase = cs * 64;
#pragma unroll
    for (int rr = 0; rr < 2; ++rr) {
        const int row0 = (rowblk0 + rr * 4) * 16;
#pragma unroll
        for (int cf = 0; cf < 4; ++cf) {
#pragma unroll
            for (int j = 0; j < 4; ++j) {
                int row = row0 + g * 4 + j;
                attn[(size_t)row * NT + colbase + cf * 16 + r] = aacc[rr][cf][j] * 0.0625f;
            }
        }
    }
}

// ---------- pagerank power iteration (fp32, unchanged) -----------------------
__global__ __launch_bounds__(256) void init_dist(float* __restrict__ d)
{
    int t = blockIdx.x * 256 + threadIdx.x;
    if (t < NT) d[t] = 1.0f / NT;
}

__global__ __launch_bounds__(256) void power_a(
    const float* __restrict__ attn, const float* __restrict__ din,
    float* __restrict__ part)
{
    int j = blockIdx.x * 256 + threadIdx.x;
    int i0 = blockIdx.y * 128;
    float acc = 0.f;
    for (int i = i0; i < i0 + 128; ++i)
        acc += din[i] * attn[(size_t)i * NT + j];
    part[(size_t)blockIdx.y * NT + j] = acc;
}

__global__ __launch_bounds__(256) void power_b(
    const float* __restrict__ part, float* __restrict__ dout)
{
    int j = blockIdx.x * 256 + threadIdx.x;
    float acc = 0.f;
    for (int ib = 0; ib < 32; ++ib) acc += part[(size_t)ib * NT + j];
    dout[j] = acc;
}

// ---------- top-k: tiled rank counting (deterministic int atomics) -----------
__global__ __launch_bounds__(256) void rank_count(
    const float* __restrict__ imp, int* __restrict__ rank, int* __restrict__ prank)
{
    __shared__ float sj[256];
    const int tid = threadIdx.x;
    const int jb = blockIdx.y * 256;
    sj[tid] = imp[jb + tid];
    __syncthreads();
    const int i = blockIdx.x * 256 + tid;
    const float mv = imp[i];
    int r = 0, rp = 0;
    for (int jj = 0; jj < 256; ++jj) {
        float vj = sj[jj];
        int j = jb + jj;
        int tie_low = (vj == mv) && (j < i);
        r  += (vj > mv) || tie_low;
        rp += (vj < mv) || tie_low;
    }
    atomicAdd(&rank[i], r);
    atomicAdd(&prank[i], rp);
}

__global__ __launch_bounds__(256) void scatter_topk2(
    const int* __restrict__ rank, const int* __restrict__ prank,
    float* __restrict__ out_imps, float* __restrict__ out_prune,
    int* __restrict__ imp_rows, int* __restrict__ prune_cols)
{
    __shared__ unsigned char fr[NT];
    __shared__ unsigned char fp[NT];
    __shared__ int sr[256], sp[256];
    const int tid = threadIdx.x;
    for (int t = tid; t < NT; t += 256) {
        fr[t] = rank[t] < KRET;
        fp[t] = prank[t] < NPR;
    }
    __syncthreads();
    const int base = tid * 16;
    int cr = 0, cp = 0;
#pragma unroll
    for (int e = 0; e < 16; ++e) { cr += fr[base + e]; cp += fp[base + e]; }
    sr[tid] = cr; sp[tid] = cp;
    __syncthreads();
    int pr = 0, pp = 0;
    for (int j = 0; j < tid; ++j) { pr += sr[j]; pp += sp[j]; }
#pragma unroll
    for (int e = 0; e < 16; ++e) {
        int i = base + e;
        if (fr[i]) { out_imps[pr] = (float)i; imp_rows[pr] = i; ++pr; }
        if (fp[i]) { out_prune[pp] = (float)i; prune_cols[pp] = i; ++pp; }
    }
}

__global__ __launch_bounds__(256) void argmax_part(
    const float* __restrict__ attn, const int* __restrict__ imp_rows,
    float* __restrict__ pbest, int* __restrict__ pbi)
{
    __shared__ int rows[CHUNK];
    const int tid = threadIdx.x;
    const int rc = blockIdx.y;
    const int r0 = rc * CHUNK;
    const int nr = min(KRET - r0, CHUNK);
    for (int t = tid; t < nr; t += 256) rows[t] = imp_rows[r0 + t];
    __syncthreads();
    const int j = blockIdx.x * 256 + tid;
    float best = -INFINITY;
    int bi = 0;
    for (int rr = 0; rr < nr; ++rr) {
        float val = attn[(size_t)rows[rr] * NT + j];
        if (val > best) { best = val; bi = r0 + rr; }
    }
    pbest[(size_t)rc * NT + j] = best;
    pbi[(size_t)rc * NT + j] = bi;
}

__global__ __launch_bounds__(256) void argmax_red(
    const float* __restrict__ pbest, const int* __restrict__ pbi,
    int* __restrict__ maxind)
{
    const int j = blockIdx.x * 256 + threadIdx.x;
    float best = -INFINITY;
    int bi = 0;
#pragma unroll
    for (int rc = 0; rc < 8; ++rc) {
        float val = pbest[(size_t)rc * NT + j];
        if (val > best) { best = val; bi = pbi[(size_t)rc * NT + j]; }
    }
    maxind[j] = bi;
}

__global__ __launch_bounds__(256) void finalize(
    const float* __restrict__ dist, const int* __restrict__ prune_cols,
    const int* __restrict__ maxind, float* __restrict__ out_imp,
    float* __restrict__ out_simi)
{
    int t = blockIdx.x * 256 + threadIdx.x;
    if (t < NT) out_imp[t] = dist[t];
    if (t < NPR) out_simi[t] = (float)maxind[prune_cols[t]];
}

extern "C" void kernel_launch(void* const* d_in, const int* in_sizes, int n_in,
                              void* d_out, int out_size, void* d_ws, size_t ws_size,
                              hipStream_t stream)
{
    const float* x  = (const float*)d_in[0];
    const float* Wq = (const float*)d_in[1];
    const float* Wk = (const float*)d_in[2];
    const float* Wv = (const float*)d_in[3];
    const float* Wo = (const float*)d_in[4];
    const float* bo = (const float*)d_in[5];
    float* out = (float*)d_out;

    const size_t QKT_EL = (size_t)NH * 256 * 3 * 16 * 32;   // 6.29M f16 per plane
    const size_t VP_EL  = (size_t)NH * 128 * 80 * 32;       // 5.24M bf16

    // ---- workspace layout (float units), ~166 MB with aliasing ----
    float* ws = (float*)d_ws;
    size_t off = 0;
    float* attn = ws + off; off += (size_t)NT * NT;
    f16* Qt0 = (f16*)(ws + off); off += QKT_EL / 2;
    f16* Qt1 = (f16*)(ws + off); off += QKT_EL / 2;
    f16* Kt0 = (f16*)(ws + off); off += QKT_EL / 2;
    f16* Kt1 = (f16*)(ws + off); off += QKT_EL / 2;
    ushort_t* Vp = (ushort_t*)(ws + off); off += VP_EL / 2;
    size_t zero_floats = 4 * (QKT_EL / 2) + VP_EL / 2;      // Qt0..Vp contiguous
    ushort_t* otmpb = (ushort_t*)(ws + off); off += ((size_t)NT * DM) / 2;
    f16* X0 = (f16*)(ws + off); f16* X1 = X0 + (size_t)NT * DM;
    float* xs_base = ws + off; off += (size_t)NT * DM;
    f16* T0 = (f16*)(ws + off); f16* T1 = T0 + (size_t)DM * DM; off += (size_t)DM * DM;
    ushort_t* Wslot = (ushort_t*)(ws + off); off += ((size_t)DM * DM) / 2;
    float* invs    = ws + off; off += (size_t)NH * NT;
    float* pbest   = ws + off; off += 8 * NT;
    int*   pbi     = (int*)(ws + off); off += 8 * NT;
    float* dist0 = ws + off; off += NT;
    float* dist1 = ws + off; off += NT;
    float* partial = ws + off; off += 32 * NT;
    int* rank      = (int*)(ws + off); off += NT;
    int* prank     = (int*)(ws + off); off += NT;
    int* imp_rows  = (int*)(ws + off); off += 2048;
    int* prune_cols= (int*)(ws + off); off += 2560;
    int* maxind    = (int*)(ws + off); off += NT;

    // aliases (lifetime-checked):
    //   xb (setup only) and part_pv (pass A only) live inside attn;
    //   rsPart lives inside the dead X-split region after projections.
    ushort_t* xb = (ushort_t*)attn;
    ushort_t* part_pv = (ushort_t*)attn;       // QSPLIT*NH*NT*DH bf16 = 37.7 MB
    float* rsPart = xs_base;                   // QSPLIT*NH*NT fp32 = 1 MB

    // output layout
    float* out_out   = out;
    float* out_imp   = out + (size_t)NT * DM;
    float* out_imps  = out_imp + NT;
    float* out_prune = out_imps + KRET;
    float* out_simi  = out_prune + NPR;

    // ---- setup ----
    hipMemsetAsync(Qt0, 0, zero_floats * sizeof(float), stream);  // zero-pad tiles
    split_x<<<2048, 256, 0, stream>>>(x, X0, X1, xb, NT * DM);

    dim3 gT(DM / 32, DM / 32);
    dim3 gP(DM / 64, NT / 128);
    transposeW_split<<<gT, 256, 0, stream>>>(Wq, T0, T1, DM);
    proj_split3<<<gP, 256, 0, stream>>>(X0, X1, T0, T1, Qt0, Qt1, SCALE);
    transposeW_split<<<gT, 256, 0, stream>>>(Wk, T0, T1, DM);
    proj_split3<<<gP, 256, 0, stream>>>(X0, X1, T0, T1, Kt0, Kt1, 1.0f);

    transposeW_bf16<<<gT, 256, 0, stream>>>(Wv, Wslot, DM);
    gemm_bf16_lds<<<gP, 256, 0, stream>>>(xb, Wslot, nullptr, Vp, 2, DM, DM);

    // ---- pass A: rowsums + PV, ct-split x4 (r16 version) ----
    rowsum_pv<<<dim3(NT / 64, NH, QSPLIT), 256, 0, stream>>>(Qt0, Qt1, Kt0, Kt1, Vp,
                                                             rsPart, part_pv);
    pv_norm<<<dim3(NH, NT / 32), 256, 0, stream>>>(rsPart, part_pv, invs, otmpb);

    // ---- pass B: attn head-sum, 2 rowblks/wave, 64 col-slices (r17) ----
    attn_sum<<<dim3(ACSB, NT / 128), 256, 0, stream>>>(Qt0, Qt1, Kt0, Kt1, invs, attn);

    // ---- output projection ----
    transposeW_bf16<<<gT, 256, 0, stream>>>(Wo, Wslot, DM);
    gemm_bf16_lds<<<gP, 256, 0, stream>>>(otmpb, Wslot, bo, out_out, 0, DM, DM);

    // ---- pagerank ----
    init_dist<<<16, 256, 0, stream>>>(dist0);
    float* da = dist0;
    float* db = dist1;
    for (int it = 0; it < 5; ++it) {
        power_a<<<dim3(16, 32), 256, 0, stream>>>(attn, da, partial);
        power_b<<<16, 256, 0, stream>>>(partial, db);
        float* t = da; da = db; db = t;
    }

    // ---- top-k ----
    hipMemsetAsync(rank, 0, 2 * NT * sizeof(int), stream);
    rank_count<<<dim3(16, 16), 256, 0, stream>>>(da, rank, prank);
    scatter_topk2<<<1, 256, 0, stream>>>(rank, prank, out_imps, out_prune,
                                         imp_rows, prune_cols);
    argmax_part<<<dim3(16, 8), 256, 0, stream>>>(attn, imp_rows, pbest, pbi);
    argmax_red<<<16, 256, 0, stream>>>(pbest, pbi, maxind);
    finalize<<<16, 256, 0, stream>>>(da, prune_cols, maxind, out_imp, out_simi);
}

// Round 19
// 793.980 us; speedup vs baseline: 1.4995x; 1.0050x over previous
//
#include <hip/hip_runtime.h>
#include <math.h>

#define NT 4096
#define DM 1152
#define NH 16
#define DH 72
#define KRET 1638
#define NPR (NT - KRET)
#define QSPLIT 4
#define ACSB 64
#define CHUNK 205
#define SCALE 0.11785113019775793f
#define RSPLIT 2048.0f
#define INV_RSPLIT 4.8828125e-4f

typedef __attribute__((ext_vector_type(8))) short bf16x8;
typedef _Float16 f16;
typedef __attribute__((ext_vector_type(8))) _Float16 f16x8;
typedef __attribute__((ext_vector_type(4))) float f32x4;
typedef unsigned short ushort_t;

#define MFMA16(a, b, c) __builtin_amdgcn_mfma_f32_16x16x32_f16(a, b, c, 0, 0, 0)
#define MFMABF(a, b, c) __builtin_amdgcn_mfma_f32_16x16x32_bf16(a, b, c, 0, 0, 0)

__device__ inline ushort_t f2b(float f) {
    union { float f; unsigned int u; } v; v.f = f;
    unsigned int u = v.u;
    return (ushort_t)((u + 0x7FFFu + ((u >> 16) & 1u)) >> 16);
}

__device__ inline float b2f(ushort_t u) {
    union { unsigned int u; float f; } v; v.u = ((unsigned int)u) << 16;
    return v.f;
}

// async global->LDS, 16B/lane: LDS base wave-uniform, global per-lane
__device__ __forceinline__ void async16(void* lds, const void* g) {
    __builtin_amdgcn_global_load_lds(
        (const __attribute__((address_space(1))) unsigned*)g,
        (__attribute__((address_space(3))) unsigned*)lds, 16, 0, 0);
}

// tiled Q/K address: [NH][rowblk 256][ks 3][r 16][ki 32]
__device__ inline size_t qkAddr(int h, int row, int ks, int ki) {
    return ((((size_t)h * 256 + (row >> 4)) * 3 + ks) * 16 + (row & 15)) * 32 + ki;
}

// ---------- split x into fp16 hi/lo(x2048) planes + bf16 copy ----------------
__global__ __launch_bounds__(256) void split_x(
    const float* __restrict__ in, f16* __restrict__ x0, f16* __restrict__ x1,
    ushort_t* __restrict__ xb, int nElem)
{
    int i = blockIdx.x * 256 + threadIdx.x;
    int stride = gridDim.x * 256;
    for (; i < nElem; i += stride) {
        float v = in[i];
        f16 h0 = (f16)v;
        float res = (v - (float)h0) * RSPLIT;
        x0[i] = h0;
        x1[i] = (f16)res;
        xb[i] = f2b(v);
    }
}

__global__ __launch_bounds__(256) void transposeW_split(
    const float* __restrict__ W, f16* __restrict__ T0, f16* __restrict__ T1, int n)
{
    __shared__ float t[32][33];
    int bx = blockIdx.x * 32, by = blockIdx.y * 32;
    int tx = threadIdx.x & 31, ty = threadIdx.x >> 5;
    for (int i = ty; i < 32; i += 8)
        t[i][tx] = W[(size_t)(by + i) * n + bx + tx];
    __syncthreads();
    for (int i = ty; i < 32; i += 8) {
        float v = t[tx][i];
        f16 h0 = (f16)v;
        float res = (v - (float)h0) * RSPLIT;
        T0[(size_t)(bx + i) * n + by + tx] = h0;
        T1[(size_t)(bx + i) * n + by + tx] = (f16)res;
    }
}

__global__ __launch_bounds__(256) void transposeW_bf16(
    const float* __restrict__ W, ushort_t* __restrict__ WT, int n)
{
    __shared__ ushort_t t[32][33];
    int bx = blockIdx.x * 32, by = blockIdx.y * 32;
    int tx = threadIdx.x & 31, ty = threadIdx.x >> 5;
    for (int i = ty; i < 32; i += 8)
        t[i][tx] = f2b(W[(size_t)(by + i) * n + bx + tx]);
    __syncthreads();
    for (int i = ty; i < 32; i += 8)
        WT[(size_t)(bx + i) * n + by + tx] = t[tx][i];
}

// ---------- LDS-tiled split projection -> MFMA-tiled per-head output ---------
__global__ __launch_bounds__(256) void proj_split3(
    const f16* __restrict__ A0, const f16* __restrict__ A1,
    const f16* __restrict__ B0, const f16* __restrict__ B1,
    f16* __restrict__ Qt0, f16* __restrict__ Qt1, float scl)
{
    __shared__ __align__(16) f16 As0[128][40];
    __shared__ __align__(16) f16 As1[128][40];
    __shared__ __align__(16) f16 Bs0[64][40];
    __shared__ __align__(16) f16 Bs1[64][40];
    const int tid = threadIdx.x;
    const int wave = tid >> 6, lane = tid & 63;
    const int r = lane & 15, g = lane >> 4;
    const int row0 = blockIdx.y * 128;
    const int col0 = blockIdx.x * 64;
    f32x4 accM[2][4] = {}, accC[2][4] = {};
    for (int k0 = 0; k0 < DM; k0 += 32) {
        for (int idx = tid; idx < 128 * 4; idx += 256) {
            int row = idx >> 2, c = idx & 3;
            size_t src = (size_t)(row0 + row) * DM + k0 + c * 8;
            *(f16x8*)&As0[row][c * 8] = *(const f16x8*)(A0 + src);
            *(f16x8*)&As1[row][c * 8] = *(const f16x8*)(A1 + src);
        }
        for (int idx = tid; idx < 64 * 4; idx += 256) {
            int row = idx >> 2, c = idx & 3;
            size_t src = (size_t)(col0 + row) * DM + k0 + c * 8;
            *(f16x8*)&Bs0[row][c * 8] = *(const f16x8*)(B0 + src);
            *(f16x8*)&Bs1[row][c * 8] = *(const f16x8*)(B1 + src);
        }
        __syncthreads();
        f16x8 a0[2], a1[2], b0[4], b1[4];
#pragma unroll
        for (int rf = 0; rf < 2; ++rf) {
            a0[rf] = *(const f16x8*)&As0[wave * 32 + rf * 16 + r][g * 8];
            a1[rf] = *(const f16x8*)&As1[wave * 32 + rf * 16 + r][g * 8];
        }
#pragma unroll
        for (int cf = 0; cf < 4; ++cf) {
            b0[cf] = *(const f16x8*)&Bs0[cf * 16 + r][g * 8];
            b1[cf] = *(const f16x8*)&Bs1[cf * 16 + r][g * 8];
        }
#pragma unroll
        for (int rf = 0; rf < 2; ++rf)
#pragma unroll
            for (int cf = 0; cf < 4; ++cf) {
                accM[rf][cf] = MFMA16(a0[rf], b0[cf], accM[rf][cf]);
                accC[rf][cf] = MFMA16(a0[rf], b1[cf], accC[rf][cf]);
                accC[rf][cf] = MFMA16(a1[rf], b0[cf], accC[rf][cf]);
            }
        __syncthreads();
    }
#pragma unroll
    for (int rf = 0; rf < 2; ++rf)
#pragma unroll
        for (int cf = 0; cf < 4; ++cf) {
            int col = col0 + cf * 16 + r;
            int head = col / DH;
            int c = col - head * DH;
            int ks = c >> 5, ki = c & 31;
#pragma unroll
            for (int j = 0; j < 4; ++j) {
                int row = row0 + wave * 32 + rf * 16 + g * 4 + j;
                float v = (accM[rf][cf][j] + accC[rf][cf][j] * INV_RSPLIT) * scl;
                f16 h0 = (f16)v;
                float res = (v - (float)h0) * RSPLIT;
                size_t addr = qkAddr(head, row, ks, ki);
                Qt0[addr] = h0;
                Qt1[addr] = (f16)res;
            }
        }
}

// ---------- LDS-tiled bf16 MFMA GEMM; mode 0 = fp32 flat, 2 = Vp tiled -------
__global__ __launch_bounds__(256) void gemm_bf16_lds(
    const ushort_t* __restrict__ A, const ushort_t* __restrict__ BT,
    const float* __restrict__ bias, void* __restrict__ C, int mode,
    int Nn, int K)
{
    __shared__ __align__(16) ushort_t As[128][40];
    __shared__ __align__(16) ushort_t Bs[64][40];
    const int tid = threadIdx.x;
    const int wave = tid >> 6, lane = tid & 63;
    const int r = lane & 15, g = lane >> 4;
    const int row0 = blockIdx.y * 128;
    const int col0 = blockIdx.x * 64;
    f32x4 acc[2][4] = {};
    for (int k0 = 0; k0 < K; k0 += 32) {
        for (int idx = tid; idx < 128 * 4; idx += 256) {
            int row = idx >> 2, c = idx & 3;
            *(bf16x8*)&As[row][c * 8] = *(const bf16x8*)(A + (size_t)(row0 + row) * K + k0 + c * 8);
        }
        for (int idx = tid; idx < 64 * 4; idx += 256) {
            int row = idx >> 2, c = idx & 3;
            *(bf16x8*)&Bs[row][c * 8] = *(const bf16x8*)(BT + (size_t)(col0 + row) * K + k0 + c * 8);
        }
        __syncthreads();
        bf16x8 a[2], b[4];
#pragma unroll
        for (int rf = 0; rf < 2; ++rf)
            a[rf] = *(const bf16x8*)&As[wave * 32 + rf * 16 + r][g * 8];
#pragma unroll
        for (int cf = 0; cf < 4; ++cf)
            b[cf] = *(const bf16x8*)&Bs[cf * 16 + r][g * 8];
#pragma unroll
        for (int rf = 0; rf < 2; ++rf)
#pragma unroll
            for (int cf = 0; cf < 4; ++cf)
                acc[rf][cf] = MFMABF(a[rf], b[cf], acc[rf][cf]);
        __syncthreads();
    }
#pragma unroll
    for (int rf = 0; rf < 2; ++rf)
#pragma unroll
        for (int cf = 0; cf < 4; ++cf) {
            int col = col0 + cf * 16 + r;
            float bv = bias ? bias[col] : 0.f;
#pragma unroll
            for (int j = 0; j < 4; ++j) {
                int row = row0 + wave * 32 + rf * 16 + g * 4 + j;
                float vv = acc[rf][cf][j] + bv;
                if (mode == 2) {
                    int head = col / DH;
                    int d = col - head * DH;
                    size_t addr = (((size_t)head * 128 + (row >> 5)) * 80 + d) * 32 + (row & 31);
                    ((ushort_t*)C)[addr] = f2b(vv);
                } else {
                    ((float*)C)[(size_t)row * Nn + col] = vv;
                }
            }
        }
}

// ---------- pass A: rowsum + PV, ct-split x4, global_load_lds staging --------
// grid (NT/64, NH, QSPLIT). Same bytes to same LDS addrs as r16 (bit-identical).
__global__ __launch_bounds__(256) void rowsum_pv(
    const f16* __restrict__ Qt0, const f16* __restrict__ Qt1,
    const f16* __restrict__ Kt0, const f16* __restrict__ Kt1,
    const ushort_t* __restrict__ Vp,
    float* __restrict__ rsPart, ushort_t* __restrict__ part_pv)
{
    __shared__ __align__(16) f16 KL[2][6144];   // [plane][12 tiles of 512]
    const int tid = threadIdx.x;
    const int wv = tid >> 6, lane = tid & 63;
    const int r = lane & 15, g = lane >> 4;
    const int h = blockIdx.y;
    const int quar = blockIdx.z;
    const int rowblk = blockIdx.x * 4 + wv;
    // Q fragments (used as the B operand of the swapped MFMA)
    f16x8 a0[3], a1[3];
#pragma unroll
    for (int ks = 0; ks < 3; ++ks) {
        size_t o = ((((size_t)h * 256 + rowblk) * 3 + ks) * 16) * 32 + r * 32 + g * 8;
        a0[ks] = *(const f16x8*)(Qt0 + o);
        a1[ks] = *(const f16x8*)(Qt1 + o);
    }
    // permuted per-lane K read columns: c32 = (r>>2)*8 + cfp*4 + (r&3)
    const int c32p0 = ((r >> 2) << 3) + (r & 3);
    float rs = 0.f;
    f32x4 oacc[5] = {};
    for (int ct = quar * 16; ct < quar * 16 + 16; ++ct) {
        __syncthreads();
        const size_t ctBase = ((size_t)h * 256 + ct * 4) * 1536;
#pragma unroll
        for (int s = 0; s < 6; ++s) {
            int wc = s * 4 + wv;             // 0..23 wave-chunks of 1024B
            int plane = wc >= 12;
            int cip = wc - plane * 12;
            const f16* src = (plane ? Kt1 : Kt0) + ctBase + cip * 512 + lane * 8;
            async16(&KL[plane][cip * 512], src);
        }
        __syncthreads();
        f32x4 accM[4] = {}, accC[4] = {};
#pragma unroll
        for (int ks = 0; ks < 3; ++ks) {
#pragma unroll
            for (int group = 0; group < 2; ++group) {
#pragma unroll
                for (int cfp = 0; cfp < 2; ++cfp) {
                    const int c32 = c32p0 + cfp * 4;
                    const int off = (((group * 2 + (c32 >> 4)) * 3 + ks) << 9)
                                  + ((c32 & 15) << 5) + (g << 3);
                    f16x8 b0 = *(const f16x8*)&KL[0][off];
                    f16x8 b1 = *(const f16x8*)&KL[1][off];
                    const int cf = group * 2 + cfp;
                    accM[cf] = MFMA16(b0, a0[ks], accM[cf]);
                    accC[cf] = MFMA16(b1, a0[ks], accC[cf]);
                    accC[cf] = MFMA16(b0, a1[ks], accC[cf]);
                }
            }
        }
        // exp -> rs + cvt_pk bf16 pack -> PV
        const int kt0 = ct * 2;
#pragma unroll
        for (int group = 0; group < 2; ++group) {
            float e[8];
#pragma unroll
            for (int cfp = 0; cfp < 2; ++cfp) {
                const int cf = group * 2 + cfp;
#pragma unroll
                for (int j = 0; j < 4; ++j) {
                    float ev = __expf(accM[cf][j] + accC[cf][j] * INV_RSPLIT);
                    rs += ev;
                    e[cfp * 4 + j] = ev;
                }
            }
            union { bf16x8 v; unsigned w[4]; } pa;
#pragma unroll
            for (int wi = 0; wi < 4; ++wi) {
                unsigned rw;
                asm("v_cvt_pk_bf16_f32 %0, %1, %2"
                    : "=v"(rw) : "v"(e[wi * 2]), "v"(e[wi * 2 + 1]));
                pa.w[wi] = rw;
            }
#pragma unroll
            for (int t = 0; t < 5; ++t) {
                int col = t * 16 + r;
                size_t vo = (((size_t)h * 128 + kt0 + group) * 80 + col) * 32 + g * 8;
                bf16x8 b = *(const bf16x8*)(Vp + vo);
                oacc[t] = MFMABF(pa.v, b, oacc[t]);
            }
        }
    }
    // rs is per-lane partial for q-row r; reduce over the 4 g-groups
    rs += __shfl_xor(rs, 16);
    rs += __shfl_xor(rs, 32);
    if (g == 0)
        rsPart[((size_t)quar * NH + h) * NT + rowblk * 16 + r] = rs;
    // unnormalized PV partial (bf16)
#pragma unroll
    for (int t = 0; t < 5; ++t) {
        int col = t * 16 + r;
        if (col < DH) {
#pragma unroll
            for (int j = 0; j < 4; ++j) {
                int row = rowblk * 16 + g * 4 + j;
                part_pv[(((size_t)quar * NH + h) * NT + row) * DH + col] = f2b(oacc[t][j]);
            }
        }
    }
}

// ---------- combine rowsum/PV quarters: invs + normalized otmpb --------------
__global__ __launch_bounds__(256) void pv_norm(
    const float* __restrict__ rsPart, const ushort_t* __restrict__ part_pv,
    float* __restrict__ invs, ushort_t* __restrict__ otmpb)
{
    __shared__ float sinv[32];
    const int h = blockIdx.x;
    const int row0 = blockIdx.y * 32;
    const int tid = threadIdx.x;
    if (tid < 32) {
        float s = 0.f;
#pragma unroll
        for (int q = 0; q < QSPLIT; ++q)
            s += rsPart[((size_t)q * NH + h) * NT + row0 + tid];
        float inv = 1.0f / s;
        sinv[tid] = inv;
        invs[(size_t)h * NT + row0 + tid] = inv;
    }
    __syncthreads();
    for (int e = tid; e < 32 * DH; e += 256) {
        int rr = e / DH, col = e - rr * DH;
        int row = row0 + rr;
        float s = 0.f;
#pragma unroll
        for (int q = 0; q < QSPLIT; ++q)
            s += b2f(part_pv[(((size_t)q * NH + h) * NT + row) * DH + col]);
        otmpb[(size_t)row * DM + h * DH + col] = f2b(s * sinv[rr]);
    }
}

// ---------- pass B: attn head-sum; 2 rowblks/wave; global_load_lds staging ---
// grid (ACSB, NT/128). Same bytes to same LDS addrs as r17 (bit-identical).
__global__ __launch_bounds__(256) void attn_sum(
    const f16* __restrict__ Qt0, const f16* __restrict__ Qt1,
    const f16* __restrict__ Kt0, const f16* __restrict__ Kt1,
    const float* __restrict__ invs, float* __restrict__ attn)
{
    __shared__ __align__(16) f16 KL[2][6144];   // [plane][12 tiles of 512]
    const int tid = threadIdx.x;
    const int wr = tid >> 6, lane = tid & 63;
    const int r = lane & 15, g = lane >> 4;
    const int cs = blockIdx.x;
    const int rowblk0 = blockIdx.y * 8 + wr;    // rowsets: rowblk0, rowblk0+4
    const int cb0 = cs * 4;                     // colblk base (64 cols/slice)
    float aacc[2][4][4] = {};                   // [rowset][cf][j]
    for (int h = 0; h < NH; ++h) {
        f16x8 a0[2][3], a1[2][3];
        float vinv[2][4];
#pragma unroll
        for (int rr = 0; rr < 2; ++rr) {
            const int rowblk = rowblk0 + rr * 4;
#pragma unroll
            for (int ks = 0; ks < 3; ++ks) {
                size_t o = ((((size_t)h * 256 + rowblk) * 3 + ks) * 16) * 32 + r * 32 + g * 8;
                a0[rr][ks] = *(const f16x8*)(Qt0 + o);
                a1[rr][ks] = *(const f16x8*)(Qt1 + o);
            }
#pragma unroll
            for (int j = 0; j < 4; ++j)
                vinv[rr][j] = invs[(size_t)h * NT + rowblk * 16 + g * 4 + j];
        }
        __syncthreads();
        const size_t ctBase = ((size_t)h * 256 + cb0) * 1536;
#pragma unroll
        for (int s = 0; s < 6; ++s) {
            int wc = s * 4 + wr;                // 0..23 wave-chunks of 1024B
            int plane = wc >= 12;
            int cip = wc - plane * 12;
            const f16* src = (plane ? Kt1 : Kt0) + ctBase + cip * 512 + lane * 8;
            async16(&KL[plane][cip * 512], src);
        }
        __syncthreads();
#pragma unroll
        for (int rr = 0; rr < 2; ++rr) {
            f32x4 accM[4] = {}, accC[4] = {};
#pragma unroll
            for (int ks = 0; ks < 3; ++ks) {
#pragma unroll
                for (int cf = 0; cf < 4; ++cf) {
                    f16x8 b0 = *(const f16x8*)&KL[0][(cf * 3 + ks) * 512 + r * 32 + g * 8];
                    f16x8 b1 = *(const f16x8*)&KL[1][(cf * 3 + ks) * 512 + r * 32 + g * 8];
                    accM[cf] = MFMA16(a0[rr][ks], b0, accM[cf]);
                    accC[cf] = MFMA16(a0[rr][ks], b1, accC[cf]);
                    accC[cf] = MFMA16(a1[rr][ks], b0, accC[cf]);
                }
            }
#pragma unroll
            for (int cf = 0; cf < 4; ++cf) {
#pragma unroll
                for (int j = 0; j < 4; ++j) {
                    float p = __expf(accM[cf][j] + accC[cf][j] * INV_RSPLIT) * vinv[rr][j];
                    aacc[rr][cf][j] += p;
                }
            }
        }
    }
    // write attn once (no rmw)
    const int colbase = cs * 64;
#pragma unroll
    for (int rr = 0; rr < 2; ++rr) {
        const int row0 = (rowblk0 + rr * 4) * 16;
#pragma unroll
        for (int cf = 0; cf < 4; ++cf) {
#pragma unroll
            for (int j = 0; j < 4; ++j) {
                int row = row0 + g * 4 + j;
                attn[(size_t)row * NT + colbase + cf * 16 + r] = aacc[rr][cf][j] * 0.0625f;
            }
        }
    }
}

// ---------- pagerank power iteration (fp32, unchanged) -----------------------
__global__ __launch_bounds__(256) void init_dist(float* __restrict__ d)
{
    int t = blockIdx.x * 256 + threadIdx.x;
    if (t < NT) d[t] = 1.0f / NT;
}

__global__ __launch_bounds__(256) void power_a(
    const float* __restrict__ attn, const float* __restrict__ din,
    float* __restrict__ part)
{
    int j = blockIdx.x * 256 + threadIdx.x;
    int i0 = blockIdx.y * 128;
    float acc = 0.f;
    for (int i = i0; i < i0 + 128; ++i)
        acc += din[i] * attn[(size_t)i * NT + j];
    part[(size_t)blockIdx.y * NT + j] = acc;
}

__global__ __launch_bounds__(256) void power_b(
    const float* __restrict__ part, float* __restrict__ dout)
{
    int j = blockIdx.x * 256 + threadIdx.x;
    float acc = 0.f;
    for (int ib = 0; ib < 32; ++ib) acc += part[(size_t)ib * NT + j];
    dout[j] = acc;
}

// ---------- top-k: tiled rank counting (deterministic int atomics) -----------
__global__ __launch_bounds__(256) void rank_count(
    const float* __restrict__ imp, int* __restrict__ rank, int* __restrict__ prank)
{
    __shared__ float sj[256];
    const int tid = threadIdx.x;
    const int jb = blockIdx.y * 256;
    sj[tid] = imp[jb + tid];
    __syncthreads();
    const int i = blockIdx.x * 256 + tid;
    const float mv = imp[i];
    int r = 0, rp = 0;
    for (int jj = 0; jj < 256; ++jj) {
        float vj = sj[jj];
        int j = jb + jj;
        int tie_low = (vj == mv) && (j < i);
        r  += (vj > mv) || tie_low;
        rp += (vj < mv) || tie_low;
    }
    atomicAdd(&rank[i], r);
    atomicAdd(&prank[i], rp);
}

__global__ __launch_bounds__(256) void scatter_topk2(
    const int* __restrict__ rank, const int* __restrict__ prank,
    float* __restrict__ out_imps, float* __restrict__ out_prune,
    int* __restrict__ imp_rows, int* __restrict__ prune_cols)
{
    __shared__ unsigned char fr[NT];
    __shared__ unsigned char fp[NT];
    __shared__ int sr[256], sp[256];
    const int tid = threadIdx.x;
    for (int t = tid; t < NT; t += 256) {
        fr[t] = rank[t] < KRET;
        fp[t] = prank[t] < NPR;
    }
    __syncthreads();
    const int base = tid * 16;
    int cr = 0, cp = 0;
#pragma unroll
    for (int e = 0; e < 16; ++e) { cr += fr[base + e]; cp += fp[base + e]; }
    sr[tid] = cr; sp[tid] = cp;
    __syncthreads();
    int pr = 0, pp = 0;
    for (int j = 0; j < tid; ++j) { pr += sr[j]; pp += sp[j]; }
#pragma unroll
    for (int e = 0; e < 16; ++e) {
        int i = base + e;
        if (fr[i]) { out_imps[pr] = (float)i; imp_rows[pr] = i; ++pr; }
        if (fp[i]) { out_prune[pp] = (float)i; prune_cols[pp] = i; ++pp; }
    }
}

__global__ __launch_bounds__(256) void argmax_part(
    const float* __restrict__ attn, const int* __restrict__ imp_rows,
    float* __restrict__ pbest, int* __restrict__ pbi)
{
    __shared__ int rows[CHUNK];
    const int tid = threadIdx.x;
    const int rc = blockIdx.y;
    const int r0 = rc * CHUNK;
    const int nr = min(KRET - r0, CHUNK);
    for (int t = tid; t < nr; t += 256) rows[t] = imp_rows[r0 + t];
    __syncthreads();
    const int j = blockIdx.x * 256 + tid;
    float best = -INFINITY;
    int bi = 0;
    for (int rr = 0; rr < nr; ++rr) {
        float val = attn[(size_t)rows[rr] * NT + j];
        if (val > best) { best = val; bi = r0 + rr; }
    }
    pbest[(size_t)rc * NT + j] = best;
    pbi[(size_t)rc * NT + j] = bi;
}

__global__ __launch_bounds__(256) void argmax_red(
    const float* __restrict__ pbest, const int* __restrict__ pbi,
    int* __restrict__ maxind)
{
    const int j = blockIdx.x * 256 + threadIdx.x;
    float best = -INFINITY;
    int bi = 0;
#pragma unroll
    for (int rc = 0; rc < 8; ++rc) {
        float val = pbest[(size_t)rc * NT + j];
        if (val > best) { best = val; bi = pbi[(size_t)rc * NT + j]; }
    }
    maxind[j] = bi;
}

__global__ __launch_bounds__(256) void finalize(
    const float* __restrict__ dist, const int* __restrict__ prune_cols,
    const int* __restrict__ maxind, float* __restrict__ out_imp,
    float* __restrict__ out_simi)
{
    int t = blockIdx.x * 256 + threadIdx.x;
    if (t < NT) out_imp[t] = dist[t];
    if (t < NPR) out_simi[t] = (float)maxind[prune_cols[t]];
}

extern "C" void kernel_launch(void* const* d_in, const int* in_sizes, int n_in,
                              void* d_out, int out_size, void* d_ws, size_t ws_size,
                              hipStream_t stream)
{
    const float* x  = (const float*)d_in[0];
    const float* Wq = (const float*)d_in[1];
    const float* Wk = (const float*)d_in[2];
    const float* Wv = (const float*)d_in[3];
    const float* Wo = (const float*)d_in[4];
    const float* bo = (const float*)d_in[5];
    float* out = (float*)d_out;

    const size_t QKT_EL = (size_t)NH * 256 * 3 * 16 * 32;   // 6.29M f16 per plane
    const size_t VP_EL  = (size_t)NH * 128 * 80 * 32;       // 5.24M bf16

    // ---- workspace layout (float units), ~166 MB with aliasing ----
    float* ws = (float*)d_ws;
    size_t off = 0;
    float* attn = ws + off; off += (size_t)NT * NT;
    f16* Qt0 = (f16*)(ws + off); off += QKT_EL / 2;
    f16* Qt1 = (f16*)(ws + off); off += QKT_EL / 2;
    f16* Kt0 = (f16*)(ws + off); off += QKT_EL / 2;
    f16* Kt1 = (f16*)(ws + off); off += QKT_EL / 2;
    ushort_t* Vp = (ushort_t*)(ws + off); off += VP_EL / 2;
    size_t zero_floats = 4 * (QKT_EL / 2) + VP_EL / 2;      // Qt0..Vp contiguous
    ushort_t* otmpb = (ushort_t*)(ws + off); off += ((size_t)NT * DM) / 2;
    f16* X0 = (f16*)(ws + off); f16* X1 = X0 + (size_t)NT * DM;
    float* xs_base = ws + off; off += (size_t)NT * DM;
    f16* T0 = (f16*)(ws + off); f16* T1 = T0 + (size_t)DM * DM; off += (size_t)DM * DM;
    ushort_t* Wslot = (ushort_t*)(ws + off); off += ((size_t)DM * DM) / 2;
    float* invs    = ws + off; off += (size_t)NH * NT;
    float* pbest   = ws + off; off += 8 * NT;
    int*   pbi     = (int*)(ws + off); off += 8 * NT;
    float* dist0 = ws + off; off += NT;
    float* dist1 = ws + off; off += NT;
    float* partial = ws + off; off += 32 * NT;
    int* rank      = (int*)(ws + off); off += NT;
    int* prank     = (int*)(ws + off); off += NT;
    int* imp_rows  = (int*)(ws + off); off += 2048;
    int* prune_cols= (int*)(ws + off); off += 2560;
    int* maxind    = (int*)(ws + off); off += NT;

    // aliases (lifetime-checked):
    //   xb (setup only) and part_pv (pass A only) live inside attn;
    //   rsPart lives inside the dead X-split region after projections.
    ushort_t* xb = (ushort_t*)attn;
    ushort_t* part_pv = (ushort_t*)attn;       // QSPLIT*NH*NT*DH bf16 = 37.7 MB
    float* rsPart = xs_base;                   // QSPLIT*NH*NT fp32 = 1 MB

    // output layout
    float* out_out   = out;
    float* out_imp   = out + (size_t)NT * DM;
    float* out_imps  = out_imp + NT;
    float* out_prune = out_imps + KRET;
    float* out_simi  = out_prune + NPR;

    // ---- setup ----
    hipMemsetAsync(Qt0, 0, zero_floats * sizeof(float), stream);  // zero-pad tiles
    split_x<<<2048, 256, 0, stream>>>(x, X0, X1, xb, NT * DM);

    dim3 gT(DM / 32, DM / 32);
    dim3 gP(DM / 64, NT / 128);
    transposeW_split<<<gT, 256, 0, stream>>>(Wq, T0, T1, DM);
    proj_split3<<<gP, 256, 0, stream>>>(X0, X1, T0, T1, Qt0, Qt1, SCALE);
    transposeW_split<<<gT, 256, 0, stream>>>(Wk, T0, T1, DM);
    proj_split3<<<gP, 256, 0, stream>>>(X0, X1, T0, T1, Kt0, Kt1, 1.0f);

    transposeW_bf16<<<gT, 256, 0, stream>>>(Wv, Wslot, DM);
    gemm_bf16_lds<<<gP, 256, 0, stream>>>(xb, Wslot, nullptr, Vp, 2, DM, DM);

    // ---- pass A: rowsums + PV, ct-split x4, async staging ----
    rowsum_pv<<<dim3(NT / 64, NH, QSPLIT), 256, 0, stream>>>(Qt0, Qt1, Kt0, Kt1, Vp,
                                                             rsPart, part_pv);
    pv_norm<<<dim3(NH, NT / 32), 256, 0, stream>>>(rsPart, part_pv, invs, otmpb);

    // ---- pass B: attn head-sum, 2 rowblks/wave, async staging ----
    attn_sum<<<dim3(ACSB, NT / 128), 256, 0, stream>>>(Qt0, Qt1, Kt0, Kt1, invs, attn);

    // ---- output projection ----
    transposeW_bf16<<<gT, 256, 0, stream>>>(Wo, Wslot, DM);
    gemm_bf16_lds<<<gP, 256, 0, stream>>>(otmpb, Wslot, bo, out_out, 0, DM, DM);

    // ---- pagerank ----
    init_dist<<<16, 256, 0, stream>>>(dist0);
    float* da = dist0;
    float* db = dist1;
    for (int it = 0; it < 5; ++it) {
        power_a<<<dim3(16, 32), 256, 0, stream>>>(attn, da, partial);
        power_b<<<16, 256, 0, stream>>>(partial, db);
        float* t = da; da = db; db = t;
    }

    // ---- top-k ----
    hipMemsetAsync(rank, 0, 2 * NT * sizeof(int), stream);
    rank_count<<<dim3(16, 16), 256, 0, stream>>>(da, rank, prank);
    scatter_topk2<<<1, 256, 0, stream>>>(rank, prank, out_imps, out_prune,
                                         imp_rows, prune_cols);
    argmax_part<<<dim3(16, 8), 256, 0, stream>>>(attn, imp_rows, pbest, pbi);
    argmax_red<<<16, 256, 0, stream>>>(pbest, pbi, maxind);
    finalize<<<16, 256, 0, stream>>>(da, prune_cols, maxind, out_imp, out_simi);
}